// Round 2
// baseline (350.966 us; speedup 1.0000x reference)
//
#include <hip/hip_runtime.h>
#include <hip/hip_bf16.h>

typedef __hip_bfloat16 bf16;
typedef __bf16 bf16x8 __attribute__((ext_vector_type(8)));
typedef float f32x4 __attribute__((ext_vector_type(4)));

#define BB 4
#define HH 240
#define WW 320
#define CG 64
#define NCO 24
#define HWSZ (HH*WW)

__device__ __forceinline__ float ldF(const void* __restrict__ p, long i, int isbf) {
    if (isbf) return __bfloat162float(((const bf16*)p)[i]);
    return ((const float*)p)[i];
}

__device__ __forceinline__ int detect_bf16(const void* asc) {
    // aff_scale_const == 4.0f: fp32 LE low u16 = 0x0000, bf16 = 0x4080.
    return ((const unsigned short*)asc)[0] != 0;
}

__device__ __forceinline__ unsigned short f2bfbits(float v) {
    bf16 h = __float2bfloat16(v);
    return *(unsigned short*)&h;
}

// ---------------------------------------------------------------------------
// Kernel 1 (old, channel-major) : emergency fallback path only
// ---------------------------------------------------------------------------
__global__ __launch_bounds__(256) void upsample_kernel(const void* __restrict__ tin,
                                                       const void* __restrict__ asc,
                                                       float* __restrict__ fea) {
    int isbf = detect_bf16(asc);
    int idx = blockIdx.x * 256 + threadIdx.x;
    if (idx >= BB * 8 * HWSZ) return;
    int j = idx % WW;
    int rest = idx / WW;
    int i = rest % HH;
    int bc = rest / HH;
    float sy = 0.5f * (float)i - 0.25f;
    float sx = 0.5f * (float)j - 0.25f;
    float y0f = floorf(sy), x0f = floorf(sx);
    float wy = sy - y0f, wx = sx - x0f;
    int y0 = (int)y0f, x0 = (int)x0f;
    int y0c = min(max(y0, 0), 119), y1c = min(max(y0 + 1, 0), 119);
    int x0c = min(max(x0, 0), 159), x1c = min(max(x0 + 1, 0), 159);
    long base = (long)bc * 120 * 160;
    float v00 = ldF(tin, base + y0c * 160 + x0c, isbf);
    float v01 = ldF(tin, base + y0c * 160 + x1c, isbf);
    float v10 = ldF(tin, base + y1c * 160 + x0c, isbf);
    float v11 = ldF(tin, base + y1c * 160 + x1c, isbf);
    fea[idx] = (1.f - wy) * ((1.f - wx) * v00 + wx * v01)
             + wy * ((1.f - wx) * v10 + wx * v11);
}

// ---------------------------------------------------------------------------
// Kernel 1b: bilinear 2x upsample -> CHANNELS-LAST fp32 fea_cl[b][i][j][ch]
// ---------------------------------------------------------------------------
__global__ __launch_bounds__(256) void upsample_cl_kernel(const void* __restrict__ tin,
                                                          const void* __restrict__ asc,
                                                          float* __restrict__ fea_cl) {
    int isbf = detect_bf16(asc);
    int idx = blockIdx.x * 256 + threadIdx.x;
    if (idx >= BB * HWSZ) return;
    int j = idx % WW;
    int rest = idx / WW;
    int i = rest % HH;
    int b = rest / HH;
    float sy = 0.5f * (float)i - 0.25f;
    float sx = 0.5f * (float)j - 0.25f;
    float y0f = floorf(sy), x0f = floorf(sx);
    float wy = sy - y0f, wx = sx - x0f;
    int y0 = (int)y0f, x0 = (int)x0f;
    int y0c = min(max(y0, 0), 119), y1c = min(max(y0 + 1, 0), 119);
    int x0c = min(max(x0, 0), 159), x1c = min(max(x0 + 1, 0), 159);
    float o[8];
#pragma unroll
    for (int ch = 0; ch < 8; ch++) {
        long base = (long)(b * 8 + ch) * 120 * 160;
        float v00 = ldF(tin, base + y0c * 160 + x0c, isbf);
        float v01 = ldF(tin, base + y0c * 160 + x1c, isbf);
        float v10 = ldF(tin, base + y1c * 160 + x0c, isbf);
        float v11 = ldF(tin, base + y1c * 160 + x1c, isbf);
        o[ch] = (1.f - wy) * ((1.f - wx) * v00 + wx * v01)
              + wy * ((1.f - wx) * v10 + wx * v11);
    }
    float* dst = fea_cl + (size_t)idx * 8;
    *(float4*)dst = make_float4(o[0], o[1], o[2], o[3]);
    *(float4*)(dst + 4) = make_float4(o[4], o[5], o[6], o[7]);
}

// ---------------------------------------------------------------------------
// Prep B: weights -> MFMA B-fragment layout Bp[t][n(32, 24 real)][k'(32)] bf16
// R2: was a single block (serial, latency-bound) -> 72 blocks.
// ---------------------------------------------------------------------------
__global__ __launch_bounds__(256) void prep_weights(const void* __restrict__ w,
                                                    const void* __restrict__ asc,
                                                    unsigned short* __restrict__ Bpu) {
    int isbf = detect_bf16(asc);
    int idx = blockIdx.x * 256 + threadIdx.x;
    if (idx >= 18 * 32 * 32) return;
    int t = idx >> 10;
    int r = idx & 1023;
    int n = r >> 5;
    int k = r & 31;
    int tap = t >> 1;
    int ch = t & 1;
    float v = 0.f;
    if (n < NCO)
        v = ldF(w, ((long)n * CG + ch * 32 + k) * 9 + tap, isbf);
    Bpu[idx] = f2bfbits(v);
}

// ---------------------------------------------------------------------------
// Kernel 2 (R2, fused): NCHW fp32/bf16 guidance -> LDS transpose -> MFMA conv.
//
// Block = 64 px (x) x 4 rows (y), 256 thr / 4 waves. Per block:
//   stage rows y0-1..y0+4 (66 px incl halo, 64 ch) as bf16 channels-last
//   into shF via two-phase LDS transpose:
//     phase1: coalesced global -> sT[ci][xi]        (2B stores, contiguous: free)
//     phase2: sT -> shF[row][xi][ch], 16B blocks XOR-swizzled by (xi&7)
//             (u32 stores cover 32 banks: free; ds_read_b128 in compute: 2-way)
//   Boundary rows/px staged as exact zeros (same result as the old kernel's
//   skip/mask: adding +0 products to an fp32 acc is exact).
// Compute: per wave 16 px x 24 co x K=576 over 4 row-passes; tap loop fully
// unrolled (no y-branch now), A-frags from LDS, B-frags from Bpu (L2-resident).
//
// Replaces prep_guidance + conv_mfma: kills the 39MB gTu write + 59MB re-read
// and the latency-bound scattered A loads (was MfmaUtil 5%, 1.07 TB/s, 84us).
// ---------------------------------------------------------------------------
__global__ __launch_bounds__(256) void conv_fused_kernel(const void* __restrict__ g,
                                                         const unsigned short* __restrict__ Bpu,
                                                         const void* __restrict__ bias,
                                                         const void* __restrict__ asc,
                                                         float* __restrict__ oa) {
    int isbf = detect_bf16(asc);
    const int x0 = blockIdx.x * 64;
    const int y0 = blockIdx.y * 4;
    const int b  = blockIdx.z;
    const int tid = threadIdx.x;

    __shared__ unsigned short shF[6 * 66 * 64];   // [row][xi 0..65][64 ch, swizzled 16B blocks]
    __shared__ unsigned short sT[64 * 66];        // [ci][xi]

    for (int row = 0; row < 6; row++) {
        int y = y0 - 1 + row;
        bool yok = (y >= 0) && (y < HH);
        // phase 1: global NCHW -> sT[ci][xi] (lanes = consecutive xi: coalesced)
        for (int it = 0; it < 17; it++) {
            int idx = it * 256 + tid;
            if (idx < 4224) {
                int ci = idx / 66;
                int xi = idx - ci * 66;
                int x = x0 - 1 + xi;
                float v = 0.f;
                if (yok && x >= 0 && x < WW)
                    v = ldF(g, ((long)(b * CG + ci) * HH + y) * WW + x, isbf);
                sT[ci * 66 + xi] = f2bfbits(v);
            }
        }
        __syncthreads();
        // phase 2: transpose repack -> shF row (channel pairs packed as u32)
        for (int it = 0; it < 9; it++) {
            int idx = it * 256 + tid;
            if (idx < 2112) {
                int cw = idx & 31;     // channel pair 0..31
                int xi = idx >> 5;     // 0..65
                unsigned int lo = sT[(2 * cw) * 66 + xi];
                unsigned int hi = sT[(2 * cw + 1) * 66 + xi];
                int q = cw >> 2;       // 16B block index 0..7
                int us = row * 4224 + xi * 64 + ((q ^ (xi & 7)) << 3) + ((2 * cw) & 7);
                *(unsigned int*)&shF[us] = lo | (hi << 16);
            }
        }
        __syncthreads();
    }

    const int wid  = tid >> 6;
    const int lane = tid & 63;
    const int m = lane & 15, quad = lane >> 4;
    const int x0w = x0 + wid * 16;
    const int n = m;
    float bias0 = ldF(bias, n, isbf);
    float bias1 = (n < 8) ? ldF(bias, 16 + n, isbf) : 0.f;

#pragma unroll 1
    for (int r = 0; r < 4; r++) {
        f32x4 acc0 = {0.f, 0.f, 0.f, 0.f};
        f32x4 acc1 = {0.f, 0.f, 0.f, 0.f};
#pragma unroll
        for (int tap = 0; tap < 9; tap++) {
            int shrow = r + tap / 3;
            int xi = wid * 16 + m + (tap % 3);
#pragma unroll
            for (int h = 0; h < 2; h++) {
                int t = tap * 2 + h;
                int us = shrow * 4224 + xi * 64 + ((((h * 4 + quad) ^ (xi & 7))) << 3);
                int4 ai = *(const int4*)&shF[us];
                bf16x8 af = __builtin_bit_cast(bf16x8, ai);
                int4 b0i = *(const int4*)(Bpu + ((t * 32 + m) * 32 + quad * 8));
                int4 b1i = *(const int4*)(Bpu + ((t * 32 + 16 + m) * 32 + quad * 8));
                bf16x8 bf0 = __builtin_bit_cast(bf16x8, b0i);
                bf16x8 bf1 = __builtin_bit_cast(bf16x8, b1i);
                acc0 = __builtin_amdgcn_mfma_f32_16x16x32_bf16(af, bf0, acc0, 0, 0, 0);
                acc1 = __builtin_amdgcn_mfma_f32_16x16x32_bf16(af, bf1, acc1, 0, 0, 0);
            }
        }
        int yy = y0 + r;
#pragma unroll
        for (int rr = 0; rr < 4; rr++) {
            int px = x0w + quad * 4 + rr;
            float* dst = &oa[(((size_t)b * HH + yy) * WW + px) * NCO];
            dst[n] = acc0[rr] + bias0;
            if (n < 8) dst[16 + n] = acc1[rr] + bias1;
        }
    }
}

// ---------------------------------------------------------------------------
// Fallback scalar conv (only if ws too small).
// ---------------------------------------------------------------------------
__global__ __launch_bounds__(256, 4) void conv_fallback(const void* __restrict__ g,
                                                        const void* __restrict__ w,
                                                        const void* __restrict__ bias,
                                                        const void* __restrict__ asc,
                                                        float* __restrict__ oa) {
    int isbf = detect_bf16(asc);
    const int b = blockIdx.z;
    const int i0 = blockIdx.y * 16;
    const int j0 = blockIdx.x * 16;
    const int tx = threadIdx.x & 15;
    const int ty = threadIdx.x >> 4;

    __shared__ float gl[8][18][20];
    __shared__ float wl[8][NCO][10];

    float acc[NCO];
#pragma unroll
    for (int c = 0; c < NCO; c++) acc[c] = ldF(bias, c, isbf);

    for (int ci0 = 0; ci0 < CG; ci0 += 8) {
        __syncthreads();
        for (int idx = threadIdx.x; idx < 8 * NCO * 9; idx += 256) {
            int t = idx % 9;
            int rest = idx / 9;
            int cc = rest & 7;
            int co = rest >> 3;
            wl[cc][co][t] = ldF(w, (long)(co * CG + ci0 + cc) * 9 + t, isbf);
        }
        for (int idx = threadIdx.x; idx < 8 * 18 * 18; idx += 256) {
            int cc = idx / 324;
            int rem = idx - cc * 324;
            int r = rem / 18;
            int c2 = rem - r * 18;
            int gi = i0 - 1 + r;
            int gj = j0 - 1 + c2;
            float v = 0.f;
            if (gi >= 0 && gi < HH && gj >= 0 && gj < WW)
                v = ldF(g, ((long)(b * CG + ci0 + cc) * HH + gi) * WW + gj, isbf);
            gl[cc][r][c2] = v;
        }
        __syncthreads();
#pragma unroll
        for (int cc = 0; cc < 8; cc++) {
            float ga[9];
#pragma unroll
            for (int dy = 0; dy < 3; dy++)
#pragma unroll
                for (int dx = 0; dx < 3; dx++)
                    ga[dy * 3 + dx] = gl[cc][ty + dy][tx + dx];
#pragma unroll 4
            for (int co = 0; co < NCO; co++) {
                float s = 0.f;
#pragma unroll
                for (int t = 0; t < 9; t++)
                    s += wl[cc][co][t] * ga[t];
                acc[co] += s;
            }
        }
    }
    int i = i0 + ty, j = j0 + tx;
    float4* p = (float4*)&oa[(((size_t)b * HH + i) * WW + j) * NCO];
#pragma unroll
    for (int q = 0; q < 6; q++)
        p[q] = make_float4(acc[4 * q], acc[4 * q + 1], acc[4 * q + 2], acc[4 * q + 3]);
}

// ---------------------------------------------------------------------------
// Branchless bilinear, zero outside: clamp indices, mask corner weights.
// ---------------------------------------------------------------------------
__device__ __forceinline__ float bil_zero_f32(const float* __restrict__ img,
                                              float x, float y) {
    float x0f = floorf(x), y0f = floorf(y);
    float wx = x - x0f, wy = y - y0f;
    int x0 = (int)x0f, y0 = (int)y0f;
    int x0c = min(max(x0, 0), WW - 1), x1c = min(max(x0 + 1, 0), WW - 1);
    int y0c = min(max(y0, 0), HH - 1), y1c = min(max(y0 + 1, 0), HH - 1);
    float mx0 = (x0 == x0c) ? 1.f : 0.f;
    float mx1 = (x0 + 1 == x1c) ? 1.f : 0.f;
    float my0 = (y0 == y0c) ? 1.f : 0.f;
    float my1 = (y0 + 1 == y1c) ? 1.f : 0.f;
    const float* r0 = img + (size_t)y0c * WW;
    const float* r1 = img + (size_t)y1c * WW;
    float v00 = r0[x0c], v01 = r0[x1c], v10 = r1[x0c], v11 = r1[x1c];
    return my0 * (1.f - wy) * (mx0 * (1.f - wx) * v00 + mx1 * wx * v01)
         + my1 * wy * (mx0 * (1.f - wx) * v10 + mx1 * wx * v11);
}

__device__ __forceinline__ float bil_zero_poly(const void* __restrict__ img, long base,
                                               float x, float y, int isbf) {
    float x0f = floorf(x), y0f = floorf(y);
    float wx = x - x0f, wy = y - y0f;
    int x0 = (int)x0f, y0 = (int)y0f;
    int x0c = min(max(x0, 0), WW - 1), x1c = min(max(x0 + 1, 0), WW - 1);
    int y0c = min(max(y0, 0), HH - 1), y1c = min(max(y0 + 1, 0), HH - 1);
    float mx0 = (x0 == x0c) ? 1.f : 0.f;
    float mx1 = (x0 + 1 == x1c) ? 1.f : 0.f;
    float my0 = (y0 == y0c) ? 1.f : 0.f;
    float my1 = (y0 + 1 == y1c) ? 1.f : 0.f;
    long r0 = base + (long)y0c * WW;
    long r1 = base + (long)y1c * WW;
    float v00 = ldF(img, r0 + x0c, isbf), v01 = ldF(img, r0 + x1c, isbf);
    float v10 = ldF(img, r1 + x0c, isbf), v11 = ldF(img, r1 + x1c, isbf);
    return my0 * (1.f - wy) * (mx0 * (1.f - wx) * v00 + mx1 * wx * v01)
         + my1 * wy * (mx0 * (1.f - wx) * v10 + mx1 * wx * v11);
}

// ---------------------------------------------------------------------------
// Kernel 3a: source-centric cosine affinity (see R1 notes).
// ---------------------------------------------------------------------------
__global__ __launch_bounds__(256, 4) void cos_kernel(const float* __restrict__ oa,
                                                     const float* __restrict__ fea_cl,
                                                     float* __restrict__ cos_buf) {
    __shared__ float S_lds[64 * 65];
    const int bx = blockIdx.x;   // 0..4 (qj chunk of 64)
    const int pi = blockIdx.y;   // 0..239
    const int b  = blockIdx.z;
    const int tid = threadIdx.x;
    const int qj_l = tid & 63;
    const int cpair = tid >> 6;  // 0..3 -> c in {2cp, 2cp+1}
    const int qj = bx * 64 + qj_l;

    const float* feaB = fea_cl + (size_t)b * HWSZ * 8;
    const float4 ov = *(const float4*)&oa[(((size_t)b * HH + pi) * WW + qj) * NCO + 4 * cpair];

#pragma unroll
    for (int t = 0; t < 2; t++) {
        int c = 2 * cpair + t;
        float ox = (t == 0) ? ov.x : ov.z;
        float oy = (t == 0) ? ov.y : ov.w;
        float add = (c < 4) ? (float)pi : (float)qj;   // wave-uniform branch
        float px = ox + add, py = oy + add;

        float x0f = floorf(px), y0f = floorf(py);
        float wx = px - x0f, wy = py - y0f;
        int x0 = (int)x0f, y0 = (int)y0f;
        int x0c = min(max(x0, 0), WW - 1), x1c = min(max(x0 + 1, 0), WW - 1);
        int y0c = min(max(y0, 0), HH - 1), y1c = min(max(y0 + 1, 0), HH - 1);
        float mx0 = (x0 == x0c) ? 1.f : 0.f;
        float mx1 = (x0 + 1 == x1c) ? 1.f : 0.f;
        float my0 = (y0 == y0c) ? 1.f : 0.f;
        float my1 = (y0 + 1 == y1c) ? 1.f : 0.f;
        float aw = mx0 * (1.f - wx);
        float bw = mx1 * wx;
        float tw = my0 * (1.f - wy);
        float dw = my1 * wy;

        const float* r0 = feaB + (size_t)y0c * WW * 8;
        const float* r1 = feaB + (size_t)y1c * WW * 8;
        float v00[8], v01[8], v10[8], v11[8];
        *(float4*)&v00[0] = *(const float4*)(r0 + x0c * 8);
        *(float4*)&v00[4] = *(const float4*)(r0 + x0c * 8 + 4);
        *(float4*)&v01[0] = *(const float4*)(r0 + x1c * 8);
        *(float4*)&v01[4] = *(const float4*)(r0 + x1c * 8 + 4);
        *(float4*)&v10[0] = *(const float4*)(r1 + x0c * 8);
        *(float4*)&v10[4] = *(const float4*)(r1 + x0c * 8 + 4);
        *(float4*)&v11[0] = *(const float4*)(r1 + x1c * 8);
        *(float4*)&v11[4] = *(const float4*)(r1 + x1c * 8 + 4);

        int base = qj_l * 65 + c * 8;
#pragma unroll
        for (int ch = 0; ch < 8; ch++)
            S_lds[base + ch] = tw * (aw * v00[ch] + bw * v01[ch])
                             + dw * (aw * v10[ch] + bw * v11[ch]);
    }

    __syncthreads();

    if (tid < 64) {
        int g = tid >> 3;       // qj group (8 qj = 8 n-slots)
        int c_img = tid & 7;    // sampled channel / output row band
        int i = c_img * 30 + (pi >> 3);
        int j = (pi & 7) * 40 + bx * 8 + g;
        const float* fp = feaB + ((size_t)i * WW + j) * 8;
        float f[8];
        *(float4*)&f[0] = *(const float4*)fp;
        *(float4*)&f[4] = *(const float4*)(fp + 4);
        float acc[8];
#pragma unroll
        for (int c = 0; c < 8; c++) acc[c] = 0.f;
#pragma unroll
        for (int n = 0; n < 8; n++) {       // ascending n: same FP order as old kernel
            float fn = f[n];
            int rb = (8 * g + n) * 65 + c_img;
#pragma unroll
            for (int c = 0; c < 8; c++)
                acc[c] += fn * S_lds[rb + c * 8];
        }
        float* dst = cos_buf + (((size_t)b * HH + i) * WW + j) * 8;
        *(float4*)dst = make_float4(acc[0], acc[1], acc[2], acc[3]);
        *(float4*)(dst + 4) = make_float4(acc[4], acc[5], acc[6], acc[7]);
    }
}

// ---------------------------------------------------------------------------
// Kernel 3b: per-pixel epilogue.
// ---------------------------------------------------------------------------
__global__ __launch_bounds__(256, 4) void final2_kernel(const float* __restrict__ oa,
                                                        const float* __restrict__ cos_buf,
                                                        const void* __restrict__ conf_in,
                                                        const void* __restrict__ asc_p,
                                                        float* __restrict__ out) {
    int isbf = detect_bf16(asc_p);
    int idx = blockIdx.x * 256 + threadIdx.x;
    if (idx >= BB * HWSZ) return;
    int j = idx % WW;
    int rest = idx / WW;
    int i = rest % HH;
    int b = rest / HH;

    float cos_acc[8];
    {
        const float* cp = cos_buf + (size_t)idx * 8;
        float4 ca = *(const float4*)cp;
        float4 cb = *(const float4*)(cp + 4);
        cos_acc[0] = ca.x; cos_acc[1] = ca.y; cos_acc[2] = ca.z; cos_acc[3] = ca.w;
        cos_acc[4] = cb.x; cos_acc[5] = cb.y; cos_acc[6] = cb.z; cos_acc[7] = cb.w;
    }

    const float4* op = (const float4*)&oa[(((size_t)b * HH + i) * WW + j) * NCO];
    float own[24];
#pragma unroll
    for (int q = 0; q < 6; q++) {
        float4 v = op[q];
        own[4 * q] = v.x; own[4 * q + 1] = v.y; own[4 * q + 2] = v.z; own[4 * q + 3] = v.w;
    }

    float asc = ldF(asc_p, 0, isbf) + 1e-8f;
    long cbase = (long)b * HWSZ;

    float a[8];
    float ssum = 0.f;
#pragma unroll
    for (int c = 0; c < 8; c++) {
        float v = own[16 + c] * cos_acc[c];
        v = tanhf(v) / asc;
        float py2 = own[2 * c] + (float)i;
        float px2 = own[2 * c + 1] + (float)j;
        float cf = bil_zero_poly(conf_in, cbase, px2, py2, isbf);
        v *= cf;
        a[c] = v;
        ssum += fabsf(v);
    }
    ssum += 1e-4f;
    ssum = fmaxf(ssum, 1.0f);
    float inv = 1.0f / ssum;
    float asum = 0.f;
#pragma unroll
    for (int c = 0; c < 8; c++) { a[c] *= inv; asum += a[c]; }
    float aref = 1.0f - asum;

    float vals[9];
#pragma unroll
    for (int c = 0; c < 4; c++) vals[c] = a[c];
    vals[4] = aref;
#pragma unroll
    for (int c = 4; c < 8; c++) vals[c + 1] = a[c];
    float m = vals[0];
#pragma unroll
    for (int k = 1; k < 9; k++) m = fmaxf(m, vals[k]);
    float es = 0.f;
#pragma unroll
    for (int k = 0; k < 9; k++) { vals[k] = __expf(vals[k] - m); es += vals[k]; }
    float ei = 1.0f / es;

    size_t pix = (size_t)i * WW + j;
    size_t base_o = (size_t)b * 18 * HWSZ + pix;
#pragma unroll
    for (int ch = 0; ch < 18; ch++) {
        float v;
        if (ch < 8) v = own[ch];
        else if (ch < 10) v = 0.f;
        else v = own[ch - 2];
        out[base_o + (size_t)ch * HWSZ] = v;
    }
    float* aff_out = out + (size_t)BB * 18 * HWSZ;
    size_t base_a = (size_t)b * 9 * HWSZ + pix;
#pragma unroll
    for (int k = 0; k < 9; k++)
        aff_out[base_a + (size_t)k * HWSZ] = vals[k] * ei;
}

// ---------------------------------------------------------------------------
// OLD monolithic final kernel — emergency fallback only (tiny workspace).
// ---------------------------------------------------------------------------
__global__ __launch_bounds__(256, 4) void final_kernel(const float* __restrict__ oa,
                                                       const float* __restrict__ fea,
                                                       const void* __restrict__ conf_in,
                                                       const void* __restrict__ asc_p,
                                                       float* __restrict__ out) {
    int isbf = detect_bf16(asc_p);
    int idx = blockIdx.x * 256 + threadIdx.x;
    if (idx >= BB * HWSZ) return;
    int j = idx % WW;
    int rest = idx / WW;
    int i = rest % HH;
    int b = rest / HH;

    const float* feaB = fea + (size_t)b * 8 * HWSZ;
    float f[8];
#pragma unroll
    for (int n = 0; n < 8; n++)
        f[n] = feaB[(size_t)n * HWSZ + (size_t)i * WW + j];

    int c_img = i / 30;
    int pi = (i % 30) * 8 + j / 40;
    int pj0 = (j % 40) * 8;
    const float* feaC = feaB + (size_t)c_img * HWSZ;

    float cos_acc[8];
#pragma unroll
    for (int c = 0; c < 8; c++) cos_acc[c] = 0.f;

#pragma unroll 1
    for (int n = 0; n < 8; n++) {
        int qj = pj0 + n;
        const float4* oq = (const float4*)&oa[(((size_t)b * HH + pi) * WW + qj) * NCO];
        float4 o0 = oq[0], o1 = oq[1], o2 = oq[2], o3 = oq[3];
        float off[16] = {o0.x, o0.y, o0.z, o0.w, o1.x, o1.y, o1.z, o1.w,
                         o2.x, o2.y, o2.z, o2.w, o3.x, o3.y, o3.z, o3.w};
        float fn = f[n];
#pragma unroll
        for (int c = 0; c < 8; c++) {
            float add = (c < 4) ? (float)pi : (float)qj;
            float px = off[2 * c] + add;
            float py = off[2 * c + 1] + add;
            cos_acc[c] += fn * bil_zero_f32(feaC, px, py);
        }
    }

    const float4* op = (const float4*)&oa[(((size_t)b * HH + i) * WW + j) * NCO];
    float own[24];
#pragma unroll
    for (int q = 0; q < 6; q++) {
        float4 v = op[q];
        own[4 * q] = v.x; own[4 * q + 1] = v.y; own[4 * q + 2] = v.z; own[4 * q + 3] = v.w;
    }

    float asc = ldF(asc_p, 0, isbf) + 1e-8f;
    long cbase = (long)b * HWSZ;

    float a[8];
    float ssum = 0.f;
#pragma unroll
    for (int c = 0; c < 8; c++) {
        float v = own[16 + c] * cos_acc[c];
        v = tanhf(v) / asc;
        float py2 = own[2 * c] + (float)i;
        float px2 = own[2 * c + 1] + (float)j;
        float cf = bil_zero_poly(conf_in, cbase, px2, py2, isbf);
        v *= cf;
        a[c] = v;
        ssum += fabsf(v);
    }
    ssum += 1e-4f;
    ssum = fmaxf(ssum, 1.0f);
    float inv = 1.0f / ssum;
    float asum = 0.f;
#pragma unroll
    for (int c = 0; c < 8; c++) { a[c] *= inv; asum += a[c]; }
    float aref = 1.0f - asum;

    float vals[9];
#pragma unroll
    for (int c = 0; c < 4; c++) vals[c] = a[c];
    vals[4] = aref;
#pragma unroll
    for (int c = 4; c < 8; c++) vals[c + 1] = a[c];
    float m = vals[0];
#pragma unroll
    for (int k = 1; k < 9; k++) m = fmaxf(m, vals[k]);
    float es = 0.f;
#pragma unroll
    for (int k = 0; k < 9; k++) { vals[k] = __expf(vals[k] - m); es += vals[k]; }
    float ei = 1.0f / es;

    size_t pix = (size_t)i * WW + j;
    size_t base_o = (size_t)b * 18 * HWSZ + pix;
#pragma unroll
    for (int ch = 0; ch < 18; ch++) {
        float v;
        if (ch < 8) v = own[ch];
        else if (ch < 10) v = 0.f;
        else v = own[ch - 2];
        out[base_o + (size_t)ch * HWSZ] = v;
    }
    float* aff_out = out + (size_t)BB * 18 * HWSZ;
    size_t base_a = (size_t)b * 9 * HWSZ + pix;
#pragma unroll
    for (int k = 0; k < 9; k++)
        aff_out[base_a + (size_t)k * HWSZ] = vals[k] * ei;
}

// ---------------------------------------------------------------------------
extern "C" void kernel_launch(void* const* d_in, const int* in_sizes, int n_in,
                              void* d_out, int out_size, void* d_ws, size_t ws_size,
                              hipStream_t stream) {
    const void* guidance = d_in[0];
    const void* gtconf   = d_in[1];
    const void* tgt      = d_in[2];
    const void* conv_w   = d_in[3];
    const void* conv_b   = d_in[4];
    const void* asc      = d_in[5];

    // Workspace layout (gTu is GONE — conv_fused stages guidance in LDS):
    //   oa   : BB*HWSZ*NCO f32 = 29,491,200 B
    //   fea  : BB*HWSZ*8   f32 =  9,830,400 B  (channels-last)
    //   cosb : BB*HWSZ*8   f32 =  9,830,400 B
    //   Bpu  : 18*32*32 bf16   =     36,864 B
    float* oa  = (float*)d_ws;
    float* fea = oa + (size_t)BB * HWSZ * NCO;
    float* cosb = fea + (size_t)BB * 8 * HWSZ;
    unsigned short* Bpu = (unsigned short*)(cosb + (size_t)BB * 8 * HWSZ);
    const size_t ws_new = (size_t)29491200 + 9830400 + 9830400 + 36864;  // 49,188,864
    float* out = (float*)d_out;

    int n_pix = BB * HWSZ;

    if (ws_size >= ws_new) {
        upsample_cl_kernel<<<(n_pix + 255) / 256, 256, 0, stream>>>(tgt, asc, fea);
        prep_weights<<<72, 256, 0, stream>>>(conv_w, asc, Bpu);
        dim3 cgrid(WW / 64, HH / 4, BB);
        conv_fused_kernel<<<cgrid, 256, 0, stream>>>(guidance, Bpu, conv_b, asc, oa);
        dim3 ggrid(WW / 64, HH, BB);
        cos_kernel<<<ggrid, 256, 0, stream>>>(oa, fea, cosb);
        final2_kernel<<<(n_pix + 255) / 256, 256, 0, stream>>>(oa, cosb, gtconf, asc, out);
    } else {
        // --- emergency tiny-workspace path (old monolithic) ---
        int n_up = BB * 8 * HWSZ;
        upsample_kernel<<<(n_up + 255) / 256, 256, 0, stream>>>(tgt, asc, fea);
        dim3 cgrid(WW / 16, HH / 16, BB);
        conv_fallback<<<cgrid, 256, 0, stream>>>(guidance, conv_w, conv_b, asc, oa);
        final_kernel<<<(n_pix + 255) / 256, 256, 0, stream>>>(oa, fea, gtconf, asc, out);
    }
}

// Round 3
// 313.594 us; speedup vs baseline: 1.1192x; 1.1192x over previous
//
#include <hip/hip_runtime.h>
#include <hip/hip_bf16.h>

typedef __hip_bfloat16 bf16;
typedef __bf16 bf16x8 __attribute__((ext_vector_type(8)));
typedef float f32x4 __attribute__((ext_vector_type(4)));

#define BB 4
#define HH 240
#define WW 320
#define CG 64
#define NCO 24
#define HWSZ (HH*WW)

__device__ __forceinline__ float ldF(const void* __restrict__ p, long i, int isbf) {
    if (isbf) return __bfloat162float(((const bf16*)p)[i]);
    return ((const float*)p)[i];
}

__device__ __forceinline__ int detect_bf16(const void* asc) {
    // aff_scale_const == 4.0f: fp32 LE low u16 = 0x0000, bf16 = 0x4080.
    return ((const unsigned short*)asc)[0] != 0;
}

__device__ __forceinline__ unsigned short f2bfbits(float v) {
    bf16 h = __float2bfloat16(v);
    return *(unsigned short*)&h;
}

// ---------------------------------------------------------------------------
// Kernel 1 (old, channel-major) : emergency fallback path only
// ---------------------------------------------------------------------------
__global__ __launch_bounds__(256) void upsample_kernel(const void* __restrict__ tin,
                                                       const void* __restrict__ asc,
                                                       float* __restrict__ fea) {
    int isbf = detect_bf16(asc);
    int idx = blockIdx.x * 256 + threadIdx.x;
    if (idx >= BB * 8 * HWSZ) return;
    int j = idx % WW;
    int rest = idx / WW;
    int i = rest % HH;
    int bc = rest / HH;
    float sy = 0.5f * (float)i - 0.25f;
    float sx = 0.5f * (float)j - 0.25f;
    float y0f = floorf(sy), x0f = floorf(sx);
    float wy = sy - y0f, wx = sx - x0f;
    int y0 = (int)y0f, x0 = (int)x0f;
    int y0c = min(max(y0, 0), 119), y1c = min(max(y0 + 1, 0), 119);
    int x0c = min(max(x0, 0), 159), x1c = min(max(x0 + 1, 0), 159);
    long base = (long)bc * 120 * 160;
    float v00 = ldF(tin, base + y0c * 160 + x0c, isbf);
    float v01 = ldF(tin, base + y0c * 160 + x1c, isbf);
    float v10 = ldF(tin, base + y1c * 160 + x0c, isbf);
    float v11 = ldF(tin, base + y1c * 160 + x1c, isbf);
    fea[idx] = (1.f - wy) * ((1.f - wx) * v00 + wx * v01)
             + wy * ((1.f - wx) * v10 + wx * v11);
}

// ---------------------------------------------------------------------------
// Kernel 0: tiny NCHW -> NHWC transpose of tgtimg_fea (2.4 MB; coalesced read)
// ---------------------------------------------------------------------------
__global__ __launch_bounds__(256) void tgt_cl_kernel(const void* __restrict__ tin,
                                                     const void* __restrict__ asc,
                                                     float* __restrict__ tcl) {
    int isbf = detect_bf16(asc);
    int idx = blockIdx.x * 256 + threadIdx.x;
    if (idx >= BB * 8 * 120 * 160) return;
    int x = idx % 160;
    int r = idx / 160;
    int yy = r % 120;
    int rc = r / 120;
    int ch = rc % 8;
    int b = rc / 8;
    float v = ldF(tin, idx, isbf);
    tcl[((((size_t)b * 120 + yy) * 160 + x) << 3) + ch] = v;
}

// ---------------------------------------------------------------------------
// Kernel 1b (R3): upsample from channels-last source -> channels-last dest.
// All loads/stores are float4; per-channel FP expression identical to before.
// ---------------------------------------------------------------------------
__global__ __launch_bounds__(256) void upsample_cl2_kernel(const float* __restrict__ tcl,
                                                           float* __restrict__ fea_cl) {
    int idx = blockIdx.x * 256 + threadIdx.x;
    if (idx >= BB * HWSZ) return;
    int j = idx % WW;
    int rest = idx / WW;
    int i = rest % HH;
    int b = rest / HH;
    float sy = 0.5f * (float)i - 0.25f;
    float sx = 0.5f * (float)j - 0.25f;
    float y0f = floorf(sy), x0f = floorf(sx);
    float wy = sy - y0f, wx = sx - x0f;
    int y0 = (int)y0f, x0 = (int)x0f;
    int y0c = min(max(y0, 0), 119), y1c = min(max(y0 + 1, 0), 119);
    int x0c = min(max(x0, 0), 159), x1c = min(max(x0 + 1, 0), 159);

    const float* s = tcl + ((size_t)b * 120 * 160) * 8;
    const float* p00 = s + ((size_t)y0c * 160 + x0c) * 8;
    const float* p01 = s + ((size_t)y0c * 160 + x1c) * 8;
    const float* p10 = s + ((size_t)y1c * 160 + x0c) * 8;
    const float* p11 = s + ((size_t)y1c * 160 + x1c) * 8;
    float v00[8], v01[8], v10[8], v11[8], o[8];
    *(float4*)&v00[0] = *(const float4*)p00; *(float4*)&v00[4] = *(const float4*)(p00 + 4);
    *(float4*)&v01[0] = *(const float4*)p01; *(float4*)&v01[4] = *(const float4*)(p01 + 4);
    *(float4*)&v10[0] = *(const float4*)p10; *(float4*)&v10[4] = *(const float4*)(p10 + 4);
    *(float4*)&v11[0] = *(const float4*)p11; *(float4*)&v11[4] = *(const float4*)(p11 + 4);
#pragma unroll
    for (int ch = 0; ch < 8; ch++)
        o[ch] = (1.f - wy) * ((1.f - wx) * v00[ch] + wx * v01[ch])
              + wy * ((1.f - wx) * v10[ch] + wx * v11[ch]);
    float* dst = fea_cl + (size_t)idx * 8;
    *(float4*)dst = make_float4(o[0], o[1], o[2], o[3]);
    *(float4*)(dst + 4) = make_float4(o[4], o[5], o[6], o[7]);
}

// ---------------------------------------------------------------------------
// Prep A (R3): guidance NCHW -> channels-last bf16 gT[b][y][x][ci].
// Phase 2 packs 2 channels per u32 store (coalesced 4B, conflict-free reads).
// ---------------------------------------------------------------------------
__global__ __launch_bounds__(256) void prep_guidance(const void* __restrict__ g,
                                                     const void* __restrict__ asc,
                                                     unsigned short* __restrict__ gTu) {
    int isbf = detect_bf16(asc);
    int x0 = blockIdx.x * 64;
    int y  = blockIdx.y;
    int b  = blockIdx.z;
    __shared__ unsigned short sh[64][66];
    int tid = threadIdx.x;
#pragma unroll
    for (int it = 0; it < 16; it++) {
        int idx = it * 256 + tid;
        int ci = idx >> 6;
        int xg = idx & 63;
        float v = ldF(g, ((long)(b * CG + ci) * HH + y) * WW + x0 + xg, isbf);
        sh[xg][ci] = f2bfbits(v);
    }
    __syncthreads();
#pragma unroll
    for (int it = 0; it < 8; it++) {
        int idx = it * 256 + tid;
        int xg = idx >> 5;
        int cp = idx & 31;
        unsigned int lo = sh[xg][2 * cp];
        unsigned int hi = sh[xg][2 * cp + 1];
        *(unsigned int*)&gTu[((((long)b * HH + y) * WW + x0 + xg) << 6) + 2 * cp]
            = lo | (hi << 16);
    }
}

// ---------------------------------------------------------------------------
// Prep B: weights -> MFMA B-fragment layout Bp[t][n(32, 24 real)][k'(32)] bf16
// ---------------------------------------------------------------------------
__global__ __launch_bounds__(256) void prep_weights(const void* __restrict__ w,
                                                    const void* __restrict__ asc,
                                                    unsigned short* __restrict__ Bpu) {
    int isbf = detect_bf16(asc);
    int idx = blockIdx.x * 256 + threadIdx.x;
    if (idx >= 18 * 32 * 32) return;
    int t = idx >> 10;
    int r = idx & 1023;
    int n = r >> 5;
    int k = r & 31;
    int tap = t >> 1;
    int ch = t & 1;
    float v = 0.f;
    if (n < NCO)
        v = ldF(w, ((long)n * CG + ch * 32 + k) * 9 + tap, isbf);
    Bpu[idx] = f2bfbits(v);
}

// ---------------------------------------------------------------------------
// Kernel 2 (R3): im2col MFMA conv, branchless + full A-prefetch.
//
// R1 post-mortem: VGPR_Count=28 proved the compiler kept ~3 loads in flight —
// the `continue` tap-branch blocked unrolling, so 54 global loads serialized
// (84us, MfmaUtil 5%). R3: taps fully unrolled; row clamp + cndmask-zeroed
// fragment (adds exact +0 to fp32 acc -> bit-identical); all 18 A-fragments
// prefetched into 72 VGPRs before the MFMA chain; B-frags stream from
// L2-resident Bpu (36KB). launch_bounds(256,4) caps VGPR at 128.
// ---------------------------------------------------------------------------
__global__ __launch_bounds__(256, 4) void conv_mfma2_kernel(const unsigned short* __restrict__ gTu,
                                                            const unsigned short* __restrict__ Bpu,
                                                            const void* __restrict__ bias,
                                                            const void* __restrict__ asc,
                                                            float* __restrict__ oa) {
    int isbf = detect_bf16(asc);
    const int y  = blockIdx.y;
    const int b  = blockIdx.z;
    const int wid  = threadIdx.x >> 6;
    const int lane = threadIdx.x & 63;
    const int m = lane & 15, quad = lane >> 4;
    const int x0 = blockIdx.x * 64 + wid * 16;

    int4 a[18];
#pragma unroll
    for (int tap = 0; tap < 9; tap++) {
        int yy = y + tap / 3 - 1;
        int yyc = min(max(yy, 0), HH - 1);
        int xx = x0 + m + (tap % 3) - 1;
        int xcl = min(max(xx, 0), WW - 1);
        bool ok = (yy == yyc) && (xx == xcl);
        long abase = (((long)b * HH + yyc) * WW + xcl) * 64;
#pragma unroll
        for (int ch = 0; ch < 2; ch++) {
            int4 ai = *(const int4*)(gTu + abase + ch * 32 + quad * 8);
            a[tap * 2 + ch] = ok ? ai : make_int4(0, 0, 0, 0);
        }
    }

    f32x4 acc0 = {0.f, 0.f, 0.f, 0.f};
    f32x4 acc1 = {0.f, 0.f, 0.f, 0.f};
#pragma unroll
    for (int t = 0; t < 18; t++) {
        bf16x8 af = __builtin_bit_cast(bf16x8, a[t]);
        int4 b0i = *(const int4*)(Bpu + ((t * 32 + m) * 32 + quad * 8));
        int4 b1i = *(const int4*)(Bpu + ((t * 32 + 16 + m) * 32 + quad * 8));
        bf16x8 bf0 = __builtin_bit_cast(bf16x8, b0i);
        bf16x8 bf1 = __builtin_bit_cast(bf16x8, b1i);
        acc0 = __builtin_amdgcn_mfma_f32_16x16x32_bf16(af, bf0, acc0, 0, 0, 0);
        acc1 = __builtin_amdgcn_mfma_f32_16x16x32_bf16(af, bf1, acc1, 0, 0, 0);
    }

    int n = m;
    float bias0 = ldF(bias, n, isbf);
    float bias1 = (n < 8) ? ldF(bias, 16 + n, isbf) : 0.f;
#pragma unroll
    for (int r = 0; r < 4; r++) {
        int px = x0 + quad * 4 + r;
        float* dst = &oa[(((size_t)b * HH + y) * WW + px) * NCO];
        dst[n] = acc0[r] + bias0;
        if (n < 8) dst[16 + n] = acc1[r] + bias1;
    }
}

// ---------------------------------------------------------------------------
// Fallback scalar conv (only if ws too small for gTu).
// ---------------------------------------------------------------------------
__global__ __launch_bounds__(256, 4) void conv_fallback(const void* __restrict__ g,
                                                        const void* __restrict__ w,
                                                        const void* __restrict__ bias,
                                                        const void* __restrict__ asc,
                                                        float* __restrict__ oa) {
    int isbf = detect_bf16(asc);
    const int b = blockIdx.z;
    const int i0 = blockIdx.y * 16;
    const int j0 = blockIdx.x * 16;
    const int tx = threadIdx.x & 15;
    const int ty = threadIdx.x >> 4;

    __shared__ float gl[8][18][20];
    __shared__ float wl[8][NCO][10];

    float acc[NCO];
#pragma unroll
    for (int c = 0; c < NCO; c++) acc[c] = ldF(bias, c, isbf);

    for (int ci0 = 0; ci0 < CG; ci0 += 8) {
        __syncthreads();
        for (int idx = threadIdx.x; idx < 8 * NCO * 9; idx += 256) {
            int t = idx % 9;
            int rest = idx / 9;
            int cc = rest & 7;
            int co = rest >> 3;
            wl[cc][co][t] = ldF(w, (long)(co * CG + ci0 + cc) * 9 + t, isbf);
        }
        for (int idx = threadIdx.x; idx < 8 * 18 * 18; idx += 256) {
            int cc = idx / 324;
            int rem = idx - cc * 324;
            int r = rem / 18;
            int c2 = rem - r * 18;
            int gi = i0 - 1 + r;
            int gj = j0 - 1 + c2;
            float v = 0.f;
            if (gi >= 0 && gi < HH && gj >= 0 && gj < WW)
                v = ldF(g, ((long)(b * CG + ci0 + cc) * HH + gi) * WW + gj, isbf);
            gl[cc][r][c2] = v;
        }
        __syncthreads();
#pragma unroll
        for (int cc = 0; cc < 8; cc++) {
            float ga[9];
#pragma unroll
            for (int dy = 0; dy < 3; dy++)
#pragma unroll
                for (int dx = 0; dx < 3; dx++)
                    ga[dy * 3 + dx] = gl[cc][ty + dy][tx + dx];
#pragma unroll 4
            for (int co = 0; co < NCO; co++) {
                float s = 0.f;
#pragma unroll
                for (int t = 0; t < 9; t++)
                    s += wl[cc][co][t] * ga[t];
                acc[co] += s;
            }
        }
    }
    int i = i0 + ty, j = j0 + tx;
    float4* p = (float4*)&oa[(((size_t)b * HH + i) * WW + j) * NCO];
#pragma unroll
    for (int q = 0; q < 6; q++)
        p[q] = make_float4(acc[4 * q], acc[4 * q + 1], acc[4 * q + 2], acc[4 * q + 3]);
}

// ---------------------------------------------------------------------------
// Branchless bilinear, zero outside: clamp indices, mask corner weights.
// ---------------------------------------------------------------------------
__device__ __forceinline__ float bil_zero_f32(const float* __restrict__ img,
                                              float x, float y) {
    float x0f = floorf(x), y0f = floorf(y);
    float wx = x - x0f, wy = y - y0f;
    int x0 = (int)x0f, y0 = (int)y0f;
    int x0c = min(max(x0, 0), WW - 1), x1c = min(max(x0 + 1, 0), WW - 1);
    int y0c = min(max(y0, 0), HH - 1), y1c = min(max(y0 + 1, 0), HH - 1);
    float mx0 = (x0 == x0c) ? 1.f : 0.f;
    float mx1 = (x0 + 1 == x1c) ? 1.f : 0.f;
    float my0 = (y0 == y0c) ? 1.f : 0.f;
    float my1 = (y0 + 1 == y1c) ? 1.f : 0.f;
    const float* r0 = img + (size_t)y0c * WW;
    const float* r1 = img + (size_t)y1c * WW;
    float v00 = r0[x0c], v01 = r0[x1c], v10 = r1[x0c], v11 = r1[x1c];
    return my0 * (1.f - wy) * (mx0 * (1.f - wx) * v00 + mx1 * wx * v01)
         + my1 * wy * (mx0 * (1.f - wx) * v10 + mx1 * wx * v11);
}

__device__ __forceinline__ float bil_zero_poly(const void* __restrict__ img, long base,
                                               float x, float y, int isbf) {
    float x0f = floorf(x), y0f = floorf(y);
    float wx = x - x0f, wy = y - y0f;
    int x0 = (int)x0f, y0 = (int)y0f;
    int x0c = min(max(x0, 0), WW - 1), x1c = min(max(x0 + 1, 0), WW - 1);
    int y0c = min(max(y0, 0), HH - 1), y1c = min(max(y0 + 1, 0), HH - 1);
    float mx0 = (x0 == x0c) ? 1.f : 0.f;
    float mx1 = (x0 + 1 == x1c) ? 1.f : 0.f;
    float my0 = (y0 == y0c) ? 1.f : 0.f;
    float my1 = (y0 + 1 == y1c) ? 1.f : 0.f;
    long r0 = base + (long)y0c * WW;
    long r1 = base + (long)y1c * WW;
    float v00 = ldF(img, r0 + x0c, isbf), v01 = ldF(img, r0 + x1c, isbf);
    float v10 = ldF(img, r1 + x0c, isbf), v11 = ldF(img, r1 + x1c, isbf);
    return my0 * (1.f - wy) * (mx0 * (1.f - wx) * v00 + mx1 * wx * v01)
         + my1 * wy * (mx0 * (1.f - wx) * v10 + mx1 * wx * v11);
}

// ---------------------------------------------------------------------------
// Kernel 3a: source-centric cosine affinity (see R1 notes).
// ---------------------------------------------------------------------------
__global__ __launch_bounds__(256, 4) void cos_kernel(const float* __restrict__ oa,
                                                     const float* __restrict__ fea_cl,
                                                     float* __restrict__ cos_buf) {
    __shared__ float S_lds[64 * 65];
    const int bx = blockIdx.x;   // 0..4 (qj chunk of 64)
    const int pi = blockIdx.y;   // 0..239
    const int b  = blockIdx.z;
    const int tid = threadIdx.x;
    const int qj_l = tid & 63;
    const int cpair = tid >> 6;  // 0..3 -> c in {2cp, 2cp+1}
    const int qj = bx * 64 + qj_l;

    const float* feaB = fea_cl + (size_t)b * HWSZ * 8;
    const float4 ov = *(const float4*)&oa[(((size_t)b * HH + pi) * WW + qj) * NCO + 4 * cpair];

#pragma unroll
    for (int t = 0; t < 2; t++) {
        int c = 2 * cpair + t;
        float ox = (t == 0) ? ov.x : ov.z;
        float oy = (t == 0) ? ov.y : ov.w;
        float add = (c < 4) ? (float)pi : (float)qj;   // wave-uniform branch
        float px = ox + add, py = oy + add;

        float x0f = floorf(px), y0f = floorf(py);
        float wx = px - x0f, wy = py - y0f;
        int x0 = (int)x0f, y0 = (int)y0f;
        int x0c = min(max(x0, 0), WW - 1), x1c = min(max(x0 + 1, 0), WW - 1);
        int y0c = min(max(y0, 0), HH - 1), y1c = min(max(y0 + 1, 0), HH - 1);
        float mx0 = (x0 == x0c) ? 1.f : 0.f;
        float mx1 = (x0 + 1 == x1c) ? 1.f : 0.f;
        float my0 = (y0 == y0c) ? 1.f : 0.f;
        float my1 = (y0 + 1 == y1c) ? 1.f : 0.f;
        float aw = mx0 * (1.f - wx);
        float bw = mx1 * wx;
        float tw = my0 * (1.f - wy);
        float dw = my1 * wy;

        const float* r0 = feaB + (size_t)y0c * WW * 8;
        const float* r1 = feaB + (size_t)y1c * WW * 8;
        float v00[8], v01[8], v10[8], v11[8];
        *(float4*)&v00[0] = *(const float4*)(r0 + x0c * 8);
        *(float4*)&v00[4] = *(const float4*)(r0 + x0c * 8 + 4);
        *(float4*)&v01[0] = *(const float4*)(r0 + x1c * 8);
        *(float4*)&v01[4] = *(const float4*)(r0 + x1c * 8 + 4);
        *(float4*)&v10[0] = *(const float4*)(r1 + x0c * 8);
        *(float4*)&v10[4] = *(const float4*)(r1 + x0c * 8 + 4);
        *(float4*)&v11[0] = *(const float4*)(r1 + x1c * 8);
        *(float4*)&v11[4] = *(const float4*)(r1 + x1c * 8 + 4);

        int base = qj_l * 65 + c * 8;
#pragma unroll
        for (int ch = 0; ch < 8; ch++)
            S_lds[base + ch] = tw * (aw * v00[ch] + bw * v01[ch])
                             + dw * (aw * v10[ch] + bw * v11[ch]);
    }

    __syncthreads();

    if (tid < 64) {
        int g = tid >> 3;       // qj group (8 qj = 8 n-slots)
        int c_img = tid & 7;    // sampled channel / output row band
        int i = c_img * 30 + (pi >> 3);
        int j = (pi & 7) * 40 + bx * 8 + g;
        const float* fp = feaB + ((size_t)i * WW + j) * 8;
        float f[8];
        *(float4*)&f[0] = *(const float4*)fp;
        *(float4*)&f[4] = *(const float4*)(fp + 4);
        float acc[8];
#pragma unroll
        for (int c = 0; c < 8; c++) acc[c] = 0.f;
#pragma unroll
        for (int n = 0; n < 8; n++) {       // ascending n: same FP order as old kernel
            float fn = f[n];
            int rb = (8 * g + n) * 65 + c_img;
#pragma unroll
            for (int c = 0; c < 8; c++)
                acc[c] += fn * S_lds[rb + c * 8];
        }
        float* dst = cos_buf + (((size_t)b * HH + i) * WW + j) * 8;
        *(float4*)dst = make_float4(acc[0], acc[1], acc[2], acc[3]);
        *(float4*)(dst + 4) = make_float4(acc[4], acc[5], acc[6], acc[7]);
    }
}

// ---------------------------------------------------------------------------
// Kernel 3b: per-pixel epilogue.
// ---------------------------------------------------------------------------
__global__ __launch_bounds__(256, 4) void final2_kernel(const float* __restrict__ oa,
                                                        const float* __restrict__ cos_buf,
                                                        const void* __restrict__ conf_in,
                                                        const void* __restrict__ asc_p,
                                                        float* __restrict__ out) {
    int isbf = detect_bf16(asc_p);
    int idx = blockIdx.x * 256 + threadIdx.x;
    if (idx >= BB * HWSZ) return;
    int j = idx % WW;
    int rest = idx / WW;
    int i = rest % HH;
    int b = rest / HH;

    float cos_acc[8];
    {
        const float* cp = cos_buf + (size_t)idx * 8;
        float4 ca = *(const float4*)cp;
        float4 cb = *(const float4*)(cp + 4);
        cos_acc[0] = ca.x; cos_acc[1] = ca.y; cos_acc[2] = ca.z; cos_acc[3] = ca.w;
        cos_acc[4] = cb.x; cos_acc[5] = cb.y; cos_acc[6] = cb.z; cos_acc[7] = cb.w;
    }

    const float4* op = (const float4*)&oa[(((size_t)b * HH + i) * WW + j) * NCO];
    float own[24];
#pragma unroll
    for (int q = 0; q < 6; q++) {
        float4 v = op[q];
        own[4 * q] = v.x; own[4 * q + 1] = v.y; own[4 * q + 2] = v.z; own[4 * q + 3] = v.w;
    }

    float asc = ldF(asc_p, 0, isbf) + 1e-8f;
    long cbase = (long)b * HWSZ;

    float a[8];
    float ssum = 0.f;
#pragma unroll
    for (int c = 0; c < 8; c++) {
        float v = own[16 + c] * cos_acc[c];
        v = tanhf(v) / asc;
        float py2 = own[2 * c] + (float)i;
        float px2 = own[2 * c + 1] + (float)j;
        float cf = bil_zero_poly(conf_in, cbase, px2, py2, isbf);
        v *= cf;
        a[c] = v;
        ssum += fabsf(v);
    }
    ssum += 1e-4f;
    ssum = fmaxf(ssum, 1.0f);
    float inv = 1.0f / ssum;
    float asum = 0.f;
#pragma unroll
    for (int c = 0; c < 8; c++) { a[c] *= inv; asum += a[c]; }
    float aref = 1.0f - asum;

    float vals[9];
#pragma unroll
    for (int c = 0; c < 4; c++) vals[c] = a[c];
    vals[4] = aref;
#pragma unroll
    for (int c = 4; c < 8; c++) vals[c + 1] = a[c];
    float m = vals[0];
#pragma unroll
    for (int k = 1; k < 9; k++) m = fmaxf(m, vals[k]);
    float es = 0.f;
#pragma unroll
    for (int k = 0; k < 9; k++) { vals[k] = __expf(vals[k] - m); es += vals[k]; }
    float ei = 1.0f / es;

    size_t pix = (size_t)i * WW + j;
    size_t base_o = (size_t)b * 18 * HWSZ + pix;
#pragma unroll
    for (int ch = 0; ch < 18; ch++) {
        float v;
        if (ch < 8) v = own[ch];
        else if (ch < 10) v = 0.f;
        else v = own[ch - 2];
        out[base_o + (size_t)ch * HWSZ] = v;
    }
    float* aff_out = out + (size_t)BB * 18 * HWSZ;
    size_t base_a = (size_t)b * 9 * HWSZ + pix;
#pragma unroll
    for (int k = 0; k < 9; k++)
        aff_out[base_a + (size_t)k * HWSZ] = vals[k] * ei;
}

// ---------------------------------------------------------------------------
// OLD monolithic final kernel — emergency fallback only (tiny workspace).
// ---------------------------------------------------------------------------
__global__ __launch_bounds__(256, 4) void final_kernel(const float* __restrict__ oa,
                                                       const float* __restrict__ fea,
                                                       const void* __restrict__ conf_in,
                                                       const void* __restrict__ asc_p,
                                                       float* __restrict__ out) {
    int isbf = detect_bf16(asc_p);
    int idx = blockIdx.x * 256 + threadIdx.x;
    if (idx >= BB * HWSZ) return;
    int j = idx % WW;
    int rest = idx / WW;
    int i = rest % HH;
    int b = rest / HH;

    const float* feaB = fea + (size_t)b * 8 * HWSZ;
    float f[8];
#pragma unroll
    for (int n = 0; n < 8; n++)
        f[n] = feaB[(size_t)n * HWSZ + (size_t)i * WW + j];

    int c_img = i / 30;
    int pi = (i % 30) * 8 + j / 40;
    int pj0 = (j % 40) * 8;
    const float* feaC = feaB + (size_t)c_img * HWSZ;

    float cos_acc[8];
#pragma unroll
    for (int c = 0; c < 8; c++) cos_acc[c] = 0.f;

#pragma unroll 1
    for (int n = 0; n < 8; n++) {
        int qj = pj0 + n;
        const float4* oq = (const float4*)&oa[(((size_t)b * HH + pi) * WW + qj) * NCO];
        float4 o0 = oq[0], o1 = oq[1], o2 = oq[2], o3 = oq[3];
        float off[16] = {o0.x, o0.y, o0.z, o0.w, o1.x, o1.y, o1.z, o1.w,
                         o2.x, o2.y, o2.z, o2.w, o3.x, o3.y, o3.z, o3.w};
        float fn = f[n];
#pragma unroll
        for (int c = 0; c < 8; c++) {
            float add = (c < 4) ? (float)pi : (float)qj;
            float px = off[2 * c] + add;
            float py = off[2 * c + 1] + add;
            cos_acc[c] += fn * bil_zero_f32(feaC, px, py);
        }
    }

    const float4* op = (const float4*)&oa[(((size_t)b * HH + i) * WW + j) * NCO];
    float own[24];
#pragma unroll
    for (int q = 0; q < 6; q++) {
        float4 v = op[q];
        own[4 * q] = v.x; own[4 * q + 1] = v.y; own[4 * q + 2] = v.z; own[4 * q + 3] = v.w;
    }

    float asc = ldF(asc_p, 0, isbf) + 1e-8f;
    long cbase = (long)b * HWSZ;

    float a[8];
    float ssum = 0.f;
#pragma unroll
    for (int c = 0; c < 8; c++) {
        float v = own[16 + c] * cos_acc[c];
        v = tanhf(v) / asc;
        float py2 = own[2 * c] + (float)i;
        float px2 = own[2 * c + 1] + (float)j;
        float cf = bil_zero_poly(conf_in, cbase, px2, py2, isbf);
        v *= cf;
        a[c] = v;
        ssum += fabsf(v);
    }
    ssum += 1e-4f;
    ssum = fmaxf(ssum, 1.0f);
    float inv = 1.0f / ssum;
    float asum = 0.f;
#pragma unroll
    for (int c = 0; c < 8; c++) { a[c] *= inv; asum += a[c]; }
    float aref = 1.0f - asum;

    float vals[9];
#pragma unroll
    for (int c = 0; c < 4; c++) vals[c] = a[c];
    vals[4] = aref;
#pragma unroll
    for (int c = 4; c < 8; c++) vals[c + 1] = a[c];
    float m = vals[0];
#pragma unroll
    for (int k = 1; k < 9; k++) m = fmaxf(m, vals[k]);
    float es = 0.f;
#pragma unroll
    for (int k = 0; k < 9; k++) { vals[k] = __expf(vals[k] - m); es += vals[k]; }
    float ei = 1.0f / es;

    size_t pix = (size_t)i * WW + j;
    size_t base_o = (size_t)b * 18 * HWSZ + pix;
#pragma unroll
    for (int ch = 0; ch < 18; ch++) {
        float v;
        if (ch < 8) v = own[ch];
        else if (ch < 10) v = 0.f;
        else v = own[ch - 2];
        out[base_o + (size_t)ch * HWSZ] = v;
    }
    float* aff_out = out + (size_t)BB * 18 * HWSZ;
    size_t base_a = (size_t)b * 9 * HWSZ + pix;
#pragma unroll
    for (int k = 0; k < 9; k++)
        aff_out[base_a + (size_t)k * HWSZ] = vals[k] * ei;
}

// ---------------------------------------------------------------------------
extern "C" void kernel_launch(void* const* d_in, const int* in_sizes, int n_in,
                              void* d_out, int out_size, void* d_ws, size_t ws_size,
                              hipStream_t stream) {
    const void* guidance = d_in[0];
    const void* gtconf   = d_in[1];
    const void* tgt      = d_in[2];
    const void* conv_w   = d_in[3];
    const void* conv_b   = d_in[4];
    const void* asc      = d_in[5];

    // Workspace layout. The 39.3MB "big" region is time-shared (sequential
    // stream => liveness is disjoint):
    //   tcl  (2.4MB)  live: tgt_cl -> upsample_cl2
    //   gTu  (39.3MB) live: prep_guidance -> conv_mfma2
    //   cosb (9.8MB)  live: cos_kernel -> final2_kernel
    //   oa   : BB*HWSZ*NCO f32 = 29,491,200 B
    //   fea  : BB*HWSZ*8   f32 =  9,830,400 B  (channels-last)
    //   big  : 39,321,600 B
    //   Bpu  : 36,864 B
    float* oa  = (float*)d_ws;
    float* fea = oa + (size_t)BB * HWSZ * NCO;
    float* big = fea + (size_t)BB * 8 * HWSZ;
    unsigned short* gTu = (unsigned short*)big;
    float* cosb = big;
    float* tcl  = big;
    unsigned short* Bpu = (unsigned short*)((char*)big + (size_t)39321600);
    const size_t ws_full = (size_t)29491200 + 9830400 + 39321600 + 36864;  // 78,680,064
    const size_t ws_mid  = (size_t)29491200 + 9830400 + 9830400;           // 49,152,000
    float* out = (float*)d_out;

    int n_pix = BB * HWSZ;
    int n_tgt = BB * 8 * 120 * 160;

    if (ws_size >= ws_full) {
        tgt_cl_kernel<<<(n_tgt + 255) / 256, 256, 0, stream>>>(tgt, asc, tcl);
        upsample_cl2_kernel<<<(n_pix + 255) / 256, 256, 0, stream>>>(tcl, fea);
        prep_weights<<<72, 256, 0, stream>>>(conv_w, asc, Bpu);
        dim3 pgrid(WW / 64, HH, BB);
        prep_guidance<<<pgrid, 256, 0, stream>>>(guidance, asc, gTu);
        dim3 cgrid(WW / 64, HH, BB);
        conv_mfma2_kernel<<<cgrid, 256, 0, stream>>>(gTu, Bpu, conv_b, asc, oa);
        dim3 ggrid(WW / 64, HH, BB);
        cos_kernel<<<ggrid, 256, 0, stream>>>(oa, fea, cosb);
        final2_kernel<<<(n_pix + 255) / 256, 256, 0, stream>>>(oa, cosb, gtconf, asc, out);
    } else if (ws_size >= ws_mid) {
        // mid path: no gTu; scalar conv + split cos/final2 (tcl aliases cosb).
        tgt_cl_kernel<<<(n_tgt + 255) / 256, 256, 0, stream>>>(tgt, asc, tcl);
        upsample_cl2_kernel<<<(n_pix + 255) / 256, 256, 0, stream>>>(tcl, fea);
        dim3 cgrid(WW / 16, HH / 16, BB);
        conv_fallback<<<cgrid, 256, 0, stream>>>(guidance, conv_w, conv_b, asc, oa);
        dim3 ggrid(WW / 64, HH, BB);
        cos_kernel<<<ggrid, 256, 0, stream>>>(oa, fea, cosb);
        final2_kernel<<<(n_pix + 255) / 256, 256, 0, stream>>>(oa, cosb, gtconf, asc, out);
    } else {
        // --- emergency tiny-workspace path (old monolithic) ---
        int n_up = BB * 8 * HWSZ;
        upsample_kernel<<<(n_up + 255) / 256, 256, 0, stream>>>(tgt, asc, fea);
        dim3 cgrid(WW / 16, HH / 16, BB);
        conv_fallback<<<cgrid, 256, 0, stream>>>(guidance, conv_w, conv_b, asc, oa);
        final_kernel<<<(n_pix + 255) / 256, 256, 0, stream>>>(oa, fea, gtconf, asc, out);
    }
}

// Round 5
// 262.374 us; speedup vs baseline: 1.3377x; 1.1952x over previous
//
#include <hip/hip_runtime.h>
#include <hip/hip_bf16.h>

typedef __hip_bfloat16 bf16;
typedef __bf16 bf16x8 __attribute__((ext_vector_type(8)));
typedef float f32x4 __attribute__((ext_vector_type(4)));

#define BB 4
#define HH 240
#define WW 320
#define CG 64
#define NCO 24
#define HWSZ (HH*WW)

__device__ __forceinline__ float ldF(const void* __restrict__ p, long i, int isbf) {
    if (isbf) return __bfloat162float(((const bf16*)p)[i]);
    return ((const float*)p)[i];
}

__device__ __forceinline__ int detect_bf16(const void* asc) {
    // aff_scale_const == 4.0f: fp32 LE low u16 = 0x0000, bf16 = 0x4080.
    return ((const unsigned short*)asc)[0] != 0;
}

__device__ __forceinline__ unsigned short f2bfbits(float v) {
    bf16 h = __float2bfloat16(v);
    return *(unsigned short*)&h;
}

// ---------------------------------------------------------------------------
// Kernel 1 (old, channel-major) : emergency fallback path only
// ---------------------------------------------------------------------------
__global__ __launch_bounds__(256) void upsample_kernel(const void* __restrict__ tin,
                                                       const void* __restrict__ asc,
                                                       float* __restrict__ fea) {
    int isbf = detect_bf16(asc);
    int idx = blockIdx.x * 256 + threadIdx.x;
    if (idx >= BB * 8 * HWSZ) return;
    int j = idx % WW;
    int rest = idx / WW;
    int i = rest % HH;
    int bc = rest / HH;
    float sy = 0.5f * (float)i - 0.25f;
    float sx = 0.5f * (float)j - 0.25f;
    float y0f = floorf(sy), x0f = floorf(sx);
    float wy = sy - y0f, wx = sx - x0f;
    int y0 = (int)y0f, x0 = (int)x0f;
    int y0c = min(max(y0, 0), 119), y1c = min(max(y0 + 1, 0), 119);
    int x0c = min(max(x0, 0), 159), x1c = min(max(x0 + 1, 0), 159);
    long base = (long)bc * 120 * 160;
    float v00 = ldF(tin, base + y0c * 160 + x0c, isbf);
    float v01 = ldF(tin, base + y0c * 160 + x1c, isbf);
    float v10 = ldF(tin, base + y1c * 160 + x0c, isbf);
    float v11 = ldF(tin, base + y1c * 160 + x1c, isbf);
    fea[idx] = (1.f - wy) * ((1.f - wx) * v00 + wx * v01)
             + wy * ((1.f - wx) * v10 + wx * v11);
}

// ---------------------------------------------------------------------------
// Kernel 0: tiny NCHW -> NHWC transpose of tgtimg_fea (2.4 MB; coalesced read)
// ---------------------------------------------------------------------------
__global__ __launch_bounds__(256) void tgt_cl_kernel(const void* __restrict__ tin,
                                                     const void* __restrict__ asc,
                                                     float* __restrict__ tcl) {
    int isbf = detect_bf16(asc);
    int idx = blockIdx.x * 256 + threadIdx.x;
    if (idx >= BB * 8 * 120 * 160) return;
    int x = idx % 160;
    int r = idx / 160;
    int yy = r % 120;
    int rc = r / 120;
    int ch = rc % 8;
    int b = rc / 8;
    float v = ldF(tin, idx, isbf);
    tcl[((((size_t)b * 120 + yy) * 160 + x) << 3) + ch] = v;
}

// ---------------------------------------------------------------------------
// Kernel 1b: upsample from channels-last source -> channels-last dest.
// ---------------------------------------------------------------------------
__global__ __launch_bounds__(256) void upsample_cl2_kernel(const float* __restrict__ tcl,
                                                           float* __restrict__ fea_cl) {
    int idx = blockIdx.x * 256 + threadIdx.x;
    if (idx >= BB * HWSZ) return;
    int j = idx % WW;
    int rest = idx / WW;
    int i = rest % HH;
    int b = rest / HH;
    float sy = 0.5f * (float)i - 0.25f;
    float sx = 0.5f * (float)j - 0.25f;
    float y0f = floorf(sy), x0f = floorf(sx);
    float wy = sy - y0f, wx = sx - x0f;
    int y0 = (int)y0f, x0 = (int)x0f;
    int y0c = min(max(y0, 0), 119), y1c = min(max(y0 + 1, 0), 119);
    int x0c = min(max(x0, 0), 159), x1c = min(max(x0 + 1, 0), 159);

    const float* s = tcl + ((size_t)b * 120 * 160) * 8;
    const float* p00 = s + ((size_t)y0c * 160 + x0c) * 8;
    const float* p01 = s + ((size_t)y0c * 160 + x1c) * 8;
    const float* p10 = s + ((size_t)y1c * 160 + x0c) * 8;
    const float* p11 = s + ((size_t)y1c * 160 + x1c) * 8;
    float v00[8], v01[8], v10[8], v11[8], o[8];
    *(float4*)&v00[0] = *(const float4*)p00; *(float4*)&v00[4] = *(const float4*)(p00 + 4);
    *(float4*)&v01[0] = *(const float4*)p01; *(float4*)&v01[4] = *(const float4*)(p01 + 4);
    *(float4*)&v10[0] = *(const float4*)p10; *(float4*)&v10[4] = *(const float4*)(p10 + 4);
    *(float4*)&v11[0] = *(const float4*)p11; *(float4*)&v11[4] = *(const float4*)(p11 + 4);
#pragma unroll
    for (int ch = 0; ch < 8; ch++)
        o[ch] = (1.f - wy) * ((1.f - wx) * v00[ch] + wx * v01[ch])
              + wy * ((1.f - wx) * v10[ch] + wx * v11[ch]);
    float* dst = fea_cl + (size_t)idx * 8;
    *(float4*)dst = make_float4(o[0], o[1], o[2], o[3]);
    *(float4*)(dst + 4) = make_float4(o[4], o[5], o[6], o[7]);
}

// ---------------------------------------------------------------------------
// Prep A: guidance NCHW -> channels-last bf16 gT[b][y][x][ci].
// ---------------------------------------------------------------------------
__global__ __launch_bounds__(256) void prep_guidance(const void* __restrict__ g,
                                                     const void* __restrict__ asc,
                                                     unsigned short* __restrict__ gTu) {
    int isbf = detect_bf16(asc);
    int x0 = blockIdx.x * 64;
    int y  = blockIdx.y;
    int b  = blockIdx.z;
    __shared__ unsigned short sh[64][66];
    int tid = threadIdx.x;
#pragma unroll
    for (int it = 0; it < 16; it++) {
        int idx = it * 256 + tid;
        int ci = idx >> 6;
        int xg = idx & 63;
        float v = ldF(g, ((long)(b * CG + ci) * HH + y) * WW + x0 + xg, isbf);
        sh[xg][ci] = f2bfbits(v);
    }
    __syncthreads();
#pragma unroll
    for (int it = 0; it < 8; it++) {
        int idx = it * 256 + tid;
        int xg = idx >> 5;
        int cp = idx & 31;
        unsigned int lo = sh[xg][2 * cp];
        unsigned int hi = sh[xg][2 * cp + 1];
        *(unsigned int*)&gTu[((((long)b * HH + y) * WW + x0 + xg) << 6) + 2 * cp]
            = lo | (hi << 16);
    }
}

// ---------------------------------------------------------------------------
// Prep B: weights -> MFMA B-fragment layout Bp[t][n(32, 24 real)][k'(32)] bf16
// ---------------------------------------------------------------------------
__global__ __launch_bounds__(256) void prep_weights(const void* __restrict__ w,
                                                    const void* __restrict__ asc,
                                                    unsigned short* __restrict__ Bpu) {
    int isbf = detect_bf16(asc);
    int idx = blockIdx.x * 256 + threadIdx.x;
    if (idx >= 18 * 32 * 32) return;
    int t = idx >> 10;
    int r = idx & 1023;
    int n = r >> 5;
    int k = r & 31;
    int tap = t >> 1;
    int ch = t & 1;
    float v = 0.f;
    if (n < NCO)
        v = ldF(w, ((long)n * CG + ch * 32 + k) * 9 + tap, isbf);
    Bpu[idx] = f2bfbits(v);
}

// ---------------------------------------------------------------------------
// Kernel 2 (R4): LDS-staged MFMA conv.
//
// R3 post-mortem: VGPR_Count=52 — the compiler re-sank the 18-fragment
// register prefetch to load-before-use, reproducing the latency serialization
// (88us, MfmaUtil 5%). R4 makes the prefetch structural: block = 64px x 4
// output rows stages its 6 input rows (66px halo, 64ch bf16) from channels-
// last gTu into LDS as ONE linear coalesced copy (3168 float4 loads, ~12 per
// thread, 1 barrier — unlike R2's fused transpose: no conversion, no 2B
// scalar ops, no 12 barriers). 16B blocks XOR-swizzled by (xi&7): stage
// writes contiguous (conflict-free), compute reads 2-way (free, m136).
// Row reuse: A-traffic halved; per wave 144 MFMA : 72 ds_read : 36 global
// B-loads (L1-resident, wave-identical). OOB cells staged as exact zeros ->
// bit-identical to the reference's zero padding; t-ascending per output row
// preserves FP order.
// ---------------------------------------------------------------------------
__global__ __launch_bounds__(256, 4) void conv_mfma3_kernel(const unsigned short* __restrict__ gTu,
                                                            const unsigned short* __restrict__ Bpu,
                                                            const void* __restrict__ bias,
                                                            const void* __restrict__ asc,
                                                            float* __restrict__ oa) {
    int isbf = detect_bf16(asc);
    const int x0 = blockIdx.x * 64;
    const int y0 = blockIdx.y * 4;
    const int b  = blockIdx.z;
    const int tid = threadIdx.x;

    __shared__ unsigned short shA[6 * 66 * 64];   // [row][xi][16B-blk swizzled by xi&7]

    // stage rows y0-1..y0+4, px x0-1..x0+64, 64 ch bf16 (50688 B)
#pragma unroll
    for (int it = 0; it < 13; it++) {
        int s = it * 256 + tid;
        if (s < 3168) {
            int row = s / 528;          // 528 = 66 px * 8 blocks
            int rem = s - row * 528;
            int xi = rem >> 3;
            int blk = rem & 7;
            int y = y0 - 1 + row;
            int x = x0 - 1 + xi;
            int4 v = make_int4(0, 0, 0, 0);
            if (y >= 0 && y < HH && x >= 0 && x < WW)
                v = *(const int4*)(gTu + ((((size_t)b * HH + y) * WW + x) << 6)
                                       + ((blk ^ (xi & 7)) << 3));
            *(int4*)&shA[((row * 66 + xi) << 6) + (blk << 3)] = v;
        }
    }
    __syncthreads();

    const int wid  = tid >> 6;
    const int lane = tid & 63;
    const int m = lane & 15, quad = lane >> 4;

    f32x4 acc0[4], acc1[4];
#pragma unroll
    for (int r = 0; r < 4; r++) {
        acc0[r] = (f32x4){0.f, 0.f, 0.f, 0.f};
        acc1[r] = (f32x4){0.f, 0.f, 0.f, 0.f};
    }

#pragma unroll
    for (int tap = 0; tap < 9; tap++) {
        const int dy = tap / 3, dx = tap % 3;
        const int xi = wid * 16 + m + dx;
#pragma unroll
        for (int h = 0; h < 2; h++) {
            const int t = tap * 2 + h;
            int4 b0i = *(const int4*)(Bpu + ((t * 32 + m) * 32 + quad * 8));
            int4 b1i = *(const int4*)(Bpu + ((t * 32 + 16 + m) * 32 + quad * 8));
            bf16x8 bf0 = __builtin_bit_cast(bf16x8, b0i);
            bf16x8 bf1 = __builtin_bit_cast(bf16x8, b1i);
            const int sw = (((h * 4 + quad) ^ (xi & 7)) << 3);
#pragma unroll
            for (int r = 0; r < 4; r++) {
                int row = r + dy;
                int4 ai = *(const int4*)&shA[(((row * 66 + xi) << 6)) + sw];
                bf16x8 af = __builtin_bit_cast(bf16x8, ai);
                acc0[r] = __builtin_amdgcn_mfma_f32_16x16x32_bf16(af, bf0, acc0[r], 0, 0, 0);
                acc1[r] = __builtin_amdgcn_mfma_f32_16x16x32_bf16(af, bf1, acc1[r], 0, 0, 0);
            }
        }
    }

    const int n = m;
    const int x0w = x0 + wid * 16;
    float bias0 = ldF(bias, n, isbf);
    float bias1 = (n < 8) ? ldF(bias, 16 + n, isbf) : 0.f;
#pragma unroll
    for (int r = 0; r < 4; r++) {
        int yy = y0 + r;
#pragma unroll
        for (int rr = 0; rr < 4; rr++) {
            int px = x0w + quad * 4 + rr;
            float* dst = &oa[(((size_t)b * HH + yy) * WW + px) * NCO];
            dst[n] = acc0[r][rr] + bias0;
            if (n < 8) dst[16 + n] = acc1[r][rr] + bias1;
        }
    }
}

// ---------------------------------------------------------------------------
// Fallback scalar conv (only if ws too small for gTu).
// ---------------------------------------------------------------------------
__global__ __launch_bounds__(256, 4) void conv_fallback(const void* __restrict__ g,
                                                        const void* __restrict__ w,
                                                        const void* __restrict__ bias,
                                                        const void* __restrict__ asc,
                                                        float* __restrict__ oa) {
    int isbf = detect_bf16(asc);
    const int b = blockIdx.z;
    const int i0 = blockIdx.y * 16;
    const int j0 = blockIdx.x * 16;
    const int tx = threadIdx.x & 15;
    const int ty = threadIdx.x >> 4;

    __shared__ float gl[8][18][20];
    __shared__ float wl[8][NCO][10];

    float acc[NCO];
#pragma unroll
    for (int c = 0; c < NCO; c++) acc[c] = ldF(bias, c, isbf);

    for (int ci0 = 0; ci0 < CG; ci0 += 8) {
        __syncthreads();
        for (int idx = threadIdx.x; idx < 8 * NCO * 9; idx += 256) {
            int t = idx % 9;
            int rest = idx / 9;
            int cc = rest & 7;
            int co = rest >> 3;
            wl[cc][co][t] = ldF(w, (long)(co * CG + ci0 + cc) * 9 + t, isbf);
        }
        for (int idx = threadIdx.x; idx < 8 * 18 * 18; idx += 256) {
            int cc = idx / 324;
            int rem = idx - cc * 324;
            int r = rem / 18;
            int c2 = rem - r * 18;
            int gi = i0 - 1 + r;
            int gj = j0 - 1 + c2;
            float v = 0.f;
            if (gi >= 0 && gi < HH && gj >= 0 && gj < WW)
                v = ldF(g, ((long)(b * CG + ci0 + cc) * HH + gi) * WW + gj, isbf);
            gl[cc][r][c2] = v;
        }
        __syncthreads();
#pragma unroll
        for (int cc = 0; cc < 8; cc++) {
            float ga[9];
#pragma unroll
            for (int dy = 0; dy < 3; dy++)
#pragma unroll
                for (int dx = 0; dx < 3; dx++)
                    ga[dy * 3 + dx] = gl[cc][ty + dy][tx + dx];
#pragma unroll 4
            for (int co = 0; co < NCO; co++) {
                float s = 0.f;
#pragma unroll
                for (int t = 0; t < 9; t++)
                    s += wl[cc][co][t] * ga[t];
                acc[co] += s;
            }
        }
    }
    int i = i0 + ty, j = j0 + tx;
    float4* p = (float4*)&oa[(((size_t)b * HH + i) * WW + j) * NCO];
#pragma unroll
    for (int q = 0; q < 6; q++)
        p[q] = make_float4(acc[4 * q], acc[4 * q + 1], acc[4 * q + 2], acc[4 * q + 3]);
}

// ---------------------------------------------------------------------------
// Branchless bilinear, zero outside: clamp indices, mask corner weights.
// ---------------------------------------------------------------------------
__device__ __forceinline__ float bil_zero_f32(const float* __restrict__ img,
                                              float x, float y) {
    float x0f = floorf(x), y0f = floorf(y);
    float wx = x - x0f, wy = y - y0f;
    int x0 = (int)x0f, y0 = (int)y0f;
    int x0c = min(max(x0, 0), WW - 1), x1c = min(max(x0 + 1, 0), WW - 1);
    int y0c = min(max(y0, 0), HH - 1), y1c = min(max(y0 + 1, 0), HH - 1);
    float mx0 = (x0 == x0c) ? 1.f : 0.f;
    float mx1 = (x0 + 1 == x1c) ? 1.f : 0.f;
    float my0 = (y0 == y0c) ? 1.f : 0.f;
    float my1 = (y0 + 1 == y1c) ? 1.f : 0.f;
    const float* r0 = img + (size_t)y0c * WW;
    const float* r1 = img + (size_t)y1c * WW;
    float v00 = r0[x0c], v01 = r0[x1c], v10 = r1[x0c], v11 = r1[x1c];
    return my0 * (1.f - wy) * (mx0 * (1.f - wx) * v00 + mx1 * wx * v01)
         + my1 * wy * (mx0 * (1.f - wx) * v10 + mx1 * wx * v11);
}

__device__ __forceinline__ float bil_zero_poly(const void* __restrict__ img, long base,
                                               float x, float y, int isbf) {
    float x0f = floorf(x), y0f = floorf(y);
    float wx = x - x0f, wy = y - y0f;
    int x0 = (int)x0f, y0 = (int)y0f;
    int x0c = min(max(x0, 0), WW - 1), x1c = min(max(x0 + 1, 0), WW - 1);
    int y0c = min(max(y0, 0), HH - 1), y1c = min(max(y0 + 1, 0), HH - 1);
    float mx0 = (x0 == x0c) ? 1.f : 0.f;
    float mx1 = (x0 + 1 == x1c) ? 1.f : 0.f;
    float my0 = (y0 == y0c) ? 1.f : 0.f;
    float my1 = (y0 + 1 == y1c) ? 1.f : 0.f;
    long r0 = base + (long)y0c * WW;
    long r1 = base + (long)y1c * WW;
    float v00 = ldF(img, r0 + x0c, isbf), v01 = ldF(img, r0 + x1c, isbf);
    float v10 = ldF(img, r1 + x0c, isbf), v11 = ldF(img, r1 + x1c, isbf);
    return my0 * (1.f - wy) * (mx0 * (1.f - wx) * v00 + mx1 * wx * v01)
         + my1 * wy * (mx0 * (1.f - wx) * v10 + mx1 * wx * v11);
}

// ---------------------------------------------------------------------------
// Kernel 3a: source-centric cosine affinity (see R1 notes).
// ---------------------------------------------------------------------------
__global__ __launch_bounds__(256, 4) void cos_kernel(const float* __restrict__ oa,
                                                     const float* __restrict__ fea_cl,
                                                     float* __restrict__ cos_buf) {
    __shared__ float S_lds[64 * 65];
    const int bx = blockIdx.x;   // 0..4 (qj chunk of 64)
    const int pi = blockIdx.y;   // 0..239
    const int b  = blockIdx.z;
    const int tid = threadIdx.x;
    const int qj_l = tid & 63;
    const int cpair = tid >> 6;  // 0..3 -> c in {2cp, 2cp+1}
    const int qj = bx * 64 + qj_l;

    const float* feaB = fea_cl + (size_t)b * HWSZ * 8;
    const float4 ov = *(const float4*)&oa[(((size_t)b * HH + pi) * WW + qj) * NCO + 4 * cpair];

#pragma unroll
    for (int t = 0; t < 2; t++) {
        int c = 2 * cpair + t;
        float ox = (t == 0) ? ov.x : ov.z;
        float oy = (t == 0) ? ov.y : ov.w;
        float add = (c < 4) ? (float)pi : (float)qj;   // wave-uniform branch
        float px = ox + add, py = oy + add;

        float x0f = floorf(px), y0f = floorf(py);
        float wx = px - x0f, wy = py - y0f;
        int x0 = (int)x0f, y0 = (int)y0f;
        int x0c = min(max(x0, 0), WW - 1), x1c = min(max(x0 + 1, 0), WW - 1);
        int y0c = min(max(y0, 0), HH - 1), y1c = min(max(y0 + 1, 0), HH - 1);
        float mx0 = (x0 == x0c) ? 1.f : 0.f;
        float mx1 = (x0 + 1 == x1c) ? 1.f : 0.f;
        float my0 = (y0 == y0c) ? 1.f : 0.f;
        float my1 = (y0 + 1 == y1c) ? 1.f : 0.f;
        float aw = mx0 * (1.f - wx);
        float bw = mx1 * wx;
        float tw = my0 * (1.f - wy);
        float dw = my1 * wy;

        const float* r0 = feaB + (size_t)y0c * WW * 8;
        const float* r1 = feaB + (size_t)y1c * WW * 8;
        float v00[8], v01[8], v10[8], v11[8];
        *(float4*)&v00[0] = *(const float4*)(r0 + x0c * 8);
        *(float4*)&v00[4] = *(const float4*)(r0 + x0c * 8 + 4);
        *(float4*)&v01[0] = *(const float4*)(r0 + x1c * 8);
        *(float4*)&v01[4] = *(const float4*)(r0 + x1c * 8 + 4);
        *(float4*)&v10[0] = *(const float4*)(r1 + x0c * 8);
        *(float4*)&v10[4] = *(const float4*)(r1 + x0c * 8 + 4);
        *(float4*)&v11[0] = *(const float4*)(r1 + x1c * 8);
        *(float4*)&v11[4] = *(const float4*)(r1 + x1c * 8 + 4);

        int base = qj_l * 65 + c * 8;
#pragma unroll
        for (int ch = 0; ch < 8; ch++)
            S_lds[base + ch] = tw * (aw * v00[ch] + bw * v01[ch])
                             + dw * (aw * v10[ch] + bw * v11[ch]);
    }

    __syncthreads();

    if (tid < 64) {
        int g = tid >> 3;       // qj group (8 qj = 8 n-slots)
        int c_img = tid & 7;    // sampled channel / output row band
        int i = c_img * 30 + (pi >> 3);
        int j = (pi & 7) * 40 + bx * 8 + g;
        const float* fp = feaB + ((size_t)i * WW + j) * 8;
        float f[8];
        *(float4*)&f[0] = *(const float4*)fp;
        *(float4*)&f[4] = *(const float4*)(fp + 4);
        float acc[8];
#pragma unroll
        for (int c = 0; c < 8; c++) acc[c] = 0.f;
#pragma unroll
        for (int n = 0; n < 8; n++) {       // ascending n: same FP order as old kernel
            float fn = f[n];
            int rb = (8 * g + n) * 65 + c_img;
#pragma unroll
            for (int c = 0; c < 8; c++)
                acc[c] += fn * S_lds[rb + c * 8];
        }
        float* dst = cos_buf + (((size_t)b * HH + i) * WW + j) * 8;
        *(float4*)dst = make_float4(acc[0], acc[1], acc[2], acc[3]);
        *(float4*)(dst + 4) = make_float4(acc[4], acc[5], acc[6], acc[7]);
    }
}

// ---------------------------------------------------------------------------
// Kernel 3b: per-pixel epilogue.
// ---------------------------------------------------------------------------
__global__ __launch_bounds__(256, 4) void final2_kernel(const float* __restrict__ oa,
                                                        const float* __restrict__ cos_buf,
                                                        const void* __restrict__ conf_in,
                                                        const void* __restrict__ asc_p,
                                                        float* __restrict__ out) {
    int isbf = detect_bf16(asc_p);
    int idx = blockIdx.x * 256 + threadIdx.x;
    if (idx >= BB * HWSZ) return;
    int j = idx % WW;
    int rest = idx / WW;
    int i = rest % HH;
    int b = rest / HH;

    float cos_acc[8];
    {
        const float* cp = cos_buf + (size_t)idx * 8;
        float4 ca = *(const float4*)cp;
        float4 cb = *(const float4*)(cp + 4);
        cos_acc[0] = ca.x; cos_acc[1] = ca.y; cos_acc[2] = ca.z; cos_acc[3] = ca.w;
        cos_acc[4] = cb.x; cos_acc[5] = cb.y; cos_acc[6] = cb.z; cos_acc[7] = cb.w;
    }

    const float4* op = (const float4*)&oa[(((size_t)b * HH + i) * WW + j) * NCO];
    float own[24];
#pragma unroll
    for (int q = 0; q < 6; q++) {
        float4 v = op[q];
        own[4 * q] = v.x; own[4 * q + 1] = v.y; own[4 * q + 2] = v.z; own[4 * q + 3] = v.w;
    }

    float asc = ldF(asc_p, 0, isbf) + 1e-8f;
    long cbase = (long)b * HWSZ;

    float a[8];
    float ssum = 0.f;
#pragma unroll
    for (int c = 0; c < 8; c++) {
        float v = own[16 + c] * cos_acc[c];
        v = tanhf(v) / asc;
        float py2 = own[2 * c] + (float)i;
        float px2 = own[2 * c + 1] + (float)j;
        float cf = bil_zero_poly(conf_in, cbase, px2, py2, isbf);
        v *= cf;
        a[c] = v;
        ssum += fabsf(v);
    }
    ssum += 1e-4f;
    ssum = fmaxf(ssum, 1.0f);
    float inv = 1.0f / ssum;
    float asum = 0.f;
#pragma unroll
    for (int c = 0; c < 8; c++) { a[c] *= inv; asum += a[c]; }
    float aref = 1.0f - asum;

    float vals[9];
#pragma unroll
    for (int c = 0; c < 4; c++) vals[c] = a[c];
    vals[4] = aref;
#pragma unroll
    for (int c = 4; c < 8; c++) vals[c + 1] = a[c];
    float m = vals[0];
#pragma unroll
    for (int k = 1; k < 9; k++) m = fmaxf(m, vals[k]);
    float es = 0.f;
#pragma unroll
    for (int k = 0; k < 9; k++) { vals[k] = __expf(vals[k] - m); es += vals[k]; }
    float ei = 1.0f / es;

    size_t pix = (size_t)i * WW + j;
    size_t base_o = (size_t)b * 18 * HWSZ + pix;
#pragma unroll
    for (int ch = 0; ch < 18; ch++) {
        float v;
        if (ch < 8) v = own[ch];
        else if (ch < 10) v = 0.f;
        else v = own[ch - 2];
        out[base_o + (size_t)ch * HWSZ] = v;
    }
    float* aff_out = out + (size_t)BB * 18 * HWSZ;
    size_t base_a = (size_t)b * 9 * HWSZ + pix;
#pragma unroll
    for (int k = 0; k < 9; k++)
        aff_out[base_a + (size_t)k * HWSZ] = vals[k] * ei;
}

// ---------------------------------------------------------------------------
// OLD monolithic final kernel — emergency fallback only (tiny workspace).
// ---------------------------------------------------------------------------
__global__ __launch_bounds__(256, 4) void final_kernel(const float* __restrict__ oa,
                                                       const float* __restrict__ fea,
                                                       const void* __restrict__ conf_in,
                                                       const void* __restrict__ asc_p,
                                                       float* __restrict__ out) {
    int isbf = detect_bf16(asc_p);
    int idx = blockIdx.x * 256 + threadIdx.x;
    if (idx >= BB * HWSZ) return;
    int j = idx % WW;
    int rest = idx / WW;
    int i = rest % HH;
    int b = rest / HH;

    const float* feaB = fea + (size_t)b * 8 * HWSZ;
    float f[8];
#pragma unroll
    for (int n = 0; n < 8; n++)
        f[n] = feaB[(size_t)n * HWSZ + (size_t)i * WW + j];

    int c_img = i / 30;
    int pi = (i % 30) * 8 + j / 40;
    int pj0 = (j % 40) * 8;
    const float* feaC = feaB + (size_t)c_img * HWSZ;

    float cos_acc[8];
#pragma unroll
    for (int c = 0; c < 8; c++) cos_acc[c] = 0.f;

#pragma unroll 1
    for (int n = 0; n < 8; n++) {
        int qj = pj0 + n;
        const float4* oq = (const float4*)&oa[(((size_t)b * HH + pi) * WW + qj) * NCO];
        float4 o0 = oq[0], o1 = oq[1], o2 = oq[2], o3 = oq[3];
        float off[16] = {o0.x, o0.y, o0.z, o0.w, o1.x, o1.y, o1.z, o1.w,
                         o2.x, o2.y, o2.z, o2.w, o3.x, o3.y, o3.z, o3.w};
        float fn = f[n];
#pragma unroll
        for (int c = 0; c < 8; c++) {
            float add = (c < 4) ? (float)pi : (float)qj;
            float px = off[2 * c] + add;
            float py = off[2 * c + 1] + add;
            cos_acc[c] += fn * bil_zero_f32(feaC, px, py);
        }
    }

    const float4* op = (const float4*)&oa[(((size_t)b * HH + i) * WW + j) * NCO];
    float own[24];
#pragma unroll
    for (int q = 0; q < 6; q++) {
        float4 v = op[q];
        own[4 * q] = v.x; own[4 * q + 1] = v.y; own[4 * q + 2] = v.z; own[4 * q + 3] = v.w;
    }

    float asc = ldF(asc_p, 0, isbf) + 1e-8f;
    long cbase = (long)b * HWSZ;

    float a[8];
    float ssum = 0.f;
#pragma unroll
    for (int c = 0; c < 8; c++) {
        float v = own[16 + c] * cos_acc[c];
        v = tanhf(v) / asc;
        float py2 = own[2 * c] + (float)i;
        float px2 = own[2 * c + 1] + (float)j;
        float cf = bil_zero_poly(conf_in, cbase, px2, py2, isbf);
        v *= cf;
        a[c] = v;
        ssum += fabsf(v);
    }
    ssum += 1e-4f;
    ssum = fmaxf(ssum, 1.0f);
    float inv = 1.0f / ssum;
    float asum = 0.f;
#pragma unroll
    for (int c = 0; c < 8; c++) { a[c] *= inv; asum += a[c]; }
    float aref = 1.0f - asum;

    float vals[9];
#pragma unroll
    for (int c = 0; c < 4; c++) vals[c] = a[c];
    vals[4] = aref;
#pragma unroll
    for (int c = 4; c < 8; c++) vals[c + 1] = a[c];
    float m = vals[0];
#pragma unroll
    for (int k = 1; k < 9; k++) m = fmaxf(m, vals[k]);
    float es = 0.f;
#pragma unroll
    for (int k = 0; k < 9; k++) { vals[k] = __expf(vals[k] - m); es += vals[k]; }
    float ei = 1.0f / es;

    size_t pix = (size_t)i * WW + j;
    size_t base_o = (size_t)b * 18 * HWSZ + pix;
#pragma unroll
    for (int ch = 0; ch < 18; ch++) {
        float v;
        if (ch < 8) v = own[ch];
        else if (ch < 10) v = 0.f;
        else v = own[ch - 2];
        out[base_o + (size_t)ch * HWSZ] = v;
    }
    float* aff_out = out + (size_t)BB * 18 * HWSZ;
    size_t base_a = (size_t)b * 9 * HWSZ + pix;
#pragma unroll
    for (int k = 0; k < 9; k++)
        aff_out[base_a + (size_t)k * HWSZ] = vals[k] * ei;
}

// ---------------------------------------------------------------------------
extern "C" void kernel_launch(void* const* d_in, const int* in_sizes, int n_in,
                              void* d_out, int out_size, void* d_ws, size_t ws_size,
                              hipStream_t stream) {
    const void* guidance = d_in[0];
    const void* gtconf   = d_in[1];
    const void* tgt      = d_in[2];
    const void* conv_w   = d_in[3];
    const void* conv_b   = d_in[4];
    const void* asc      = d_in[5];

    // Workspace layout. The 39.3MB "big" region is time-shared (sequential
    // stream => liveness is disjoint):
    //   tcl  (2.4MB)  live: tgt_cl -> upsample_cl2
    //   gTu  (39.3MB) live: prep_guidance -> conv_mfma3
    //   cosb (9.8MB)  live: cos_kernel -> final2_kernel
    float* oa  = (float*)d_ws;
    float* fea = oa + (size_t)BB * HWSZ * NCO;
    float* big = fea + (size_t)BB * 8 * HWSZ;
    unsigned short* gTu = (unsigned short*)big;
    float* cosb = big;
    float* tcl  = big;
    unsigned short* Bpu = (unsigned short*)((char*)big + (size_t)39321600);
    const size_t ws_full = (size_t)29491200 + 9830400 + 39321600 + 36864;  // 78,680,064
    const size_t ws_mid  = (size_t)29491200 + 9830400 + 9830400;           // 49,152,000
    float* out = (float*)d_out;

    int n_pix = BB * HWSZ;
    int n_tgt = BB * 8 * 120 * 160;

    if (ws_size >= ws_full) {
        tgt_cl_kernel<<<(n_tgt + 255) / 256, 256, 0, stream>>>(tgt, asc, tcl);
        upsample_cl2_kernel<<<(n_pix + 255) / 256, 256, 0, stream>>>(tcl, fea);
        prep_weights<<<72, 256, 0, stream>>>(conv_w, asc, Bpu);
        dim3 pgrid(WW / 64, HH, BB);
        prep_guidance<<<pgrid, 256, 0, stream>>>(guidance, asc, gTu);
        dim3 cgrid(WW / 64, HH / 4, BB);
        conv_mfma3_kernel<<<cgrid, 256, 0, stream>>>(gTu, Bpu, conv_b, asc, oa);
        dim3 ggrid(WW / 64, HH, BB);
        cos_kernel<<<ggrid, 256, 0, stream>>>(oa, fea, cosb);
        final2_kernel<<<(n_pix + 255) / 256, 256, 0, stream>>>(oa, cosb, gtconf, asc, out);
    } else if (ws_size >= ws_mid) {
        // mid path: no gTu; scalar conv + split cos/final2 (tcl aliases cosb).
        tgt_cl_kernel<<<(n_tgt + 255) / 256, 256, 0, stream>>>(tgt, asc, tcl);
        upsample_cl2_kernel<<<(n_pix + 255) / 256, 256, 0, stream>>>(tcl, fea);
        dim3 cgrid(WW / 16, HH / 16, BB);
        conv_fallback<<<cgrid, 256, 0, stream>>>(guidance, conv_w, conv_b, asc, oa);
        dim3 ggrid(WW / 64, HH, BB);
        cos_kernel<<<ggrid, 256, 0, stream>>>(oa, fea, cosb);
        final2_kernel<<<(n_pix + 255) / 256, 256, 0, stream>>>(oa, cosb, gtconf, asc, out);
    } else {
        // --- emergency tiny-workspace path (old monolithic) ---
        int n_up = BB * 8 * HWSZ;
        upsample_kernel<<<(n_up + 255) / 256, 256, 0, stream>>>(tgt, asc, fea);
        dim3 cgrid(WW / 16, HH / 16, BB);
        conv_fallback<<<cgrid, 256, 0, stream>>>(guidance, conv_w, conv_b, asc, oa);
        final_kernel<<<(n_pix + 255) / 256, 256, 0, stream>>>(oa, fea, gtconf, asc, out);
    }
}

// Round 6
// 251.331 us; speedup vs baseline: 1.3964x; 1.0439x over previous
//
#include <hip/hip_runtime.h>
#include <hip/hip_bf16.h>

typedef __hip_bfloat16 bf16;
typedef __bf16 bf16x8 __attribute__((ext_vector_type(8)));
typedef float f32x4 __attribute__((ext_vector_type(4)));

#define BB 4
#define HH 240
#define WW 320
#define CG 64
#define NCO 24
#define HWSZ (HH*WW)

__device__ __forceinline__ float ldF(const void* __restrict__ p, long i, int isbf) {
    if (isbf) return __bfloat162float(((const bf16*)p)[i]);
    return ((const float*)p)[i];
}

__device__ __forceinline__ int detect_bf16(const void* asc) {
    // aff_scale_const == 4.0f: fp32 LE low u16 = 0x0000, bf16 = 0x4080.
    return ((const unsigned short*)asc)[0] != 0;
}

__device__ __forceinline__ unsigned short f2bfbits(float v) {
    bf16 h = __float2bfloat16(v);
    return *(unsigned short*)&h;
}

// load 4 consecutive elements as bf16 bits (fp32 path converts; bf16 path copies)
__device__ __forceinline__ void ld4bf(const void* __restrict__ p, long i, int isbf,
                                      unsigned short* __restrict__ o) {
    if (isbf) {
        ushort4 v = *(const ushort4*)((const unsigned short*)p + i);
        o[0] = v.x; o[1] = v.y; o[2] = v.z; o[3] = v.w;
    } else {
        float4 v = *(const float4*)((const float*)p + i);
        o[0] = f2bfbits(v.x); o[1] = f2bfbits(v.y);
        o[2] = f2bfbits(v.z); o[3] = f2bfbits(v.w);
    }
}

// ---------------------------------------------------------------------------
// Kernel 1 (old, channel-major) : emergency fallback path only
// ---------------------------------------------------------------------------
__global__ __launch_bounds__(256) void upsample_kernel(const void* __restrict__ tin,
                                                       const void* __restrict__ asc,
                                                       float* __restrict__ fea) {
    int isbf = detect_bf16(asc);
    int idx = blockIdx.x * 256 + threadIdx.x;
    if (idx >= BB * 8 * HWSZ) return;
    int j = idx % WW;
    int rest = idx / WW;
    int i = rest % HH;
    int bc = rest / HH;
    float sy = 0.5f * (float)i - 0.25f;
    float sx = 0.5f * (float)j - 0.25f;
    float y0f = floorf(sy), x0f = floorf(sx);
    float wy = sy - y0f, wx = sx - x0f;
    int y0 = (int)y0f, x0 = (int)x0f;
    int y0c = min(max(y0, 0), 119), y1c = min(max(y0 + 1, 0), 119);
    int x0c = min(max(x0, 0), 159), x1c = min(max(x0 + 1, 0), 159);
    long base = (long)bc * 120 * 160;
    float v00 = ldF(tin, base + y0c * 160 + x0c, isbf);
    float v01 = ldF(tin, base + y0c * 160 + x1c, isbf);
    float v10 = ldF(tin, base + y1c * 160 + x0c, isbf);
    float v11 = ldF(tin, base + y1c * 160 + x1c, isbf);
    fea[idx] = (1.f - wy) * ((1.f - wx) * v00 + wx * v01)
             + wy * ((1.f - wx) * v10 + wx * v11);
}

// ---------------------------------------------------------------------------
// Kernel 0: tiny NCHW -> NHWC transpose of tgtimg_fea (2.4 MB; coalesced read)
// ---------------------------------------------------------------------------
__global__ __launch_bounds__(256) void tgt_cl_kernel(const void* __restrict__ tin,
                                                     const void* __restrict__ asc,
                                                     float* __restrict__ tcl) {
    int isbf = detect_bf16(asc);
    int idx = blockIdx.x * 256 + threadIdx.x;
    if (idx >= BB * 8 * 120 * 160) return;
    int x = idx % 160;
    int r = idx / 160;
    int yy = r % 120;
    int rc = r / 120;
    int ch = rc % 8;
    int b = rc / 8;
    float v = ldF(tin, idx, isbf);
    tcl[((((size_t)b * 120 + yy) * 160 + x) << 3) + ch] = v;
}

// ---------------------------------------------------------------------------
// Kernel 1b: upsample from channels-last source -> channels-last dest.
// ---------------------------------------------------------------------------
__global__ __launch_bounds__(256) void upsample_cl2_kernel(const float* __restrict__ tcl,
                                                           float* __restrict__ fea_cl) {
    int idx = blockIdx.x * 256 + threadIdx.x;
    if (idx >= BB * HWSZ) return;
    int j = idx % WW;
    int rest = idx / WW;
    int i = rest % HH;
    int b = rest / HH;
    float sy = 0.5f * (float)i - 0.25f;
    float sx = 0.5f * (float)j - 0.25f;
    float y0f = floorf(sy), x0f = floorf(sx);
    float wy = sy - y0f, wx = sx - x0f;
    int y0 = (int)y0f, x0 = (int)x0f;
    int y0c = min(max(y0, 0), 119), y1c = min(max(y0 + 1, 0), 119);
    int x0c = min(max(x0, 0), 159), x1c = min(max(x0 + 1, 0), 159);

    const float* s = tcl + ((size_t)b * 120 * 160) * 8;
    const float* p00 = s + ((size_t)y0c * 160 + x0c) * 8;
    const float* p01 = s + ((size_t)y0c * 160 + x1c) * 8;
    const float* p10 = s + ((size_t)y1c * 160 + x0c) * 8;
    const float* p11 = s + ((size_t)y1c * 160 + x1c) * 8;
    float v00[8], v01[8], v10[8], v11[8], o[8];
    *(float4*)&v00[0] = *(const float4*)p00; *(float4*)&v00[4] = *(const float4*)(p00 + 4);
    *(float4*)&v01[0] = *(const float4*)p01; *(float4*)&v01[4] = *(const float4*)(p01 + 4);
    *(float4*)&v10[0] = *(const float4*)p10; *(float4*)&v10[4] = *(const float4*)(p10 + 4);
    *(float4*)&v11[0] = *(const float4*)p11; *(float4*)&v11[4] = *(const float4*)(p11 + 4);
#pragma unroll
    for (int ch = 0; ch < 8; ch++)
        o[ch] = (1.f - wy) * ((1.f - wx) * v00[ch] + wx * v01[ch])
              + wy * ((1.f - wx) * v10[ch] + wx * v11[ch]);
    float* dst = fea_cl + (size_t)idx * 8;
    *(float4*)dst = make_float4(o[0], o[1], o[2], o[3]);
    *(float4*)(dst + 4) = make_float4(o[4], o[5], o[6], o[7]);
}

// ---------------------------------------------------------------------------
// Prep A (R6): guidance NCHW -> channels-last bf16 gT[b][y][x][ci], vectorized.
//
// R5 post-mortem: old version was 47us at 1.67 TB/s with ~48 memory
// instructions per thread (scalar 4B loads, 2B LDS writes, u32 stores).
// R6: phase1 loads float4 from ch-pair (2cp,2cp+1), packs to u32, 8x
// ds_write_b32 into sh2[64][33] (bank stride 33 -> <=2-way, free).
// phase2: 4x ds_read_b32 (8 ch of one pixel) + ONE global_store_dwordx4
// (64 lanes contiguous = 1KB/wave). ~14 memory instrs/thread, same bytes.
// ---------------------------------------------------------------------------
__global__ __launch_bounds__(256) void prep_guidance2(const void* __restrict__ g,
                                                      const void* __restrict__ asc,
                                                      unsigned short* __restrict__ gTu) {
    int isbf = detect_bf16(asc);
    const int x0 = blockIdx.x * 64;
    const int y  = blockIdx.y;
    const int b  = blockIdx.z;
    __shared__ unsigned int sh2[64][33];
    const int t = threadIdx.x;

#pragma unroll
    for (int it = 0; it < 2; it++) {
        int cp = it * 16 + (t >> 4);   // channel pair 0..31
        int xq = t & 15;               // 4-px group 0..15
        long base0 = ((long)(b * CG + 2 * cp) * HH + y) * WW + x0 + 4 * xq;
        long base1 = base0 + (long)HH * WW;
        unsigned short lo[4], hi[4];
        ld4bf(g, base0, isbf, lo);
        ld4bf(g, base1, isbf, hi);
#pragma unroll
        for (int k = 0; k < 4; k++)
            sh2[4 * xq + k][cp] = (unsigned int)lo[k] | ((unsigned int)hi[k] << 16);
    }
    __syncthreads();

#pragma unroll
    for (int it = 0; it < 2; it++) {
        int s = it * 256 + t;
        int xg = s >> 3;      // pixel 0..63
        int cb = s & 7;       // 8-channel block 0..7
        int4 v = make_int4((int)sh2[xg][cb * 4 + 0], (int)sh2[xg][cb * 4 + 1],
                           (int)sh2[xg][cb * 4 + 2], (int)sh2[xg][cb * 4 + 3]);
        *(int4*)&gTu[((((long)b * HH + y) * WW + x0 + xg) << 6) + cb * 8] = v;
    }
}

// ---------------------------------------------------------------------------
// Prep B: weights -> MFMA B-fragment layout Bp[t][n(32, 24 real)][k'(32)] bf16
// ---------------------------------------------------------------------------
__global__ __launch_bounds__(256) void prep_weights(const void* __restrict__ w,
                                                    const void* __restrict__ asc,
                                                    unsigned short* __restrict__ Bpu) {
    int isbf = detect_bf16(asc);
    int idx = blockIdx.x * 256 + threadIdx.x;
    if (idx >= 18 * 32 * 32) return;
    int t = idx >> 10;
    int r = idx & 1023;
    int n = r >> 5;
    int k = r & 31;
    int tap = t >> 1;
    int ch = t & 1;
    float v = 0.f;
    if (n < NCO)
        v = ldF(w, ((long)n * CG + ch * 32 + k) * 9 + tap, isbf);
    Bpu[idx] = f2bfbits(v);
}

// ---------------------------------------------------------------------------
// Kernel 2 (R4): LDS-staged MFMA conv. (unchanged — R5 confirmed: out of top-5)
// ---------------------------------------------------------------------------
__global__ __launch_bounds__(256, 4) void conv_mfma3_kernel(const unsigned short* __restrict__ gTu,
                                                            const unsigned short* __restrict__ Bpu,
                                                            const void* __restrict__ bias,
                                                            const void* __restrict__ asc,
                                                            float* __restrict__ oa) {
    int isbf = detect_bf16(asc);
    const int x0 = blockIdx.x * 64;
    const int y0 = blockIdx.y * 4;
    const int b  = blockIdx.z;
    const int tid = threadIdx.x;

    __shared__ unsigned short shA[6 * 66 * 64];   // [row][xi][16B-blk swizzled by xi&7]

    // stage rows y0-1..y0+4, px x0-1..x0+64, 64 ch bf16 (50688 B)
#pragma unroll
    for (int it = 0; it < 13; it++) {
        int s = it * 256 + tid;
        if (s < 3168) {
            int row = s / 528;          // 528 = 66 px * 8 blocks
            int rem = s - row * 528;
            int xi = rem >> 3;
            int blk = rem & 7;
            int y = y0 - 1 + row;
            int x = x0 - 1 + xi;
            int4 v = make_int4(0, 0, 0, 0);
            if (y >= 0 && y < HH && x >= 0 && x < WW)
                v = *(const int4*)(gTu + ((((size_t)b * HH + y) * WW + x) << 6)
                                       + ((blk ^ (xi & 7)) << 3));
            *(int4*)&shA[((row * 66 + xi) << 6) + (blk << 3)] = v;
        }
    }
    __syncthreads();

    const int wid  = tid >> 6;
    const int lane = tid & 63;
    const int m = lane & 15, quad = lane >> 4;

    f32x4 acc0[4], acc1[4];
#pragma unroll
    for (int r = 0; r < 4; r++) {
        acc0[r] = (f32x4){0.f, 0.f, 0.f, 0.f};
        acc1[r] = (f32x4){0.f, 0.f, 0.f, 0.f};
    }

#pragma unroll
    for (int tap = 0; tap < 9; tap++) {
        const int dy = tap / 3, dx = tap % 3;
        const int xi = wid * 16 + m + dx;
#pragma unroll
        for (int h = 0; h < 2; h++) {
            const int t = tap * 2 + h;
            int4 b0i = *(const int4*)(Bpu + ((t * 32 + m) * 32 + quad * 8));
            int4 b1i = *(const int4*)(Bpu + ((t * 32 + 16 + m) * 32 + quad * 8));
            bf16x8 bf0 = __builtin_bit_cast(bf16x8, b0i);
            bf16x8 bf1 = __builtin_bit_cast(bf16x8, b1i);
            const int sw = (((h * 4 + quad) ^ (xi & 7)) << 3);
#pragma unroll
            for (int r = 0; r < 4; r++) {
                int row = r + dy;
                int4 ai = *(const int4*)&shA[(((row * 66 + xi) << 6)) + sw];
                bf16x8 af = __builtin_bit_cast(bf16x8, ai);
                acc0[r] = __builtin_amdgcn_mfma_f32_16x16x32_bf16(af, bf0, acc0[r], 0, 0, 0);
                acc1[r] = __builtin_amdgcn_mfma_f32_16x16x32_bf16(af, bf1, acc1[r], 0, 0, 0);
            }
        }
    }

    const int n = m;
    const int x0w = x0 + wid * 16;
    float bias0 = ldF(bias, n, isbf);
    float bias1 = (n < 8) ? ldF(bias, 16 + n, isbf) : 0.f;
#pragma unroll
    for (int r = 0; r < 4; r++) {
        int yy = y0 + r;
#pragma unroll
        for (int rr = 0; rr < 4; rr++) {
            int px = x0w + quad * 4 + rr;
            float* dst = &oa[(((size_t)b * HH + yy) * WW + px) * NCO];
            dst[n] = acc0[r][rr] + bias0;
            if (n < 8) dst[16 + n] = acc1[r][rr] + bias1;
        }
    }
}

// ---------------------------------------------------------------------------
// Fallback scalar conv (only if ws too small for gTu).
// ---------------------------------------------------------------------------
__global__ __launch_bounds__(256, 4) void conv_fallback(const void* __restrict__ g,
                                                        const void* __restrict__ w,
                                                        const void* __restrict__ bias,
                                                        const void* __restrict__ asc,
                                                        float* __restrict__ oa) {
    int isbf = detect_bf16(asc);
    const int b = blockIdx.z;
    const int i0 = blockIdx.y * 16;
    const int j0 = blockIdx.x * 16;
    const int tx = threadIdx.x & 15;
    const int ty = threadIdx.x >> 4;

    __shared__ float gl[8][18][20];
    __shared__ float wl[8][NCO][10];

    float acc[NCO];
#pragma unroll
    for (int c = 0; c < NCO; c++) acc[c] = ldF(bias, c, isbf);

    for (int ci0 = 0; ci0 < CG; ci0 += 8) {
        __syncthreads();
        for (int idx = threadIdx.x; idx < 8 * NCO * 9; idx += 256) {
            int t = idx % 9;
            int rest = idx / 9;
            int cc = rest & 7;
            int co = rest >> 3;
            wl[cc][co][t] = ldF(w, (long)(co * CG + ci0 + cc) * 9 + t, isbf);
        }
        for (int idx = threadIdx.x; idx < 8 * 18 * 18; idx += 256) {
            int cc = idx / 324;
            int rem = idx - cc * 324;
            int r = rem / 18;
            int c2 = rem - r * 18;
            int gi = i0 - 1 + r;
            int gj = j0 - 1 + c2;
            float v = 0.f;
            if (gi >= 0 && gi < HH && gj >= 0 && gj < WW)
                v = ldF(g, ((long)(b * CG + ci0 + cc) * HH + gi) * WW + gj, isbf);
            gl[cc][r][c2] = v;
        }
        __syncthreads();
#pragma unroll
        for (int cc = 0; cc < 8; cc++) {
            float ga[9];
#pragma unroll
            for (int dy = 0; dy < 3; dy++)
#pragma unroll
                for (int dx = 0; dx < 3; dx++)
                    ga[dy * 3 + dx] = gl[cc][ty + dy][tx + dx];
#pragma unroll 4
            for (int co = 0; co < NCO; co++) {
                float s = 0.f;
#pragma unroll
                for (int t = 0; t < 9; t++)
                    s += wl[cc][co][t] * ga[t];
                acc[co] += s;
            }
        }
    }
    int i = i0 + ty, j = j0 + tx;
    float4* p = (float4*)&oa[(((size_t)b * HH + i) * WW + j) * NCO];
#pragma unroll
    for (int q = 0; q < 6; q++)
        p[q] = make_float4(acc[4 * q], acc[4 * q + 1], acc[4 * q + 2], acc[4 * q + 3]);
}

// ---------------------------------------------------------------------------
// Branchless bilinear, zero outside: clamp indices, mask corner weights.
// ---------------------------------------------------------------------------
__device__ __forceinline__ float bil_zero_f32(const float* __restrict__ img,
                                              float x, float y) {
    float x0f = floorf(x), y0f = floorf(y);
    float wx = x - x0f, wy = y - y0f;
    int x0 = (int)x0f, y0 = (int)y0f;
    int x0c = min(max(x0, 0), WW - 1), x1c = min(max(x0 + 1, 0), WW - 1);
    int y0c = min(max(y0, 0), HH - 1), y1c = min(max(y0 + 1, 0), HH - 1);
    float mx0 = (x0 == x0c) ? 1.f : 0.f;
    float mx1 = (x0 + 1 == x1c) ? 1.f : 0.f;
    float my0 = (y0 == y0c) ? 1.f : 0.f;
    float my1 = (y0 + 1 == y1c) ? 1.f : 0.f;
    const float* r0 = img + (size_t)y0c * WW;
    const float* r1 = img + (size_t)y1c * WW;
    float v00 = r0[x0c], v01 = r0[x1c], v10 = r1[x0c], v11 = r1[x1c];
    return my0 * (1.f - wy) * (mx0 * (1.f - wx) * v00 + mx1 * wx * v01)
         + my1 * wy * (mx0 * (1.f - wx) * v10 + mx1 * wx * v11);
}

__device__ __forceinline__ float bil_zero_poly(const void* __restrict__ img, long base,
                                               float x, float y, int isbf) {
    float x0f = floorf(x), y0f = floorf(y);
    float wx = x - x0f, wy = y - y0f;
    int x0 = (int)x0f, y0 = (int)y0f;
    int x0c = min(max(x0, 0), WW - 1), x1c = min(max(x0 + 1, 0), WW - 1);
    int y0c = min(max(y0, 0), HH - 1), y1c = min(max(y0 + 1, 0), HH - 1);
    float mx0 = (x0 == x0c) ? 1.f : 0.f;
    float mx1 = (x0 + 1 == x1c) ? 1.f : 0.f;
    float my0 = (y0 == y0c) ? 1.f : 0.f;
    float my1 = (y0 + 1 == y1c) ? 1.f : 0.f;
    long r0 = base + (long)y0c * WW;
    long r1 = base + (long)y1c * WW;
    float v00 = ldF(img, r0 + x0c, isbf), v01 = ldF(img, r0 + x1c, isbf);
    float v10 = ldF(img, r1 + x0c, isbf), v11 = ldF(img, r1 + x1c, isbf);
    return my0 * (1.f - wy) * (mx0 * (1.f - wx) * v00 + mx1 * wx * v01)
         + my1 * wy * (mx0 * (1.f - wx) * v10 + mx1 * wx * v11);
}

// ---------------------------------------------------------------------------
// Kernel 3a: source-centric cosine affinity (see R1 notes).
// ---------------------------------------------------------------------------
__global__ __launch_bounds__(256, 4) void cos_kernel(const float* __restrict__ oa,
                                                     const float* __restrict__ fea_cl,
                                                     float* __restrict__ cos_buf) {
    __shared__ float S_lds[64 * 65];
    const int bx = blockIdx.x;   // 0..4 (qj chunk of 64)
    const int pi = blockIdx.y;   // 0..239
    const int b  = blockIdx.z;
    const int tid = threadIdx.x;
    const int qj_l = tid & 63;
    const int cpair = tid >> 6;  // 0..3 -> c in {2cp, 2cp+1}
    const int qj = bx * 64 + qj_l;

    const float* feaB = fea_cl + (size_t)b * HWSZ * 8;
    const float4 ov = *(const float4*)&oa[(((size_t)b * HH + pi) * WW + qj) * NCO + 4 * cpair];

#pragma unroll
    for (int t = 0; t < 2; t++) {
        int c = 2 * cpair + t;
        float ox = (t == 0) ? ov.x : ov.z;
        float oy = (t == 0) ? ov.y : ov.w;
        float add = (c < 4) ? (float)pi : (float)qj;   // wave-uniform branch
        float px = ox + add, py = oy + add;

        float x0f = floorf(px), y0f = floorf(py);
        float wx = px - x0f, wy = py - y0f;
        int x0 = (int)x0f, y0 = (int)y0f;
        int x0c = min(max(x0, 0), WW - 1), x1c = min(max(x0 + 1, 0), WW - 1);
        int y0c = min(max(y0, 0), HH - 1), y1c = min(max(y0 + 1, 0), HH - 1);
        float mx0 = (x0 == x0c) ? 1.f : 0.f;
        float mx1 = (x0 + 1 == x1c) ? 1.f : 0.f;
        float my0 = (y0 == y0c) ? 1.f : 0.f;
        float my1 = (y0 + 1 == y1c) ? 1.f : 0.f;
        float aw = mx0 * (1.f - wx);
        float bw = mx1 * wx;
        float tw = my0 * (1.f - wy);
        float dw = my1 * wy;

        const float* r0 = feaB + (size_t)y0c * WW * 8;
        const float* r1 = feaB + (size_t)y1c * WW * 8;
        float v00[8], v01[8], v10[8], v11[8];
        *(float4*)&v00[0] = *(const float4*)(r0 + x0c * 8);
        *(float4*)&v00[4] = *(const float4*)(r0 + x0c * 8 + 4);
        *(float4*)&v01[0] = *(const float4*)(r0 + x1c * 8);
        *(float4*)&v01[4] = *(const float4*)(r0 + x1c * 8 + 4);
        *(float4*)&v10[0] = *(const float4*)(r1 + x0c * 8);
        *(float4*)&v10[4] = *(const float4*)(r1 + x0c * 8 + 4);
        *(float4*)&v11[0] = *(const float4*)(r1 + x1c * 8);
        *(float4*)&v11[4] = *(const float4*)(r1 + x1c * 8 + 4);

        int base = qj_l * 65 + c * 8;
#pragma unroll
        for (int ch = 0; ch < 8; ch++)
            S_lds[base + ch] = tw * (aw * v00[ch] + bw * v01[ch])
                             + dw * (aw * v10[ch] + bw * v11[ch]);
    }

    __syncthreads();

    if (tid < 64) {
        int g = tid >> 3;       // qj group (8 qj = 8 n-slots)
        int c_img = tid & 7;    // sampled channel / output row band
        int i = c_img * 30 + (pi >> 3);
        int j = (pi & 7) * 40 + bx * 8 + g;
        const float* fp = feaB + ((size_t)i * WW + j) * 8;
        float f[8];
        *(float4*)&f[0] = *(const float4*)fp;
        *(float4*)&f[4] = *(const float4*)(fp + 4);
        float acc[8];
#pragma unroll
        for (int c = 0; c < 8; c++) acc[c] = 0.f;
#pragma unroll
        for (int n = 0; n < 8; n++) {       // ascending n: same FP order as old kernel
            float fn = f[n];
            int rb = (8 * g + n) * 65 + c_img;
#pragma unroll
            for (int c = 0; c < 8; c++)
                acc[c] += fn * S_lds[rb + c * 8];
        }
        float* dst = cos_buf + (((size_t)b * HH + i) * WW + j) * 8;
        *(float4*)dst = make_float4(acc[0], acc[1], acc[2], acc[3]);
        *(float4*)(dst + 4) = make_float4(acc[4], acc[5], acc[6], acc[7]);
    }
}

// ---------------------------------------------------------------------------
// Kernel 3b: per-pixel epilogue.
// ---------------------------------------------------------------------------
__global__ __launch_bounds__(256, 4) void final2_kernel(const float* __restrict__ oa,
                                                        const float* __restrict__ cos_buf,
                                                        const void* __restrict__ conf_in,
                                                        const void* __restrict__ asc_p,
                                                        float* __restrict__ out) {
    int isbf = detect_bf16(asc_p);
    int idx = blockIdx.x * 256 + threadIdx.x;
    if (idx >= BB * HWSZ) return;
    int j = idx % WW;
    int rest = idx / WW;
    int i = rest % HH;
    int b = rest / HH;

    float cos_acc[8];
    {
        const float* cp = cos_buf + (size_t)idx * 8;
        float4 ca = *(const float4*)cp;
        float4 cb = *(const float4*)(cp + 4);
        cos_acc[0] = ca.x; cos_acc[1] = ca.y; cos_acc[2] = ca.z; cos_acc[3] = ca.w;
        cos_acc[4] = cb.x; cos_acc[5] = cb.y; cos_acc[6] = cb.z; cos_acc[7] = cb.w;
    }

    const float4* op = (const float4*)&oa[(((size_t)b * HH + i) * WW + j) * NCO];
    float own[24];
#pragma unroll
    for (int q = 0; q < 6; q++) {
        float4 v = op[q];
        own[4 * q] = v.x; own[4 * q + 1] = v.y; own[4 * q + 2] = v.z; own[4 * q + 3] = v.w;
    }

    float asc = ldF(asc_p, 0, isbf) + 1e-8f;
    long cbase = (long)b * HWSZ;

    float a[8];
    float ssum = 0.f;
#pragma unroll
    for (int c = 0; c < 8; c++) {
        float v = own[16 + c] * cos_acc[c];
        v = tanhf(v) / asc;
        float py2 = own[2 * c] + (float)i;
        float px2 = own[2 * c + 1] + (float)j;
        float cf = bil_zero_poly(conf_in, cbase, px2, py2, isbf);
        v *= cf;
        a[c] = v;
        ssum += fabsf(v);
    }
    ssum += 1e-4f;
    ssum = fmaxf(ssum, 1.0f);
    float inv = 1.0f / ssum;
    float asum = 0.f;
#pragma unroll
    for (int c = 0; c < 8; c++) { a[c] *= inv; asum += a[c]; }
    float aref = 1.0f - asum;

    float vals[9];
#pragma unroll
    for (int c = 0; c < 4; c++) vals[c] = a[c];
    vals[4] = aref;
#pragma unroll
    for (int c = 4; c < 8; c++) vals[c + 1] = a[c];
    float m = vals[0];
#pragma unroll
    for (int k = 1; k < 9; k++) m = fmaxf(m, vals[k]);
    float es = 0.f;
#pragma unroll
    for (int k = 0; k < 9; k++) { vals[k] = __expf(vals[k] - m); es += vals[k]; }
    float ei = 1.0f / es;

    size_t pix = (size_t)i * WW + j;
    size_t base_o = (size_t)b * 18 * HWSZ + pix;
#pragma unroll
    for (int ch = 0; ch < 18; ch++) {
        float v;
        if (ch < 8) v = own[ch];
        else if (ch < 10) v = 0.f;
        else v = own[ch - 2];
        out[base_o + (size_t)ch * HWSZ] = v;
    }
    float* aff_out = out + (size_t)BB * 18 * HWSZ;
    size_t base_a = (size_t)b * 9 * HWSZ + pix;
#pragma unroll
    for (int k = 0; k < 9; k++)
        aff_out[base_a + (size_t)k * HWSZ] = vals[k] * ei;
}

// ---------------------------------------------------------------------------
// OLD monolithic final kernel — emergency fallback only (tiny workspace).
// ---------------------------------------------------------------------------
__global__ __launch_bounds__(256, 4) void final_kernel(const float* __restrict__ oa,
                                                       const float* __restrict__ fea,
                                                       const void* __restrict__ conf_in,
                                                       const void* __restrict__ asc_p,
                                                       float* __restrict__ out) {
    int isbf = detect_bf16(asc_p);
    int idx = blockIdx.x * 256 + threadIdx.x;
    if (idx >= BB * HWSZ) return;
    int j = idx % WW;
    int rest = idx / WW;
    int i = rest % HH;
    int b = rest / HH;

    const float* feaB = fea + (size_t)b * 8 * HWSZ;
    float f[8];
#pragma unroll
    for (int n = 0; n < 8; n++)
        f[n] = feaB[(size_t)n * HWSZ + (size_t)i * WW + j];

    int c_img = i / 30;
    int pi = (i % 30) * 8 + j / 40;
    int pj0 = (j % 40) * 8;
    const float* feaC = feaB + (size_t)c_img * HWSZ;

    float cos_acc[8];
#pragma unroll
    for (int c = 0; c < 8; c++) cos_acc[c] = 0.f;

#pragma unroll 1
    for (int n = 0; n < 8; n++) {
        int qj = pj0 + n;
        const float4* oq = (const float4*)&oa[(((size_t)b * HH + pi) * WW + qj) * NCO];
        float4 o0 = oq[0], o1 = oq[1], o2 = oq[2], o3 = oq[3];
        float off[16] = {o0.x, o0.y, o0.z, o0.w, o1.x, o1.y, o1.z, o1.w,
                         o2.x, o2.y, o2.z, o2.w, o3.x, o3.y, o3.z, o3.w};
        float fn = f[n];
#pragma unroll
        for (int c = 0; c < 8; c++) {
            float add = (c < 4) ? (float)pi : (float)qj;
            float px = off[2 * c] + add;
            float py = off[2 * c + 1] + add;
            cos_acc[c] += fn * bil_zero_f32(feaC, px, py);
        }
    }

    const float4* op = (const float4*)&oa[(((size_t)b * HH + i) * WW + j) * NCO];
    float own[24];
#pragma unroll
    for (int q = 0; q < 6; q++) {
        float4 v = op[q];
        own[4 * q] = v.x; own[4 * q + 1] = v.y; own[4 * q + 2] = v.z; own[4 * q + 3] = v.w;
    }

    float asc = ldF(asc_p, 0, isbf) + 1e-8f;
    long cbase = (long)b * HWSZ;

    float a[8];
    float ssum = 0.f;
#pragma unroll
    for (int c = 0; c < 8; c++) {
        float v = own[16 + c] * cos_acc[c];
        v = tanhf(v) / asc;
        float py2 = own[2 * c] + (float)i;
        float px2 = own[2 * c + 1] + (float)j;
        float cf = bil_zero_poly(conf_in, cbase, px2, py2, isbf);
        v *= cf;
        a[c] = v;
        ssum += fabsf(v);
    }
    ssum += 1e-4f;
    ssum = fmaxf(ssum, 1.0f);
    float inv = 1.0f / ssum;
    float asum = 0.f;
#pragma unroll
    for (int c = 0; c < 8; c++) { a[c] *= inv; asum += a[c]; }
    float aref = 1.0f - asum;

    float vals[9];
#pragma unroll
    for (int c = 0; c < 4; c++) vals[c] = a[c];
    vals[4] = aref;
#pragma unroll
    for (int c = 4; c < 8; c++) vals[c + 1] = a[c];
    float m = vals[0];
#pragma unroll
    for (int k = 1; k < 9; k++) m = fmaxf(m, vals[k]);
    float es = 0.f;
#pragma unroll
    for (int k = 0; k < 9; k++) { vals[k] = __expf(vals[k] - m); es += vals[k]; }
    float ei = 1.0f / es;

    size_t pix = (size_t)i * WW + j;
    size_t base_o = (size_t)b * 18 * HWSZ + pix;
#pragma unroll
    for (int ch = 0; ch < 18; ch++) {
        float v;
        if (ch < 8) v = own[ch];
        else if (ch < 10) v = 0.f;
        else v = own[ch - 2];
        out[base_o + (size_t)ch * HWSZ] = v;
    }
    float* aff_out = out + (size_t)BB * 18 * HWSZ;
    size_t base_a = (size_t)b * 9 * HWSZ + pix;
#pragma unroll
    for (int k = 0; k < 9; k++)
        aff_out[base_a + (size_t)k * HWSZ] = vals[k] * ei;
}

// ---------------------------------------------------------------------------
extern "C" void kernel_launch(void* const* d_in, const int* in_sizes, int n_in,
                              void* d_out, int out_size, void* d_ws, size_t ws_size,
                              hipStream_t stream) {
    const void* guidance = d_in[0];
    const void* gtconf   = d_in[1];
    const void* tgt      = d_in[2];
    const void* conv_w   = d_in[3];
    const void* conv_b   = d_in[4];
    const void* asc      = d_in[5];

    // Workspace layout. The 39.3MB "big" region is time-shared (sequential
    // stream => liveness is disjoint):
    //   tcl  (2.4MB)  live: tgt_cl -> upsample_cl2
    //   gTu  (39.3MB) live: prep_guidance2 -> conv_mfma3
    //   cosb (9.8MB)  live: cos_kernel -> final2_kernel
    float* oa  = (float*)d_ws;
    float* fea = oa + (size_t)BB * HWSZ * NCO;
    float* big = fea + (size_t)BB * 8 * HWSZ;
    unsigned short* gTu = (unsigned short*)big;
    float* cosb = big;
    float* tcl  = big;
    unsigned short* Bpu = (unsigned short*)((char*)big + (size_t)39321600);
    const size_t ws_full = (size_t)29491200 + 9830400 + 39321600 + 36864;  // 78,680,064
    const size_t ws_mid  = (size_t)29491200 + 9830400 + 9830400;           // 49,152,000
    float* out = (float*)d_out;

    int n_pix = BB * HWSZ;
    int n_tgt = BB * 8 * 120 * 160;

    if (ws_size >= ws_full) {
        tgt_cl_kernel<<<(n_tgt + 255) / 256, 256, 0, stream>>>(tgt, asc, tcl);
        upsample_cl2_kernel<<<(n_pix + 255) / 256, 256, 0, stream>>>(tcl, fea);
        prep_weights<<<72, 256, 0, stream>>>(conv_w, asc, Bpu);
        dim3 pgrid(WW / 64, HH, BB);
        prep_guidance2<<<pgrid, 256, 0, stream>>>(guidance, asc, gTu);
        dim3 cgrid(WW / 64, HH / 4, BB);
        conv_mfma3_kernel<<<cgrid, 256, 0, stream>>>(gTu, Bpu, conv_b, asc, oa);
        dim3 ggrid(WW / 64, HH, BB);
        cos_kernel<<<ggrid, 256, 0, stream>>>(oa, fea, cosb);
        final2_kernel<<<(n_pix + 255) / 256, 256, 0, stream>>>(oa, cosb, gtconf, asc, out);
    } else if (ws_size >= ws_mid) {
        // mid path: no gTu; scalar conv + split cos/final2 (tcl aliases cosb).
        tgt_cl_kernel<<<(n_tgt + 255) / 256, 256, 0, stream>>>(tgt, asc, tcl);
        upsample_cl2_kernel<<<(n_pix + 255) / 256, 256, 0, stream>>>(tcl, fea);
        dim3 cgrid(WW / 16, HH / 16, BB);
        conv_fallback<<<cgrid, 256, 0, stream>>>(guidance, conv_w, conv_b, asc, oa);
        dim3 ggrid(WW / 64, HH, BB);
        cos_kernel<<<ggrid, 256, 0, stream>>>(oa, fea, cosb);
        final2_kernel<<<(n_pix + 255) / 256, 256, 0, stream>>>(oa, cosb, gtconf, asc, out);
    } else {
        // --- emergency tiny-workspace path (old monolithic) ---
        int n_up = BB * 8 * HWSZ;
        upsample_kernel<<<(n_up + 255) / 256, 256, 0, stream>>>(tgt, asc, fea);
        dim3 cgrid(WW / 16, HH / 16, BB);
        conv_fallback<<<cgrid, 256, 0, stream>>>(guidance, conv_w, conv_b, asc, oa);
        final_kernel<<<(n_pix + 255) / 256, 256, 0, stream>>>(oa, fea, gtconf, asc, out);
    }
}

// Round 7
// 236.312 us; speedup vs baseline: 1.4852x; 1.0636x over previous
//
#include <hip/hip_runtime.h>
#include <hip/hip_bf16.h>

typedef __hip_bfloat16 bf16;
typedef __bf16 bf16x8 __attribute__((ext_vector_type(8)));
typedef float f32x4 __attribute__((ext_vector_type(4)));

#define BB 4
#define HH 240
#define WW 320
#define CG 64
#define NCO 24
#define HWSZ (HH*WW)

__device__ __forceinline__ float ldF(const void* __restrict__ p, long i, int isbf) {
    if (isbf) return __bfloat162float(((const bf16*)p)[i]);
    return ((const float*)p)[i];
}

__device__ __forceinline__ int detect_bf16(const void* asc) {
    // aff_scale_const == 4.0f: fp32 LE low u16 = 0x0000, bf16 = 0x4080.
    return ((const unsigned short*)asc)[0] != 0;
}

__device__ __forceinline__ unsigned short f2bfbits(float v) {
    bf16 h = __float2bfloat16(v);
    return *(unsigned short*)&h;
}

// load 4 consecutive elements as bf16 bits (fp32 path converts; bf16 path copies)
__device__ __forceinline__ void ld4bf(const void* __restrict__ p, long i, int isbf,
                                      unsigned short* __restrict__ o) {
    if (isbf) {
        ushort4 v = *(const ushort4*)((const unsigned short*)p + i);
        o[0] = v.x; o[1] = v.y; o[2] = v.z; o[3] = v.w;
    } else {
        float4 v = *(const float4*)((const float*)p + i);
        o[0] = f2bfbits(v.x); o[1] = f2bfbits(v.y);
        o[2] = f2bfbits(v.z); o[3] = f2bfbits(v.w);
    }
}

// ---------------------------------------------------------------------------
// Kernel 1 (old, channel-major) : emergency fallback path only
// ---------------------------------------------------------------------------
__global__ __launch_bounds__(256) void upsample_kernel(const void* __restrict__ tin,
                                                       const void* __restrict__ asc,
                                                       float* __restrict__ fea) {
    int isbf = detect_bf16(asc);
    int idx = blockIdx.x * 256 + threadIdx.x;
    if (idx >= BB * 8 * HWSZ) return;
    int j = idx % WW;
    int rest = idx / WW;
    int i = rest % HH;
    int bc = rest / HH;
    float sy = 0.5f * (float)i - 0.25f;
    float sx = 0.5f * (float)j - 0.25f;
    float y0f = floorf(sy), x0f = floorf(sx);
    float wy = sy - y0f, wx = sx - x0f;
    int y0 = (int)y0f, x0 = (int)x0f;
    int y0c = min(max(y0, 0), 119), y1c = min(max(y0 + 1, 0), 119);
    int x0c = min(max(x0, 0), 159), x1c = min(max(x0 + 1, 0), 159);
    long base = (long)bc * 120 * 160;
    float v00 = ldF(tin, base + y0c * 160 + x0c, isbf);
    float v01 = ldF(tin, base + y0c * 160 + x1c, isbf);
    float v10 = ldF(tin, base + y1c * 160 + x0c, isbf);
    float v11 = ldF(tin, base + y1c * 160 + x1c, isbf);
    fea[idx] = (1.f - wy) * ((1.f - wx) * v00 + wx * v01)
             + wy * ((1.f - wx) * v10 + wx * v11);
}

// ---------------------------------------------------------------------------
// Kernel 0: tiny NCHW -> NHWC transpose of tgtimg_fea (2.4 MB; coalesced read)
// ---------------------------------------------------------------------------
__global__ __launch_bounds__(256) void tgt_cl_kernel(const void* __restrict__ tin,
                                                     const void* __restrict__ asc,
                                                     float* __restrict__ tcl) {
    int isbf = detect_bf16(asc);
    int idx = blockIdx.x * 256 + threadIdx.x;
    if (idx >= BB * 8 * 120 * 160) return;
    int x = idx % 160;
    int r = idx / 160;
    int yy = r % 120;
    int rc = r / 120;
    int ch = rc % 8;
    int b = rc / 8;
    float v = ldF(tin, idx, isbf);
    tcl[((((size_t)b * 120 + yy) * 160 + x) << 3) + ch] = v;
}

// ---------------------------------------------------------------------------
// Kernel 1b: upsample from channels-last source -> channels-last dest.
// ---------------------------------------------------------------------------
__global__ __launch_bounds__(256) void upsample_cl2_kernel(const float* __restrict__ tcl,
                                                           float* __restrict__ fea_cl) {
    int idx = blockIdx.x * 256 + threadIdx.x;
    if (idx >= BB * HWSZ) return;
    int j = idx % WW;
    int rest = idx / WW;
    int i = rest % HH;
    int b = rest / HH;
    float sy = 0.5f * (float)i - 0.25f;
    float sx = 0.5f * (float)j - 0.25f;
    float y0f = floorf(sy), x0f = floorf(sx);
    float wy = sy - y0f, wx = sx - x0f;
    int y0 = (int)y0f, x0 = (int)x0f;
    int y0c = min(max(y0, 0), 119), y1c = min(max(y0 + 1, 0), 119);
    int x0c = min(max(x0, 0), 159), x1c = min(max(x0 + 1, 0), 159);

    const float* s = tcl + ((size_t)b * 120 * 160) * 8;
    const float* p00 = s + ((size_t)y0c * 160 + x0c) * 8;
    const float* p01 = s + ((size_t)y0c * 160 + x1c) * 8;
    const float* p10 = s + ((size_t)y1c * 160 + x0c) * 8;
    const float* p11 = s + ((size_t)y1c * 160 + x1c) * 8;
    float v00[8], v01[8], v10[8], v11[8], o[8];
    *(float4*)&v00[0] = *(const float4*)p00; *(float4*)&v00[4] = *(const float4*)(p00 + 4);
    *(float4*)&v01[0] = *(const float4*)p01; *(float4*)&v01[4] = *(const float4*)(p01 + 4);
    *(float4*)&v10[0] = *(const float4*)p10; *(float4*)&v10[4] = *(const float4*)(p10 + 4);
    *(float4*)&v11[0] = *(const float4*)p11; *(float4*)&v11[4] = *(const float4*)(p11 + 4);
#pragma unroll
    for (int ch = 0; ch < 8; ch++)
        o[ch] = (1.f - wy) * ((1.f - wx) * v00[ch] + wx * v01[ch])
              + wy * ((1.f - wx) * v10[ch] + wx * v11[ch]);
    float* dst = fea_cl + (size_t)idx * 8;
    *(float4*)dst = make_float4(o[0], o[1], o[2], o[3]);
    *(float4*)(dst + 4) = make_float4(o[4], o[5], o[6], o[7]);
}

// ---------------------------------------------------------------------------
// Prep A (R6): guidance NCHW -> channels-last bf16 gT[b][y][x][ci], vectorized.
// ---------------------------------------------------------------------------
__global__ __launch_bounds__(256) void prep_guidance2(const void* __restrict__ g,
                                                      const void* __restrict__ asc,
                                                      unsigned short* __restrict__ gTu) {
    int isbf = detect_bf16(asc);
    const int x0 = blockIdx.x * 64;
    const int y  = blockIdx.y;
    const int b  = blockIdx.z;
    __shared__ unsigned int sh2[64][33];
    const int t = threadIdx.x;

#pragma unroll
    for (int it = 0; it < 2; it++) {
        int cp = it * 16 + (t >> 4);   // channel pair 0..31
        int xq = t & 15;               // 4-px group 0..15
        long base0 = ((long)(b * CG + 2 * cp) * HH + y) * WW + x0 + 4 * xq;
        long base1 = base0 + (long)HH * WW;
        unsigned short lo[4], hi[4];
        ld4bf(g, base0, isbf, lo);
        ld4bf(g, base1, isbf, hi);
#pragma unroll
        for (int k = 0; k < 4; k++)
            sh2[4 * xq + k][cp] = (unsigned int)lo[k] | ((unsigned int)hi[k] << 16);
    }
    __syncthreads();

#pragma unroll
    for (int it = 0; it < 2; it++) {
        int s = it * 256 + t;
        int xg = s >> 3;      // pixel 0..63
        int cb = s & 7;       // 8-channel block 0..7
        int4 v = make_int4((int)sh2[xg][cb * 4 + 0], (int)sh2[xg][cb * 4 + 1],
                           (int)sh2[xg][cb * 4 + 2], (int)sh2[xg][cb * 4 + 3]);
        *(int4*)&gTu[((((long)b * HH + y) * WW + x0 + xg) << 6) + cb * 8] = v;
    }
}

// ---------------------------------------------------------------------------
// Prep B: weights -> MFMA B-fragment layout Bp[t][n(32, 24 real)][k'(32)] bf16
// ---------------------------------------------------------------------------
__global__ __launch_bounds__(256) void prep_weights(const void* __restrict__ w,
                                                    const void* __restrict__ asc,
                                                    unsigned short* __restrict__ Bpu) {
    int isbf = detect_bf16(asc);
    int idx = blockIdx.x * 256 + threadIdx.x;
    if (idx >= 18 * 32 * 32) return;
    int t = idx >> 10;
    int r = idx & 1023;
    int n = r >> 5;
    int k = r & 31;
    int tap = t >> 1;
    int ch = t & 1;
    float v = 0.f;
    if (n < NCO)
        v = ldF(w, ((long)n * CG + ch * 32 + k) * 9 + tap, isbf);
    Bpu[idx] = f2bfbits(v);
}

// ---------------------------------------------------------------------------
// Kernel 2 (R7): LDS-staged MFMA conv + direct offset-plane output.
//
// R7: conv already holds acc0+bias (= offset channels 0..15) in registers;
// it now ALSO writes the 16 offset_full planes of `out` (out_ch = n<8?n:n+2;
// zref planes 8,9 are written by final3). To keep the plane stores coalesced
// the results go through reused LDS ([4][16][67] f32, stride 67 => <=2-way)
// and are written 64px-contiguous per instruction. Values bit-identical to
// the oa copy (same fp expression). final3 then drops 16 of 27 plane stores.
// ---------------------------------------------------------------------------
__global__ __launch_bounds__(256, 4) void conv_mfma3_kernel(const unsigned short* __restrict__ gTu,
                                                            const unsigned short* __restrict__ Bpu,
                                                            const void* __restrict__ bias,
                                                            const void* __restrict__ asc,
                                                            float* __restrict__ oa,
                                                            float* __restrict__ out) {
    int isbf = detect_bf16(asc);
    const int x0 = blockIdx.x * 64;
    const int y0 = blockIdx.y * 4;
    const int b  = blockIdx.z;
    const int tid = threadIdx.x;

    __shared__ unsigned short shA[6 * 66 * 64];   // [row][xi][16B-blk swizzled by xi&7]

    // stage rows y0-1..y0+4, px x0-1..x0+64, 64 ch bf16 (50688 B)
#pragma unroll
    for (int it = 0; it < 13; it++) {
        int s = it * 256 + tid;
        if (s < 3168) {
            int row = s / 528;          // 528 = 66 px * 8 blocks
            int rem = s - row * 528;
            int xi = rem >> 3;
            int blk = rem & 7;
            int y = y0 - 1 + row;
            int x = x0 - 1 + xi;
            int4 v = make_int4(0, 0, 0, 0);
            if (y >= 0 && y < HH && x >= 0 && x < WW)
                v = *(const int4*)(gTu + ((((size_t)b * HH + y) * WW + x) << 6)
                                       + ((blk ^ (xi & 7)) << 3));
            *(int4*)&shA[((row * 66 + xi) << 6) + (blk << 3)] = v;
        }
    }
    __syncthreads();

    const int wid  = tid >> 6;
    const int lane = tid & 63;
    const int m = lane & 15, quad = lane >> 4;

    f32x4 acc0[4], acc1[4];
#pragma unroll
    for (int r = 0; r < 4; r++) {
        acc0[r] = (f32x4){0.f, 0.f, 0.f, 0.f};
        acc1[r] = (f32x4){0.f, 0.f, 0.f, 0.f};
    }

#pragma unroll
    for (int tap = 0; tap < 9; tap++) {
        const int dy = tap / 3, dx = tap % 3;
        const int xi = wid * 16 + m + dx;
#pragma unroll
        for (int h = 0; h < 2; h++) {
            const int t = tap * 2 + h;
            int4 b0i = *(const int4*)(Bpu + ((t * 32 + m) * 32 + quad * 8));
            int4 b1i = *(const int4*)(Bpu + ((t * 32 + 16 + m) * 32 + quad * 8));
            bf16x8 bf0 = __builtin_bit_cast(bf16x8, b0i);
            bf16x8 bf1 = __builtin_bit_cast(bf16x8, b1i);
            const int sw = (((h * 4 + quad) ^ (xi & 7)) << 3);
#pragma unroll
            for (int r = 0; r < 4; r++) {
                int row = r + dy;
                int4 ai = *(const int4*)&shA[(((row * 66 + xi) << 6)) + sw];
                bf16x8 af = __builtin_bit_cast(bf16x8, ai);
                acc0[r] = __builtin_amdgcn_mfma_f32_16x16x32_bf16(af, bf0, acc0[r], 0, 0, 0);
                acc1[r] = __builtin_amdgcn_mfma_f32_16x16x32_bf16(af, bf1, acc1[r], 0, 0, 0);
            }
        }
    }

    const int n = m;
    const int x0w = x0 + wid * 16;
    float bias0 = ldF(bias, n, isbf);
    float bias1 = (n < 8) ? ldF(bias, 16 + n, isbf) : 0.f;

    // oa write (all 24 ch) + stage acc0 into reused LDS for coalesced plane-out
    __syncthreads();                    // shA reads done; reuse as float shO
    float* shO = (float*)shA;           // [4 rows][16 n][67] stride pad
#pragma unroll
    for (int r = 0; r < 4; r++) {
        int yy = y0 + r;
#pragma unroll
        for (int rr = 0; rr < 4; rr++) {
            int px = x0w + quad * 4 + rr;
            float v0 = acc0[r][rr] + bias0;
            float* dst = &oa[(((size_t)b * HH + yy) * WW + px) * NCO];
            dst[n] = v0;
            shO[(r * 16 + n) * 67 + (px - x0)] = v0;
            if (n < 8) dst[16 + n] = acc1[r][rr] + bias1;
        }
    }
    __syncthreads();

    // 16 offset planes, coalesced: 4096 floats / 256 thr = 16 stores each
#pragma unroll
    for (int it = 0; it < 16; it++) {
        int s = it * 256 + tid;
        int px = s & 63;
        int rest = s >> 6;
        int nn = rest & 15;
        int r = rest >> 4;
        int och = (nn < 8) ? nn : nn + 2;
        out[(((size_t)b * 18 + och) * HH + (y0 + r)) * WW + x0 + px]
            = shO[(r * 16 + nn) * 67 + px];
    }
}

// ---------------------------------------------------------------------------
// Fallback scalar conv (only if ws too small for gTu).
// ---------------------------------------------------------------------------
__global__ __launch_bounds__(256, 4) void conv_fallback(const void* __restrict__ g,
                                                        const void* __restrict__ w,
                                                        const void* __restrict__ bias,
                                                        const void* __restrict__ asc,
                                                        float* __restrict__ oa) {
    int isbf = detect_bf16(asc);
    const int b = blockIdx.z;
    const int i0 = blockIdx.y * 16;
    const int j0 = blockIdx.x * 16;
    const int tx = threadIdx.x & 15;
    const int ty = threadIdx.x >> 4;

    __shared__ float gl[8][18][20];
    __shared__ float wl[8][NCO][10];

    float acc[NCO];
#pragma unroll
    for (int c = 0; c < NCO; c++) acc[c] = ldF(bias, c, isbf);

    for (int ci0 = 0; ci0 < CG; ci0 += 8) {
        __syncthreads();
        for (int idx = threadIdx.x; idx < 8 * NCO * 9; idx += 256) {
            int t = idx % 9;
            int rest = idx / 9;
            int cc = rest & 7;
            int co = rest >> 3;
            wl[cc][co][t] = ldF(w, (long)(co * CG + ci0 + cc) * 9 + t, isbf);
        }
        for (int idx = threadIdx.x; idx < 8 * 18 * 18; idx += 256) {
            int cc = idx / 324;
            int rem = idx - cc * 324;
            int r = rem / 18;
            int c2 = rem - r * 18;
            int gi = i0 - 1 + r;
            int gj = j0 - 1 + c2;
            float v = 0.f;
            if (gi >= 0 && gi < HH && gj >= 0 && gj < WW)
                v = ldF(g, ((long)(b * CG + ci0 + cc) * HH + gi) * WW + gj, isbf);
            gl[cc][r][c2] = v;
        }
        __syncthreads();
#pragma unroll
        for (int cc = 0; cc < 8; cc++) {
            float ga[9];
#pragma unroll
            for (int dy = 0; dy < 3; dy++)
#pragma unroll
                for (int dx = 0; dx < 3; dx++)
                    ga[dy * 3 + dx] = gl[cc][ty + dy][tx + dx];
#pragma unroll 4
            for (int co = 0; co < NCO; co++) {
                float s = 0.f;
#pragma unroll
                for (int t = 0; t < 9; t++)
                    s += wl[cc][co][t] * ga[t];
                acc[co] += s;
            }
        }
    }
    int i = i0 + ty, j = j0 + tx;
    float4* p = (float4*)&oa[(((size_t)b * HH + i) * WW + j) * NCO];
#pragma unroll
    for (int q = 0; q < 6; q++)
        p[q] = make_float4(acc[4 * q], acc[4 * q + 1], acc[4 * q + 2], acc[4 * q + 3]);
}

// ---------------------------------------------------------------------------
// Branchless bilinear, zero outside: clamp indices, mask corner weights.
// ---------------------------------------------------------------------------
__device__ __forceinline__ float bil_zero_f32(const float* __restrict__ img,
                                              float x, float y) {
    float x0f = floorf(x), y0f = floorf(y);
    float wx = x - x0f, wy = y - y0f;
    int x0 = (int)x0f, y0 = (int)y0f;
    int x0c = min(max(x0, 0), WW - 1), x1c = min(max(x0 + 1, 0), WW - 1);
    int y0c = min(max(y0, 0), HH - 1), y1c = min(max(y0 + 1, 0), HH - 1);
    float mx0 = (x0 == x0c) ? 1.f : 0.f;
    float mx1 = (x0 + 1 == x1c) ? 1.f : 0.f;
    float my0 = (y0 == y0c) ? 1.f : 0.f;
    float my1 = (y0 + 1 == y1c) ? 1.f : 0.f;
    const float* r0 = img + (size_t)y0c * WW;
    const float* r1 = img + (size_t)y1c * WW;
    float v00 = r0[x0c], v01 = r0[x1c], v10 = r1[x0c], v11 = r1[x1c];
    return my0 * (1.f - wy) * (mx0 * (1.f - wx) * v00 + mx1 * wx * v01)
         + my1 * wy * (mx0 * (1.f - wx) * v10 + mx1 * wx * v11);
}

__device__ __forceinline__ float bil_zero_poly(const void* __restrict__ img, long base,
                                               float x, float y, int isbf) {
    float x0f = floorf(x), y0f = floorf(y);
    float wx = x - x0f, wy = y - y0f;
    int x0 = (int)x0f, y0 = (int)y0f;
    int x0c = min(max(x0, 0), WW - 1), x1c = min(max(x0 + 1, 0), WW - 1);
    int y0c = min(max(y0, 0), HH - 1), y1c = min(max(y0 + 1, 0), HH - 1);
    float mx0 = (x0 == x0c) ? 1.f : 0.f;
    float mx1 = (x0 + 1 == x1c) ? 1.f : 0.f;
    float my0 = (y0 == y0c) ? 1.f : 0.f;
    float my1 = (y0 + 1 == y1c) ? 1.f : 0.f;
    long r0 = base + (long)y0c * WW;
    long r1 = base + (long)y1c * WW;
    float v00 = ldF(img, r0 + x0c, isbf), v01 = ldF(img, r0 + x1c, isbf);
    float v10 = ldF(img, r1 + x0c, isbf), v11 = ldF(img, r1 + x1c, isbf);
    return my0 * (1.f - wy) * (mx0 * (1.f - wx) * v00 + mx1 * wx * v01)
         + my1 * wy * (mx0 * (1.f - wx) * v10 + mx1 * wx * v11);
}

// ---------------------------------------------------------------------------
// Kernel 3a (R7): source-centric cosine affinity. Phase 2 now uses all 256
// threads (4 thr/pixel, 2 channels each; float2 stores; n-ascending FP order
// unchanged).
// ---------------------------------------------------------------------------
__global__ __launch_bounds__(256, 4) void cos_kernel(const float* __restrict__ oa,
                                                     const float* __restrict__ fea_cl,
                                                     float* __restrict__ cos_buf) {
    __shared__ float S_lds[64 * 65];
    const int bx = blockIdx.x;   // 0..4 (qj chunk of 64)
    const int pi = blockIdx.y;   // 0..239
    const int b  = blockIdx.z;
    const int tid = threadIdx.x;
    const int qj_l = tid & 63;
    const int cpair = tid >> 6;  // 0..3 -> c in {2cp, 2cp+1}
    const int qj = bx * 64 + qj_l;

    const float* feaB = fea_cl + (size_t)b * HWSZ * 8;
    const float4 ov = *(const float4*)&oa[(((size_t)b * HH + pi) * WW + qj) * NCO + 4 * cpair];

#pragma unroll
    for (int t = 0; t < 2; t++) {
        int c = 2 * cpair + t;
        float ox = (t == 0) ? ov.x : ov.z;
        float oy = (t == 0) ? ov.y : ov.w;
        float add = (c < 4) ? (float)pi : (float)qj;   // wave-uniform branch
        float px = ox + add, py = oy + add;

        float x0f = floorf(px), y0f = floorf(py);
        float wx = px - x0f, wy = py - y0f;
        int x0 = (int)x0f, y0 = (int)y0f;
        int x0c = min(max(x0, 0), WW - 1), x1c = min(max(x0 + 1, 0), WW - 1);
        int y0c = min(max(y0, 0), HH - 1), y1c = min(max(y0 + 1, 0), HH - 1);
        float mx0 = (x0 == x0c) ? 1.f : 0.f;
        float mx1 = (x0 + 1 == x1c) ? 1.f : 0.f;
        float my0 = (y0 == y0c) ? 1.f : 0.f;
        float my1 = (y0 + 1 == y1c) ? 1.f : 0.f;
        float aw = mx0 * (1.f - wx);
        float bw = mx1 * wx;
        float tw = my0 * (1.f - wy);
        float dw = my1 * wy;

        const float* r0 = feaB + (size_t)y0c * WW * 8;
        const float* r1 = feaB + (size_t)y1c * WW * 8;
        float v00[8], v01[8], v10[8], v11[8];
        *(float4*)&v00[0] = *(const float4*)(r0 + x0c * 8);
        *(float4*)&v00[4] = *(const float4*)(r0 + x0c * 8 + 4);
        *(float4*)&v01[0] = *(const float4*)(r0 + x1c * 8);
        *(float4*)&v01[4] = *(const float4*)(r0 + x1c * 8 + 4);
        *(float4*)&v10[0] = *(const float4*)(r1 + x0c * 8);
        *(float4*)&v10[4] = *(const float4*)(r1 + x0c * 8 + 4);
        *(float4*)&v11[0] = *(const float4*)(r1 + x1c * 8);
        *(float4*)&v11[4] = *(const float4*)(r1 + x1c * 8 + 4);

        int base = qj_l * 65 + c * 8;
#pragma unroll
        for (int ch = 0; ch < 8; ch++)
            S_lds[base + ch] = tw * (aw * v00[ch] + bw * v01[ch])
                             + dw * (aw * v10[ch] + bw * v11[ch]);
    }

    __syncthreads();

    {
        int pix = tid >> 2;     // 0..63: (g, c_img)
        int cp  = tid & 3;      // computes c = 2cp, 2cp+1
        int g = pix >> 3;
        int c_img = pix & 7;
        int i = c_img * 30 + (pi >> 3);
        int j = (pi & 7) * 40 + bx * 8 + g;
        const float* fp = feaB + ((size_t)i * WW + j) * 8;
        float f[8];
        *(float4*)&f[0] = *(const float4*)fp;
        *(float4*)&f[4] = *(const float4*)(fp + 4);
        float a0 = 0.f, a1 = 0.f;
        int c0 = 2 * cp;
#pragma unroll
        for (int n = 0; n < 8; n++) {       // ascending n: same FP order
            float fn = f[n];
            int rb = (8 * g + n) * 65 + c_img;
            a0 += fn * S_lds[rb + c0 * 8];
            a1 += fn * S_lds[rb + (c0 + 1) * 8];
        }
        float* dst = cos_buf + (((size_t)b * HH + i) * WW + j) * 8 + c0;
        *(float2*)dst = make_float2(a0, a1);
    }
}

// ---------------------------------------------------------------------------
// Kernel 3b (R7, full path): per-pixel epilogue WITHOUT the 16 offset planes
// (conv writes those). Writes zref planes (8,9) + 9 aff planes only.
// ---------------------------------------------------------------------------
__global__ __launch_bounds__(256, 4) void final3_kernel(const float* __restrict__ oa,
                                                        const float* __restrict__ cos_buf,
                                                        const void* __restrict__ conf_in,
                                                        const void* __restrict__ asc_p,
                                                        float* __restrict__ out) {
    int isbf = detect_bf16(asc_p);
    int idx = blockIdx.x * 256 + threadIdx.x;
    if (idx >= BB * HWSZ) return;
    int j = idx % WW;
    int rest = idx / WW;
    int i = rest % HH;
    int b = rest / HH;

    float cos_acc[8];
    {
        const float* cp = cos_buf + (size_t)idx * 8;
        float4 ca = *(const float4*)cp;
        float4 cb = *(const float4*)(cp + 4);
        cos_acc[0] = ca.x; cos_acc[1] = ca.y; cos_acc[2] = ca.z; cos_acc[3] = ca.w;
        cos_acc[4] = cb.x; cos_acc[5] = cb.y; cos_acc[6] = cb.z; cos_acc[7] = cb.w;
    }

    const float4* op = (const float4*)&oa[(((size_t)b * HH + i) * WW + j) * NCO];
    float own[24];
#pragma unroll
    for (int q = 0; q < 6; q++) {
        float4 v = op[q];
        own[4 * q] = v.x; own[4 * q + 1] = v.y; own[4 * q + 2] = v.z; own[4 * q + 3] = v.w;
    }

    float asc = ldF(asc_p, 0, isbf) + 1e-8f;
    long cbase = (long)b * HWSZ;

    float a[8];
    float ssum = 0.f;
#pragma unroll
    for (int c = 0; c < 8; c++) {
        float v = own[16 + c] * cos_acc[c];
        v = tanhf(v) / asc;
        float py2 = own[2 * c] + (float)i;
        float px2 = own[2 * c + 1] + (float)j;
        float cf = bil_zero_poly(conf_in, cbase, px2, py2, isbf);
        v *= cf;
        a[c] = v;
        ssum += fabsf(v);
    }
    ssum += 1e-4f;
    ssum = fmaxf(ssum, 1.0f);
    float inv = 1.0f / ssum;
    float asum = 0.f;
#pragma unroll
    for (int c = 0; c < 8; c++) { a[c] *= inv; asum += a[c]; }
    float aref = 1.0f - asum;

    float vals[9];
#pragma unroll
    for (int c = 0; c < 4; c++) vals[c] = a[c];
    vals[4] = aref;
#pragma unroll
    for (int c = 4; c < 8; c++) vals[c + 1] = a[c];
    float m = vals[0];
#pragma unroll
    for (int k = 1; k < 9; k++) m = fmaxf(m, vals[k]);
    float es = 0.f;
#pragma unroll
    for (int k = 0; k < 9; k++) { vals[k] = __expf(vals[k] - m); es += vals[k]; }
    float ei = 1.0f / es;

    size_t pix = (size_t)i * WW + j;
    size_t base_o = (size_t)b * 18 * HWSZ + pix;
    out[base_o + (size_t)8 * HWSZ] = 0.f;     // zref planes
    out[base_o + (size_t)9 * HWSZ] = 0.f;
    float* aff_out = out + (size_t)BB * 18 * HWSZ;
    size_t base_a = (size_t)b * 9 * HWSZ + pix;
#pragma unroll
    for (int k = 0; k < 9; k++)
        aff_out[base_a + (size_t)k * HWSZ] = vals[k] * ei;
}

// ---------------------------------------------------------------------------
// Kernel 3b (mid path): full epilogue incl. all 18 offset planes.
// ---------------------------------------------------------------------------
__global__ __launch_bounds__(256, 4) void final2_kernel(const float* __restrict__ oa,
                                                        const float* __restrict__ cos_buf,
                                                        const void* __restrict__ conf_in,
                                                        const void* __restrict__ asc_p,
                                                        float* __restrict__ out) {
    int isbf = detect_bf16(asc_p);
    int idx = blockIdx.x * 256 + threadIdx.x;
    if (idx >= BB * HWSZ) return;
    int j = idx % WW;
    int rest = idx / WW;
    int i = rest % HH;
    int b = rest / HH;

    float cos_acc[8];
    {
        const float* cp = cos_buf + (size_t)idx * 8;
        float4 ca = *(const float4*)cp;
        float4 cb = *(const float4*)(cp + 4);
        cos_acc[0] = ca.x; cos_acc[1] = ca.y; cos_acc[2] = ca.z; cos_acc[3] = ca.w;
        cos_acc[4] = cb.x; cos_acc[5] = cb.y; cos_acc[6] = cb.z; cos_acc[7] = cb.w;
    }

    const float4* op = (const float4*)&oa[(((size_t)b * HH + i) * WW + j) * NCO];
    float own[24];
#pragma unroll
    for (int q = 0; q < 6; q++) {
        float4 v = op[q];
        own[4 * q] = v.x; own[4 * q + 1] = v.y; own[4 * q + 2] = v.z; own[4 * q + 3] = v.w;
    }

    float asc = ldF(asc_p, 0, isbf) + 1e-8f;
    long cbase = (long)b * HWSZ;

    float a[8];
    float ssum = 0.f;
#pragma unroll
    for (int c = 0; c < 8; c++) {
        float v = own[16 + c] * cos_acc[c];
        v = tanhf(v) / asc;
        float py2 = own[2 * c] + (float)i;
        float px2 = own[2 * c + 1] + (float)j;
        float cf = bil_zero_poly(conf_in, cbase, px2, py2, isbf);
        v *= cf;
        a[c] = v;
        ssum += fabsf(v);
    }
    ssum += 1e-4f;
    ssum = fmaxf(ssum, 1.0f);
    float inv = 1.0f / ssum;
    float asum = 0.f;
#pragma unroll
    for (int c = 0; c < 8; c++) { a[c] *= inv; asum += a[c]; }
    float aref = 1.0f - asum;

    float vals[9];
#pragma unroll
    for (int c = 0; c < 4; c++) vals[c] = a[c];
    vals[4] = aref;
#pragma unroll
    for (int c = 4; c < 8; c++) vals[c + 1] = a[c];
    float m = vals[0];
#pragma unroll
    for (int k = 1; k < 9; k++) m = fmaxf(m, vals[k]);
    float es = 0.f;
#pragma unroll
    for (int k = 0; k < 9; k++) { vals[k] = __expf(vals[k] - m); es += vals[k]; }
    float ei = 1.0f / es;

    size_t pix = (size_t)i * WW + j;
    size_t base_o = (size_t)b * 18 * HWSZ + pix;
#pragma unroll
    for (int ch = 0; ch < 18; ch++) {
        float v;
        if (ch < 8) v = own[ch];
        else if (ch < 10) v = 0.f;
        else v = own[ch - 2];
        out[base_o + (size_t)ch * HWSZ] = v;
    }
    float* aff_out = out + (size_t)BB * 18 * HWSZ;
    size_t base_a = (size_t)b * 9 * HWSZ + pix;
#pragma unroll
    for (int k = 0; k < 9; k++)
        aff_out[base_a + (size_t)k * HWSZ] = vals[k] * ei;
}

// ---------------------------------------------------------------------------
// OLD monolithic final kernel — emergency fallback only (tiny workspace).
// ---------------------------------------------------------------------------
__global__ __launch_bounds__(256, 4) void final_kernel(const float* __restrict__ oa,
                                                       const float* __restrict__ fea,
                                                       const void* __restrict__ conf_in,
                                                       const void* __restrict__ asc_p,
                                                       float* __restrict__ out) {
    int isbf = detect_bf16(asc_p);
    int idx = blockIdx.x * 256 + threadIdx.x;
    if (idx >= BB * HWSZ) return;
    int j = idx % WW;
    int rest = idx / WW;
    int i = rest % HH;
    int b = rest / HH;

    const float* feaB = fea + (size_t)b * 8 * HWSZ;
    float f[8];
#pragma unroll
    for (int n = 0; n < 8; n++)
        f[n] = feaB[(size_t)n * HWSZ + (size_t)i * WW + j];

    int c_img = i / 30;
    int pi = (i % 30) * 8 + j / 40;
    int pj0 = (j % 40) * 8;
    const float* feaC = feaB + (size_t)c_img * HWSZ;

    float cos_acc[8];
#pragma unroll
    for (int c = 0; c < 8; c++) cos_acc[c] = 0.f;

#pragma unroll 1
    for (int n = 0; n < 8; n++) {
        int qj = pj0 + n;
        const float4* oq = (const float4*)&oa[(((size_t)b * HH + pi) * WW + qj) * NCO];
        float4 o0 = oq[0], o1 = oq[1], o2 = oq[2], o3 = oq[3];
        float off[16] = {o0.x, o0.y, o0.z, o0.w, o1.x, o1.y, o1.z, o1.w,
                         o2.x, o2.y, o2.z, o2.w, o3.x, o3.y, o3.z, o3.w};
        float fn = f[n];
#pragma unroll
        for (int c = 0; c < 8; c++) {
            float add = (c < 4) ? (float)pi : (float)qj;
            float px = off[2 * c] + add;
            float py = off[2 * c + 1] + add;
            cos_acc[c] += fn * bil_zero_f32(feaC, px, py);
        }
    }

    const float4* op = (const float4*)&oa[(((size_t)b * HH + i) * WW + j) * NCO];
    float own[24];
#pragma unroll
    for (int q = 0; q < 6; q++) {
        float4 v = op[q];
        own[4 * q] = v.x; own[4 * q + 1] = v.y; own[4 * q + 2] = v.z; own[4 * q + 3] = v.w;
    }

    float asc = ldF(asc_p, 0, isbf) + 1e-8f;
    long cbase = (long)b * HWSZ;

    float a[8];
    float ssum = 0.f;
#pragma unroll
    for (int c = 0; c < 8; c++) {
        float v = own[16 + c] * cos_acc[c];
        v = tanhf(v) / asc;
        float py2 = own[2 * c] + (float)i;
        float px2 = own[2 * c + 1] + (float)j;
        float cf = bil_zero_poly(conf_in, cbase, px2, py2, isbf);
        v *= cf;
        a[c] = v;
        ssum += fabsf(v);
    }
    ssum += 1e-4f;
    ssum = fmaxf(ssum, 1.0f);
    float inv = 1.0f / ssum;
    float asum = 0.f;
#pragma unroll
    for (int c = 0; c < 8; c++) { a[c] *= inv; asum += a[c]; }
    float aref = 1.0f - asum;

    float vals[9];
#pragma unroll
    for (int c = 0; c < 4; c++) vals[c] = a[c];
    vals[4] = aref;
#pragma unroll
    for (int c = 4; c < 8; c++) vals[c + 1] = a[c];
    float m = vals[0];
#pragma unroll
    for (int k = 1; k < 9; k++) m = fmaxf(m, vals[k]);
    float es = 0.f;
#pragma unroll
    for (int k = 0; k < 9; k++) { vals[k] = __expf(vals[k] - m); es += vals[k]; }
    float ei = 1.0f / es;

    size_t pix = (size_t)i * WW + j;
    size_t base_o = (size_t)b * 18 * HWSZ + pix;
#pragma unroll
    for (int ch = 0; ch < 18; ch++) {
        float v;
        if (ch < 8) v = own[ch];
        else if (ch < 10) v = 0.f;
        else v = own[ch - 2];
        out[base_o + (size_t)ch * HWSZ] = v;
    }
    float* aff_out = out + (size_t)BB * 18 * HWSZ;
    size_t base_a = (size_t)b * 9 * HWSZ + pix;
#pragma unroll
    for (int k = 0; k < 9; k++)
        aff_out[base_a + (size_t)k * HWSZ] = vals[k] * ei;
}

// ---------------------------------------------------------------------------
extern "C" void kernel_launch(void* const* d_in, const int* in_sizes, int n_in,
                              void* d_out, int out_size, void* d_ws, size_t ws_size,
                              hipStream_t stream) {
    const void* guidance = d_in[0];
    const void* gtconf   = d_in[1];
    const void* tgt      = d_in[2];
    const void* conv_w   = d_in[3];
    const void* conv_b   = d_in[4];
    const void* asc      = d_in[5];

    // Workspace layout. The 39.3MB "big" region is time-shared (sequential
    // stream => liveness is disjoint):
    //   tcl  (2.4MB)  live: tgt_cl -> upsample_cl2
    //   gTu  (39.3MB) live: prep_guidance2 -> conv_mfma3
    //   cosb (9.8MB)  live: cos_kernel -> final3
    float* oa  = (float*)d_ws;
    float* fea = oa + (size_t)BB * HWSZ * NCO;
    float* big = fea + (size_t)BB * 8 * HWSZ;
    unsigned short* gTu = (unsigned short*)big;
    float* cosb = big;
    float* tcl  = big;
    unsigned short* Bpu = (unsigned short*)((char*)big + (size_t)39321600);
    const size_t ws_full = (size_t)29491200 + 9830400 + 39321600 + 36864;  // 78,680,064
    const size_t ws_mid  = (size_t)29491200 + 9830400 + 9830400;           // 49,152,000
    float* out = (float*)d_out;

    int n_pix = BB * HWSZ;
    int n_tgt = BB * 8 * 120 * 160;

    if (ws_size >= ws_full) {
        tgt_cl_kernel<<<(n_tgt + 255) / 256, 256, 0, stream>>>(tgt, asc, tcl);
        upsample_cl2_kernel<<<(n_pix + 255) / 256, 256, 0, stream>>>(tcl, fea);
        prep_weights<<<72, 256, 0, stream>>>(conv_w, asc, Bpu);
        dim3 pgrid(WW / 64, HH, BB);
        prep_guidance2<<<pgrid, 256, 0, stream>>>(guidance, asc, gTu);
        dim3 cgrid(WW / 64, HH / 4, BB);
        conv_mfma3_kernel<<<cgrid, 256, 0, stream>>>(gTu, Bpu, conv_b, asc, oa, out);
        dim3 ggrid(WW / 64, HH, BB);
        cos_kernel<<<ggrid, 256, 0, stream>>>(oa, fea, cosb);
        final3_kernel<<<(n_pix + 255) / 256, 256, 0, stream>>>(oa, cosb, gtconf, asc, out);
    } else if (ws_size >= ws_mid) {
        // mid path: no gTu; scalar conv + split cos/final2 (tcl aliases cosb).
        tgt_cl_kernel<<<(n_tgt + 255) / 256, 256, 0, stream>>>(tgt, asc, tcl);
        upsample_cl2_kernel<<<(n_pix + 255) / 256, 256, 0, stream>>>(tcl, fea);
        dim3 cgrid(WW / 16, HH / 16, BB);
        conv_fallback<<<cgrid, 256, 0, stream>>>(guidance, conv_w, conv_b, asc, oa);
        dim3 ggrid(WW / 64, HH, BB);
        cos_kernel<<<ggrid, 256, 0, stream>>>(oa, fea, cosb);
        final2_kernel<<<(n_pix + 255) / 256, 256, 0, stream>>>(oa, cosb, gtconf, asc, out);
    } else {
        // --- emergency tiny-workspace path (old monolithic) ---
        int n_up = BB * 8 * HWSZ;
        upsample_kernel<<<(n_up + 255) / 256, 256, 0, stream>>>(tgt, asc, fea);
        dim3 cgrid(WW / 16, HH / 16, BB);
        conv_fallback<<<cgrid, 256, 0, stream>>>(guidance, conv_w, conv_b, asc, oa);
        final_kernel<<<(n_pix + 255) / 256, 256, 0, stream>>>(oa, fea, gtconf, asc, out);
    }
}

// Round 8
// 218.425 us; speedup vs baseline: 1.6068x; 1.0819x over previous
//
#include <hip/hip_runtime.h>
#include <hip/hip_bf16.h>

typedef __hip_bfloat16 bf16;
typedef __bf16 bf16x8 __attribute__((ext_vector_type(8)));
typedef float f32x4 __attribute__((ext_vector_type(4)));

#define BB 4
#define HH 240
#define WW 320
#define CG 64
#define NCO 24
#define HWSZ (HH*WW)

__device__ __forceinline__ float ldF(const void* __restrict__ p, long i, int isbf) {
    if (isbf) return __bfloat162float(((const bf16*)p)[i]);
    return ((const float*)p)[i];
}

__device__ __forceinline__ int detect_bf16(const void* asc) {
    // aff_scale_const == 4.0f: fp32 LE low u16 = 0x0000, bf16 = 0x4080.
    return ((const unsigned short*)asc)[0] != 0;
}

__device__ __forceinline__ unsigned short f2bfbits(float v) {
    bf16 h = __float2bfloat16(v);
    return *(unsigned short*)&h;
}

// load 4 consecutive elements as bf16 bits (fp32 path converts; bf16 path copies)
__device__ __forceinline__ void ld4bf(const void* __restrict__ p, long i, int isbf,
                                      unsigned short* __restrict__ o) {
    if (isbf) {
        ushort4 v = *(const ushort4*)((const unsigned short*)p + i);
        o[0] = v.x; o[1] = v.y; o[2] = v.z; o[3] = v.w;
    } else {
        float4 v = *(const float4*)((const float*)p + i);
        o[0] = f2bfbits(v.x); o[1] = f2bfbits(v.y);
        o[2] = f2bfbits(v.z); o[3] = f2bfbits(v.w);
    }
}

// ---------------------------------------------------------------------------
// Kernel 1 (old, channel-major) : emergency fallback path only
// ---------------------------------------------------------------------------
__global__ __launch_bounds__(256) void upsample_kernel(const void* __restrict__ tin,
                                                       const void* __restrict__ asc,
                                                       float* __restrict__ fea) {
    int isbf = detect_bf16(asc);
    int idx = blockIdx.x * 256 + threadIdx.x;
    if (idx >= BB * 8 * HWSZ) return;
    int j = idx % WW;
    int rest = idx / WW;
    int i = rest % HH;
    int bc = rest / HH;
    float sy = 0.5f * (float)i - 0.25f;
    float sx = 0.5f * (float)j - 0.25f;
    float y0f = floorf(sy), x0f = floorf(sx);
    float wy = sy - y0f, wx = sx - x0f;
    int y0 = (int)y0f, x0 = (int)x0f;
    int y0c = min(max(y0, 0), 119), y1c = min(max(y0 + 1, 0), 119);
    int x0c = min(max(x0, 0), 159), x1c = min(max(x0 + 1, 0), 159);
    long base = (long)bc * 120 * 160;
    float v00 = ldF(tin, base + y0c * 160 + x0c, isbf);
    float v01 = ldF(tin, base + y0c * 160 + x1c, isbf);
    float v10 = ldF(tin, base + y1c * 160 + x0c, isbf);
    float v11 = ldF(tin, base + y1c * 160 + x1c, isbf);
    fea[idx] = (1.f - wy) * ((1.f - wx) * v00 + wx * v01)
             + wy * ((1.f - wx) * v10 + wx * v11);
}

// ---------------------------------------------------------------------------
// Kernel 0: tiny NCHW -> NHWC transpose of tgtimg_fea (2.4 MB; coalesced read)
// ---------------------------------------------------------------------------
__global__ __launch_bounds__(256) void tgt_cl_kernel(const void* __restrict__ tin,
                                                     const void* __restrict__ asc,
                                                     float* __restrict__ tcl) {
    int isbf = detect_bf16(asc);
    int idx = blockIdx.x * 256 + threadIdx.x;
    if (idx >= BB * 8 * 120 * 160) return;
    int x = idx % 160;
    int r = idx / 160;
    int yy = r % 120;
    int rc = r / 120;
    int ch = rc % 8;
    int b = rc / 8;
    float v = ldF(tin, idx, isbf);
    tcl[((((size_t)b * 120 + yy) * 160 + x) << 3) + ch] = v;
}

// ---------------------------------------------------------------------------
// Kernel 1b: upsample from channels-last source -> channels-last dest.
// ---------------------------------------------------------------------------
__global__ __launch_bounds__(256) void upsample_cl2_kernel(const float* __restrict__ tcl,
                                                           float* __restrict__ fea_cl) {
    int idx = blockIdx.x * 256 + threadIdx.x;
    if (idx >= BB * HWSZ) return;
    int j = idx % WW;
    int rest = idx / WW;
    int i = rest % HH;
    int b = rest / HH;
    float sy = 0.5f * (float)i - 0.25f;
    float sx = 0.5f * (float)j - 0.25f;
    float y0f = floorf(sy), x0f = floorf(sx);
    float wy = sy - y0f, wx = sx - x0f;
    int y0 = (int)y0f, x0 = (int)x0f;
    int y0c = min(max(y0, 0), 119), y1c = min(max(y0 + 1, 0), 119);
    int x0c = min(max(x0, 0), 159), x1c = min(max(x0 + 1, 0), 159);

    const float* s = tcl + ((size_t)b * 120 * 160) * 8;
    const float* p00 = s + ((size_t)y0c * 160 + x0c) * 8;
    const float* p01 = s + ((size_t)y0c * 160 + x1c) * 8;
    const float* p10 = s + ((size_t)y1c * 160 + x0c) * 8;
    const float* p11 = s + ((size_t)y1c * 160 + x1c) * 8;
    float v00[8], v01[8], v10[8], v11[8], o[8];
    *(float4*)&v00[0] = *(const float4*)p00; *(float4*)&v00[4] = *(const float4*)(p00 + 4);
    *(float4*)&v01[0] = *(const float4*)p01; *(float4*)&v01[4] = *(const float4*)(p01 + 4);
    *(float4*)&v10[0] = *(const float4*)p10; *(float4*)&v10[4] = *(const float4*)(p10 + 4);
    *(float4*)&v11[0] = *(const float4*)p11; *(float4*)&v11[4] = *(const float4*)(p11 + 4);
#pragma unroll
    for (int ch = 0; ch < 8; ch++)
        o[ch] = (1.f - wy) * ((1.f - wx) * v00[ch] + wx * v01[ch])
              + wy * ((1.f - wx) * v10[ch] + wx * v11[ch]);
    float* dst = fea_cl + (size_t)idx * 8;
    *(float4*)dst = make_float4(o[0], o[1], o[2], o[3]);
    *(float4*)(dst + 4) = make_float4(o[4], o[5], o[6], o[7]);
}

// ---------------------------------------------------------------------------
// Prep A (R6): guidance NCHW -> channels-last bf16 gT[b][y][x][ci], vectorized.
// ---------------------------------------------------------------------------
__global__ __launch_bounds__(256) void prep_guidance2(const void* __restrict__ g,
                                                      const void* __restrict__ asc,
                                                      unsigned short* __restrict__ gTu) {
    int isbf = detect_bf16(asc);
    const int x0 = blockIdx.x * 64;
    const int y  = blockIdx.y;
    const int b  = blockIdx.z;
    __shared__ unsigned int sh2[64][33];
    const int t = threadIdx.x;

#pragma unroll
    for (int it = 0; it < 2; it++) {
        int cp = it * 16 + (t >> 4);   // channel pair 0..31
        int xq = t & 15;               // 4-px group 0..15
        long base0 = ((long)(b * CG + 2 * cp) * HH + y) * WW + x0 + 4 * xq;
        long base1 = base0 + (long)HH * WW;
        unsigned short lo[4], hi[4];
        ld4bf(g, base0, isbf, lo);
        ld4bf(g, base1, isbf, hi);
#pragma unroll
        for (int k = 0; k < 4; k++)
            sh2[4 * xq + k][cp] = (unsigned int)lo[k] | ((unsigned int)hi[k] << 16);
    }
    __syncthreads();

#pragma unroll
    for (int it = 0; it < 2; it++) {
        int s = it * 256 + t;
        int xg = s >> 3;      // pixel 0..63
        int cb = s & 7;       // 8-channel block 0..7
        int4 v = make_int4((int)sh2[xg][cb * 4 + 0], (int)sh2[xg][cb * 4 + 1],
                           (int)sh2[xg][cb * 4 + 2], (int)sh2[xg][cb * 4 + 3]);
        *(int4*)&gTu[((((long)b * HH + y) * WW + x0 + xg) << 6) + cb * 8] = v;
    }
}

// ---------------------------------------------------------------------------
// Prep B: weights -> MFMA B-fragment layout Bp[t][n(32, 24 real)][k'(32)] bf16
// ---------------------------------------------------------------------------
__global__ __launch_bounds__(256) void prep_weights(const void* __restrict__ w,
                                                    const void* __restrict__ asc,
                                                    unsigned short* __restrict__ Bpu) {
    int isbf = detect_bf16(asc);
    int idx = blockIdx.x * 256 + threadIdx.x;
    if (idx >= 18 * 32 * 32) return;
    int t = idx >> 10;
    int r = idx & 1023;
    int n = r >> 5;
    int k = r & 31;
    int tap = t >> 1;
    int ch = t & 1;
    float v = 0.f;
    if (n < NCO)
        v = ldF(w, ((long)n * CG + ch * 32 + k) * 9 + tap, isbf);
    Bpu[idx] = f2bfbits(v);
}

// ---------------------------------------------------------------------------
// Kernel 2 (R8): LDS-staged MFMA conv + offset planes + FUSED cos affinity.
//
// R8 fusion rationale: this block's shO LDS already holds the 16 offset
// channels for source rows (pi=y0..y0+3, qj=x0..x0+63) — exactly cos's only
// oa dependency. The cos reduce is block-self-contained (outputs (i,j) with
// pi in rows, pj0 in x-range need only in-block qj groups). Per row r:
//   phase1: 512 samples (64 qj x 8 c), offsets from shO, 8x float4 fea
//           gathers -> S[qj][c][ch] (16.6 KB LDS reused per row, stride 65)
//   reduce: 4 thr/px, n-ascending (FP order identical to R7 cos), -> cosb.
// Unlike R2's failed fusion: LDS stays 50.7 KB (S+shO fit in dead shA),
// occupancy unchanged (3/CU), phases are chunky (16 float4/thread/barrier).
// ---------------------------------------------------------------------------
__global__ __launch_bounds__(256, 4) void conv_mfma4_kernel(const unsigned short* __restrict__ gTu,
                                                            const unsigned short* __restrict__ Bpu,
                                                            const void* __restrict__ bias,
                                                            const void* __restrict__ asc,
                                                            const float* __restrict__ fea_cl,
                                                            float* __restrict__ oa,
                                                            float* __restrict__ cosb,
                                                            float* __restrict__ out) {
    int isbf = detect_bf16(asc);
    const int x0 = blockIdx.x * 64;
    const int y0 = blockIdx.y * 4;
    const int b  = blockIdx.z;
    const int tid = threadIdx.x;
    const int bx = blockIdx.x;

    __shared__ unsigned short shA[6 * 66 * 64];   // 50688 B union:
    float* shO = (float*)shA;                     //   [4][16][67] f32 = 17152 B
    float* S   = (float*)((char*)shA + 17408);    //   [64][65] f32  = 16640 B

    // ---- stage rows y0-1..y0+4, px x0-1..x0+64, 64 ch bf16 (50688 B) ----
#pragma unroll
    for (int it = 0; it < 13; it++) {
        int s = it * 256 + tid;
        if (s < 3168) {
            int row = s / 528;          // 528 = 66 px * 8 blocks
            int rem = s - row * 528;
            int xi = rem >> 3;
            int blk = rem & 7;
            int y = y0 - 1 + row;
            int x = x0 - 1 + xi;
            int4 v = make_int4(0, 0, 0, 0);
            if (y >= 0 && y < HH && x >= 0 && x < WW)
                v = *(const int4*)(gTu + ((((size_t)b * HH + y) * WW + x) << 6)
                                       + ((blk ^ (xi & 7)) << 3));
            *(int4*)&shA[((row * 66 + xi) << 6) + (blk << 3)] = v;
        }
    }
    __syncthreads();

    const int wid  = tid >> 6;
    const int lane = tid & 63;
    const int m = lane & 15, quad = lane >> 4;

    f32x4 acc0[4], acc1[4];
#pragma unroll
    for (int r = 0; r < 4; r++) {
        acc0[r] = (f32x4){0.f, 0.f, 0.f, 0.f};
        acc1[r] = (f32x4){0.f, 0.f, 0.f, 0.f};
    }

#pragma unroll
    for (int tap = 0; tap < 9; tap++) {
        const int dy = tap / 3, dx = tap % 3;
        const int xi = wid * 16 + m + dx;
#pragma unroll
        for (int h = 0; h < 2; h++) {
            const int t = tap * 2 + h;
            int4 b0i = *(const int4*)(Bpu + ((t * 32 + m) * 32 + quad * 8));
            int4 b1i = *(const int4*)(Bpu + ((t * 32 + 16 + m) * 32 + quad * 8));
            bf16x8 bf0 = __builtin_bit_cast(bf16x8, b0i);
            bf16x8 bf1 = __builtin_bit_cast(bf16x8, b1i);
            const int sw = (((h * 4 + quad) ^ (xi & 7)) << 3);
#pragma unroll
            for (int r = 0; r < 4; r++) {
                int row = r + dy;
                int4 ai = *(const int4*)&shA[(((row * 66 + xi) << 6)) + sw];
                bf16x8 af = __builtin_bit_cast(bf16x8, ai);
                acc0[r] = __builtin_amdgcn_mfma_f32_16x16x32_bf16(af, bf0, acc0[r], 0, 0, 0);
                acc1[r] = __builtin_amdgcn_mfma_f32_16x16x32_bf16(af, bf1, acc1[r], 0, 0, 0);
            }
        }
    }

    const int n = m;
    const int x0w = x0 + wid * 16;
    float bias0 = ldF(bias, n, isbf);
    float bias1 = (n < 8) ? ldF(bias, 16 + n, isbf) : 0.f;

    // ---- oa write (all 24 ch) + stage acc0 into shO ----
    __syncthreads();                    // shA reads done; reuse as shO/S
#pragma unroll
    for (int r = 0; r < 4; r++) {
        int yy = y0 + r;
#pragma unroll
        for (int rr = 0; rr < 4; rr++) {
            int px = x0w + quad * 4 + rr;
            float v0 = acc0[r][rr] + bias0;
            float* dst = &oa[(((size_t)b * HH + yy) * WW + px) * NCO];
            dst[n] = v0;
            shO[(r * 16 + n) * 67 + (px - x0)] = v0;
            if (n < 8) dst[16 + n] = acc1[r][rr] + bias1;
        }
    }
    __syncthreads();

    // ---- 16 offset planes, coalesced (reads shO) ----
#pragma unroll
    for (int it = 0; it < 16; it++) {
        int s = it * 256 + tid;
        int px = s & 63;
        int rest = s >> 6;
        int nn = rest & 15;
        int r = rest >> 4;
        int och = (nn < 8) ? nn : nn + 2;
        out[(((size_t)b * 18 + och) * HH + (y0 + r)) * WW + x0 + px]
            = shO[(r * 16 + nn) * 67 + px];
    }

    // ---- fused cos: per source row r, phase1 gather -> S, then reduce ----
    const float* feaB = fea_cl + (size_t)b * HWSZ * 8;
#pragma unroll 1
    for (int r = 0; r < 4; r++) {
        const int pi = y0 + r;
#pragma unroll
        for (int k = 0; k < 2; k++) {
            int s = k * 256 + tid;
            int c = s >> 6;            // 0..7 (wave-uniform)
            int qj_l = s & 63;
            int qj = x0 + qj_l;
            float ox = shO[(r * 16 + 2 * c) * 67 + qj_l];
            float oy = shO[(r * 16 + 2 * c + 1) * 67 + qj_l];
            float add = (c < 4) ? (float)pi : (float)qj;
            float px = ox + add, py = oy + add;

            float x0f = floorf(px), y0f = floorf(py);
            float wx = px - x0f, wy = py - y0f;
            int xx0 = (int)x0f, yy0 = (int)y0f;
            int x0c = min(max(xx0, 0), WW - 1), x1c = min(max(xx0 + 1, 0), WW - 1);
            int y0c = min(max(yy0, 0), HH - 1), y1c = min(max(yy0 + 1, 0), HH - 1);
            float mx0 = (xx0 == x0c) ? 1.f : 0.f;
            float mx1 = (xx0 + 1 == x1c) ? 1.f : 0.f;
            float my0 = (yy0 == y0c) ? 1.f : 0.f;
            float my1 = (yy0 + 1 == y1c) ? 1.f : 0.f;
            float aw = mx0 * (1.f - wx);
            float bw = mx1 * wx;
            float tw = my0 * (1.f - wy);
            float dw = my1 * wy;

            const float* r0 = feaB + (size_t)y0c * WW * 8;
            const float* r1 = feaB + (size_t)y1c * WW * 8;
            float v00[8], v01[8], v10[8], v11[8];
            *(float4*)&v00[0] = *(const float4*)(r0 + x0c * 8);
            *(float4*)&v00[4] = *(const float4*)(r0 + x0c * 8 + 4);
            *(float4*)&v01[0] = *(const float4*)(r0 + x1c * 8);
            *(float4*)&v01[4] = *(const float4*)(r0 + x1c * 8 + 4);
            *(float4*)&v10[0] = *(const float4*)(r1 + x0c * 8);
            *(float4*)&v10[4] = *(const float4*)(r1 + x0c * 8 + 4);
            *(float4*)&v11[0] = *(const float4*)(r1 + x1c * 8);
            *(float4*)&v11[4] = *(const float4*)(r1 + x1c * 8 + 4);

            int base = qj_l * 65 + c * 8;
#pragma unroll
            for (int ch = 0; ch < 8; ch++)
                S[base + ch] = tw * (aw * v00[ch] + bw * v01[ch])
                             + dw * (aw * v10[ch] + bw * v11[ch]);
        }
        __syncthreads();

        {
            int pix = tid >> 2;     // 0..63: (g, c_img)
            int cp  = tid & 3;      // computes c = 2cp, 2cp+1
            int g = pix >> 3;
            int c_img = pix & 7;
            int i = c_img * 30 + (pi >> 3);
            int j = (pi & 7) * 40 + bx * 8 + g;
            const float* fp = feaB + ((size_t)i * WW + j) * 8;
            float f[8];
            *(float4*)&f[0] = *(const float4*)fp;
            *(float4*)&f[4] = *(const float4*)(fp + 4);
            float a0 = 0.f, a1 = 0.f;
            int c0 = 2 * cp;
#pragma unroll
            for (int nn = 0; nn < 8; nn++) {   // ascending n: same FP order
                float fn = f[nn];
                int rb = (8 * g + nn) * 65 + c_img;
                a0 += fn * S[rb + c0 * 8];
                a1 += fn * S[rb + (c0 + 1) * 8];
            }
            float* dst = cosb + (((size_t)b * HH + i) * WW + j) * 8 + c0;
            *(float2*)dst = make_float2(a0, a1);
        }
        __syncthreads();
    }
}

// ---------------------------------------------------------------------------
// Fallback scalar conv (only if ws too small for gTu).
// ---------------------------------------------------------------------------
__global__ __launch_bounds__(256, 4) void conv_fallback(const void* __restrict__ g,
                                                        const void* __restrict__ w,
                                                        const void* __restrict__ bias,
                                                        const void* __restrict__ asc,
                                                        float* __restrict__ oa) {
    int isbf = detect_bf16(asc);
    const int b = blockIdx.z;
    const int i0 = blockIdx.y * 16;
    const int j0 = blockIdx.x * 16;
    const int tx = threadIdx.x & 15;
    const int ty = threadIdx.x >> 4;

    __shared__ float gl[8][18][20];
    __shared__ float wl[8][NCO][10];

    float acc[NCO];
#pragma unroll
    for (int c = 0; c < NCO; c++) acc[c] = ldF(bias, c, isbf);

    for (int ci0 = 0; ci0 < CG; ci0 += 8) {
        __syncthreads();
        for (int idx = threadIdx.x; idx < 8 * NCO * 9; idx += 256) {
            int t = idx % 9;
            int rest = idx / 9;
            int cc = rest & 7;
            int co = rest >> 3;
            wl[cc][co][t] = ldF(w, (long)(co * CG + ci0 + cc) * 9 + t, isbf);
        }
        for (int idx = threadIdx.x; idx < 8 * 18 * 18; idx += 256) {
            int cc = idx / 324;
            int rem = idx - cc * 324;
            int r = rem / 18;
            int c2 = rem - r * 18;
            int gi = i0 - 1 + r;
            int gj = j0 - 1 + c2;
            float v = 0.f;
            if (gi >= 0 && gi < HH && gj >= 0 && gj < WW)
                v = ldF(g, ((long)(b * CG + ci0 + cc) * HH + gi) * WW + gj, isbf);
            gl[cc][r][c2] = v;
        }
        __syncthreads();
#pragma unroll
        for (int cc = 0; cc < 8; cc++) {
            float ga[9];
#pragma unroll
            for (int dy = 0; dy < 3; dy++)
#pragma unroll
                for (int dx = 0; dx < 3; dx++)
                    ga[dy * 3 + dx] = gl[cc][ty + dy][tx + dx];
#pragma unroll 4
            for (int co = 0; co < NCO; co++) {
                float s = 0.f;
#pragma unroll
                for (int t = 0; t < 9; t++)
                    s += wl[cc][co][t] * ga[t];
                acc[co] += s;
            }
        }
    }
    int i = i0 + ty, j = j0 + tx;
    float4* p = (float4*)&oa[(((size_t)b * HH + i) * WW + j) * NCO];
#pragma unroll
    for (int q = 0; q < 6; q++)
        p[q] = make_float4(acc[4 * q], acc[4 * q + 1], acc[4 * q + 2], acc[4 * q + 3]);
}

// ---------------------------------------------------------------------------
// Branchless bilinear, zero outside: clamp indices, mask corner weights.
// ---------------------------------------------------------------------------
__device__ __forceinline__ float bil_zero_f32(const float* __restrict__ img,
                                              float x, float y) {
    float x0f = floorf(x), y0f = floorf(y);
    float wx = x - x0f, wy = y - y0f;
    int x0 = (int)x0f, y0 = (int)y0f;
    int x0c = min(max(x0, 0), WW - 1), x1c = min(max(x0 + 1, 0), WW - 1);
    int y0c = min(max(y0, 0), HH - 1), y1c = min(max(y0 + 1, 0), HH - 1);
    float mx0 = (x0 == x0c) ? 1.f : 0.f;
    float mx1 = (x0 + 1 == x1c) ? 1.f : 0.f;
    float my0 = (y0 == y0c) ? 1.f : 0.f;
    float my1 = (y0 + 1 == y1c) ? 1.f : 0.f;
    const float* r0 = img + (size_t)y0c * WW;
    const float* r1 = img + (size_t)y1c * WW;
    float v00 = r0[x0c], v01 = r0[x1c], v10 = r1[x0c], v11 = r1[x1c];
    return my0 * (1.f - wy) * (mx0 * (1.f - wx) * v00 + mx1 * wx * v01)
         + my1 * wy * (mx0 * (1.f - wx) * v10 + mx1 * wx * v11);
}

__device__ __forceinline__ float bil_zero_poly(const void* __restrict__ img, long base,
                                               float x, float y, int isbf) {
    float x0f = floorf(x), y0f = floorf(y);
    float wx = x - x0f, wy = y - y0f;
    int x0 = (int)x0f, y0 = (int)y0f;
    int x0c = min(max(x0, 0), WW - 1), x1c = min(max(x0 + 1, 0), WW - 1);
    int y0c = min(max(y0, 0), HH - 1), y1c = min(max(y0 + 1, 0), HH - 1);
    float mx0 = (x0 == x0c) ? 1.f : 0.f;
    float mx1 = (x0 + 1 == x1c) ? 1.f : 0.f;
    float my0 = (y0 == y0c) ? 1.f : 0.f;
    float my1 = (y0 + 1 == y1c) ? 1.f : 0.f;
    long r0 = base + (long)y0c * WW;
    long r1 = base + (long)y1c * WW;
    float v00 = ldF(img, r0 + x0c, isbf), v01 = ldF(img, r0 + x1c, isbf);
    float v10 = ldF(img, r1 + x0c, isbf), v11 = ldF(img, r1 + x1c, isbf);
    return my0 * (1.f - wy) * (mx0 * (1.f - wx) * v00 + mx1 * wx * v01)
         + my1 * wy * (mx0 * (1.f - wx) * v10 + mx1 * wx * v11);
}

// ---------------------------------------------------------------------------
// Kernel 3a (mid path only): source-centric cosine affinity.
// ---------------------------------------------------------------------------
__global__ __launch_bounds__(256, 4) void cos_kernel(const float* __restrict__ oa,
                                                     const float* __restrict__ fea_cl,
                                                     float* __restrict__ cos_buf) {
    __shared__ float S_lds[64 * 65];
    const int bx = blockIdx.x;   // 0..4 (qj chunk of 64)
    const int pi = blockIdx.y;   // 0..239
    const int b  = blockIdx.z;
    const int tid = threadIdx.x;
    const int qj_l = tid & 63;
    const int cpair = tid >> 6;  // 0..3 -> c in {2cp, 2cp+1}
    const int qj = bx * 64 + qj_l;

    const float* feaB = fea_cl + (size_t)b * HWSZ * 8;
    const float4 ov = *(const float4*)&oa[(((size_t)b * HH + pi) * WW + qj) * NCO + 4 * cpair];

#pragma unroll
    for (int t = 0; t < 2; t++) {
        int c = 2 * cpair + t;
        float ox = (t == 0) ? ov.x : ov.z;
        float oy = (t == 0) ? ov.y : ov.w;
        float add = (c < 4) ? (float)pi : (float)qj;   // wave-uniform branch
        float px = ox + add, py = oy + add;

        float x0f = floorf(px), y0f = floorf(py);
        float wx = px - x0f, wy = py - y0f;
        int x0 = (int)x0f, y0 = (int)y0f;
        int x0c = min(max(x0, 0), WW - 1), x1c = min(max(x0 + 1, 0), WW - 1);
        int y0c = min(max(y0, 0), HH - 1), y1c = min(max(y0 + 1, 0), HH - 1);
        float mx0 = (x0 == x0c) ? 1.f : 0.f;
        float mx1 = (x0 + 1 == x1c) ? 1.f : 0.f;
        float my0 = (y0 == y0c) ? 1.f : 0.f;
        float my1 = (y0 + 1 == y1c) ? 1.f : 0.f;
        float aw = mx0 * (1.f - wx);
        float bw = mx1 * wx;
        float tw = my0 * (1.f - wy);
        float dw = my1 * wy;

        const float* r0 = feaB + (size_t)y0c * WW * 8;
        const float* r1 = feaB + (size_t)y1c * WW * 8;
        float v00[8], v01[8], v10[8], v11[8];
        *(float4*)&v00[0] = *(const float4*)(r0 + x0c * 8);
        *(float4*)&v00[4] = *(const float4*)(r0 + x0c * 8 + 4);
        *(float4*)&v01[0] = *(const float4*)(r0 + x1c * 8);
        *(float4*)&v01[4] = *(const float4*)(r0 + x1c * 8 + 4);
        *(float4*)&v10[0] = *(const float4*)(r1 + x0c * 8);
        *(float4*)&v10[4] = *(const float4*)(r1 + x0c * 8 + 4);
        *(float4*)&v11[0] = *(const float4*)(r1 + x1c * 8);
        *(float4*)&v11[4] = *(const float4*)(r1 + x1c * 8 + 4);

        int base = qj_l * 65 + c * 8;
#pragma unroll
        for (int ch = 0; ch < 8; ch++)
            S_lds[base + ch] = tw * (aw * v00[ch] + bw * v01[ch])
                             + dw * (aw * v10[ch] + bw * v11[ch]);
    }

    __syncthreads();

    {
        int pix = tid >> 2;     // 0..63: (g, c_img)
        int cp  = tid & 3;      // computes c = 2cp, 2cp+1
        int g = pix >> 3;
        int c_img = pix & 7;
        int i = c_img * 30 + (pi >> 3);
        int j = (pi & 7) * 40 + bx * 8 + g;
        const float* fp = feaB + ((size_t)i * WW + j) * 8;
        float f[8];
        *(float4*)&f[0] = *(const float4*)fp;
        *(float4*)&f[4] = *(const float4*)(fp + 4);
        float a0 = 0.f, a1 = 0.f;
        int c0 = 2 * cp;
#pragma unroll
        for (int n = 0; n < 8; n++) {       // ascending n: same FP order
            float fn = f[n];
            int rb = (8 * g + n) * 65 + c_img;
            a0 += fn * S_lds[rb + c0 * 8];
            a1 += fn * S_lds[rb + (c0 + 1) * 8];
        }
        float* dst = cos_buf + (((size_t)b * HH + i) * WW + j) * 8 + c0;
        *(float2*)dst = make_float2(a0, a1);
    }
}

// ---------------------------------------------------------------------------
// Kernel 3b (R8, full path): epilogue without offset planes; fast tanh.
// tanh(v) = 1 - 2/(exp(2v)+1): exact at saturation (exp->inf => 1, exp->0
// => -1), no NaN, abs err ~1e-7 << absmax tolerance.
// ---------------------------------------------------------------------------
__global__ __launch_bounds__(256, 4) void final3_kernel(const float* __restrict__ oa,
                                                        const float* __restrict__ cos_buf,
                                                        const void* __restrict__ conf_in,
                                                        const void* __restrict__ asc_p,
                                                        float* __restrict__ out) {
    int isbf = detect_bf16(asc_p);
    int idx = blockIdx.x * 256 + threadIdx.x;
    if (idx >= BB * HWSZ) return;
    int j = idx % WW;
    int rest = idx / WW;
    int i = rest % HH;
    int b = rest / HH;

    float cos_acc[8];
    {
        const float* cp = cos_buf + (size_t)idx * 8;
        float4 ca = *(const float4*)cp;
        float4 cb = *(const float4*)(cp + 4);
        cos_acc[0] = ca.x; cos_acc[1] = ca.y; cos_acc[2] = ca.z; cos_acc[3] = ca.w;
        cos_acc[4] = cb.x; cos_acc[5] = cb.y; cos_acc[6] = cb.z; cos_acc[7] = cb.w;
    }

    const float4* op = (const float4*)&oa[(((size_t)b * HH + i) * WW + j) * NCO];
    float own[24];
#pragma unroll
    for (int q = 0; q < 6; q++) {
        float4 v = op[q];
        own[4 * q] = v.x; own[4 * q + 1] = v.y; own[4 * q + 2] = v.z; own[4 * q + 3] = v.w;
    }

    float asc = ldF(asc_p, 0, isbf) + 1e-8f;
    long cbase = (long)b * HWSZ;

    float a[8];
    float ssum = 0.f;
#pragma unroll
    for (int c = 0; c < 8; c++) {
        float v = own[16 + c] * cos_acc[c];
        float e2 = __expf(2.f * v);
        v = (1.f - 2.f / (e2 + 1.f)) / asc;
        float py2 = own[2 * c] + (float)i;
        float px2 = own[2 * c + 1] + (float)j;
        float cf = bil_zero_poly(conf_in, cbase, px2, py2, isbf);
        v *= cf;
        a[c] = v;
        ssum += fabsf(v);
    }
    ssum += 1e-4f;
    ssum = fmaxf(ssum, 1.0f);
    float inv = 1.0f / ssum;
    float asum = 0.f;
#pragma unroll
    for (int c = 0; c < 8; c++) { a[c] *= inv; asum += a[c]; }
    float aref = 1.0f - asum;

    float vals[9];
#pragma unroll
    for (int c = 0; c < 4; c++) vals[c] = a[c];
    vals[4] = aref;
#pragma unroll
    for (int c = 4; c < 8; c++) vals[c + 1] = a[c];
    float m = vals[0];
#pragma unroll
    for (int k = 1; k < 9; k++) m = fmaxf(m, vals[k]);
    float es = 0.f;
#pragma unroll
    for (int k = 0; k < 9; k++) { vals[k] = __expf(vals[k] - m); es += vals[k]; }
    float ei = 1.0f / es;

    size_t pix = (size_t)i * WW + j;
    size_t base_o = (size_t)b * 18 * HWSZ + pix;
    out[base_o + (size_t)8 * HWSZ] = 0.f;     // zref planes
    out[base_o + (size_t)9 * HWSZ] = 0.f;
    float* aff_out = out + (size_t)BB * 18 * HWSZ;
    size_t base_a = (size_t)b * 9 * HWSZ + pix;
#pragma unroll
    for (int k = 0; k < 9; k++)
        aff_out[base_a + (size_t)k * HWSZ] = vals[k] * ei;
}

// ---------------------------------------------------------------------------
// Kernel 3b (mid path): full epilogue incl. all 18 offset planes.
// ---------------------------------------------------------------------------
__global__ __launch_bounds__(256, 4) void final2_kernel(const float* __restrict__ oa,
                                                        const float* __restrict__ cos_buf,
                                                        const void* __restrict__ conf_in,
                                                        const void* __restrict__ asc_p,
                                                        float* __restrict__ out) {
    int isbf = detect_bf16(asc_p);
    int idx = blockIdx.x * 256 + threadIdx.x;
    if (idx >= BB * HWSZ) return;
    int j = idx % WW;
    int rest = idx / WW;
    int i = rest % HH;
    int b = rest / HH;

    float cos_acc[8];
    {
        const float* cp = cos_buf + (size_t)idx * 8;
        float4 ca = *(const float4*)cp;
        float4 cb = *(const float4*)(cp + 4);
        cos_acc[0] = ca.x; cos_acc[1] = ca.y; cos_acc[2] = ca.z; cos_acc[3] = ca.w;
        cos_acc[4] = cb.x; cos_acc[5] = cb.y; cos_acc[6] = cb.z; cos_acc[7] = cb.w;
    }

    const float4* op = (const float4*)&oa[(((size_t)b * HH + i) * WW + j) * NCO];
    float own[24];
#pragma unroll
    for (int q = 0; q < 6; q++) {
        float4 v = op[q];
        own[4 * q] = v.x; own[4 * q + 1] = v.y; own[4 * q + 2] = v.z; own[4 * q + 3] = v.w;
    }

    float asc = ldF(asc_p, 0, isbf) + 1e-8f;
    long cbase = (long)b * HWSZ;

    float a[8];
    float ssum = 0.f;
#pragma unroll
    for (int c = 0; c < 8; c++) {
        float v = own[16 + c] * cos_acc[c];
        v = tanhf(v) / asc;
        float py2 = own[2 * c] + (float)i;
        float px2 = own[2 * c + 1] + (float)j;
        float cf = bil_zero_poly(conf_in, cbase, px2, py2, isbf);
        v *= cf;
        a[c] = v;
        ssum += fabsf(v);
    }
    ssum += 1e-4f;
    ssum = fmaxf(ssum, 1.0f);
    float inv = 1.0f / ssum;
    float asum = 0.f;
#pragma unroll
    for (int c = 0; c < 8; c++) { a[c] *= inv; asum += a[c]; }
    float aref = 1.0f - asum;

    float vals[9];
#pragma unroll
    for (int c = 0; c < 4; c++) vals[c] = a[c];
    vals[4] = aref;
#pragma unroll
    for (int c = 4; c < 8; c++) vals[c + 1] = a[c];
    float m = vals[0];
#pragma unroll
    for (int k = 1; k < 9; k++) m = fmaxf(m, vals[k]);
    float es = 0.f;
#pragma unroll
    for (int k = 0; k < 9; k++) { vals[k] = __expf(vals[k] - m); es += vals[k]; }
    float ei = 1.0f / es;

    size_t pix = (size_t)i * WW + j;
    size_t base_o = (size_t)b * 18 * HWSZ + pix;
#pragma unroll
    for (int ch = 0; ch < 18; ch++) {
        float v;
        if (ch < 8) v = own[ch];
        else if (ch < 10) v = 0.f;
        else v = own[ch - 2];
        out[base_o + (size_t)ch * HWSZ] = v;
    }
    float* aff_out = out + (size_t)BB * 18 * HWSZ;
    size_t base_a = (size_t)b * 9 * HWSZ + pix;
#pragma unroll
    for (int k = 0; k < 9; k++)
        aff_out[base_a + (size_t)k * HWSZ] = vals[k] * ei;
}

// ---------------------------------------------------------------------------
// OLD monolithic final kernel — emergency fallback only (tiny workspace).
// ---------------------------------------------------------------------------
__global__ __launch_bounds__(256, 4) void final_kernel(const float* __restrict__ oa,
                                                       const float* __restrict__ fea,
                                                       const void* __restrict__ conf_in,
                                                       const void* __restrict__ asc_p,
                                                       float* __restrict__ out) {
    int isbf = detect_bf16(asc_p);
    int idx = blockIdx.x * 256 + threadIdx.x;
    if (idx >= BB * HWSZ) return;
    int j = idx % WW;
    int rest = idx / WW;
    int i = rest % HH;
    int b = rest / HH;

    const float* feaB = fea + (size_t)b * 8 * HWSZ;
    float f[8];
#pragma unroll
    for (int n = 0; n < 8; n++)
        f[n] = feaB[(size_t)n * HWSZ + (size_t)i * WW + j];

    int c_img = i / 30;
    int pi = (i % 30) * 8 + j / 40;
    int pj0 = (j % 40) * 8;
    const float* feaC = feaB + (size_t)c_img * HWSZ;

    float cos_acc[8];
#pragma unroll
    for (int c = 0; c < 8; c++) cos_acc[c] = 0.f;

#pragma unroll 1
    for (int n = 0; n < 8; n++) {
        int qj = pj0 + n;
        const float4* oq = (const float4*)&oa[(((size_t)b * HH + pi) * WW + qj) * NCO];
        float4 o0 = oq[0], o1 = oq[1], o2 = oq[2], o3 = oq[3];
        float off[16] = {o0.x, o0.y, o0.z, o0.w, o1.x, o1.y, o1.z, o1.w,
                         o2.x, o2.y, o2.z, o2.w, o3.x, o3.y, o3.z, o3.w};
        float fn = f[n];
#pragma unroll
        for (int c = 0; c < 8; c++) {
            float add = (c < 4) ? (float)pi : (float)qj;
            float px = off[2 * c] + add;
            float py = off[2 * c + 1] + add;
            cos_acc[c] += fn * bil_zero_f32(feaC, px, py);
        }
    }

    const float4* op = (const float4*)&oa[(((size_t)b * HH + i) * WW + j) * NCO];
    float own[24];
#pragma unroll
    for (int q = 0; q < 6; q++) {
        float4 v = op[q];
        own[4 * q] = v.x; own[4 * q + 1] = v.y; own[4 * q + 2] = v.z; own[4 * q + 3] = v.w;
    }

    float asc = ldF(asc_p, 0, isbf) + 1e-8f;
    long cbase = (long)b * HWSZ;

    float a[8];
    float ssum = 0.f;
#pragma unroll
    for (int c = 0; c < 8; c++) {
        float v = own[16 + c] * cos_acc[c];
        v = tanhf(v) / asc;
        float py2 = own[2 * c] + (float)i;
        float px2 = own[2 * c + 1] + (float)j;
        float cf = bil_zero_poly(conf_in, cbase, px2, py2, isbf);
        v *= cf;
        a[c] = v;
        ssum += fabsf(v);
    }
    ssum += 1e-4f;
    ssum = fmaxf(ssum, 1.0f);
    float inv = 1.0f / ssum;
    float asum = 0.f;
#pragma unroll
    for (int c = 0; c < 8; c++) { a[c] *= inv; asum += a[c]; }
    float aref = 1.0f - asum;

    float vals[9];
#pragma unroll
    for (int c = 0; c < 4; c++) vals[c] = a[c];
    vals[4] = aref;
#pragma unroll
    for (int c = 4; c < 8; c++) vals[c + 1] = a[c];
    float m = vals[0];
#pragma unroll
    for (int k = 1; k < 9; k++) m = fmaxf(m, vals[k]);
    float es = 0.f;
#pragma unroll
    for (int k = 0; k < 9; k++) { vals[k] = __expf(vals[k] - m); es += vals[k]; }
    float ei = 1.0f / es;

    size_t pix = (size_t)i * WW + j;
    size_t base_o = (size_t)b * 18 * HWSZ + pix;
#pragma unroll
    for (int ch = 0; ch < 18; ch++) {
        float v;
        if (ch < 8) v = own[ch];
        else if (ch < 10) v = 0.f;
        else v = own[ch - 2];
        out[base_o + (size_t)ch * HWSZ] = v;
    }
    float* aff_out = out + (size_t)BB * 18 * HWSZ;
    size_t base_a = (size_t)b * 9 * HWSZ + pix;
#pragma unroll
    for (int k = 0; k < 9; k++)
        aff_out[base_a + (size_t)k * HWSZ] = vals[k] * ei;
}

// ---------------------------------------------------------------------------
extern "C" void kernel_launch(void* const* d_in, const int* in_sizes, int n_in,
                              void* d_out, int out_size, void* d_ws, size_t ws_size,
                              hipStream_t stream) {
    const void* guidance = d_in[0];
    const void* gtconf   = d_in[1];
    const void* tgt      = d_in[2];
    const void* conv_w   = d_in[3];
    const void* conv_b   = d_in[4];
    const void* asc      = d_in[5];

    // Workspace layout. gTu (39.3MB) and tcl (2.4MB) time-share "big";
    // cosb moved to its own region (it must outlive conv_mfma4 into final3
    // while gTu is still live during conv_mfma4 -> no aliasing with gTu).
    //   oa   : 29,491,200 B
    //   fea  :  9,830,400 B
    //   cosb :  9,830,400 B
    //   big  : 39,321,600 B (tcl | gTu)
    //   Bpu  :     36,864 B
    float* oa   = (float*)d_ws;
    float* fea  = oa + (size_t)BB * HWSZ * NCO;
    float* cosb = fea + (size_t)BB * 8 * HWSZ;
    float* big  = cosb + (size_t)BB * 8 * HWSZ;
    unsigned short* gTu = (unsigned short*)big;
    float* tcl  = big;
    unsigned short* Bpu = (unsigned short*)((char*)big + (size_t)39321600);
    const size_t ws_full = (size_t)29491200 + 9830400 + 9830400 + 39321600 + 36864; // 88,510,464
    const size_t ws_mid  = (size_t)29491200 + 9830400 + 9830400;                    // 49,152,000
    float* out = (float*)d_out;

    int n_pix = BB * HWSZ;
    int n_tgt = BB * 8 * 120 * 160;

    if (ws_size >= ws_full) {
        tgt_cl_kernel<<<(n_tgt + 255) / 256, 256, 0, stream>>>(tgt, asc, tcl);
        upsample_cl2_kernel<<<(n_pix + 255) / 256, 256, 0, stream>>>(tcl, fea);
        prep_weights<<<72, 256, 0, stream>>>(conv_w, asc, Bpu);
        dim3 pgrid(WW / 64, HH, BB);
        prep_guidance2<<<pgrid, 256, 0, stream>>>(guidance, asc, gTu);
        dim3 cgrid(WW / 64, HH / 4, BB);
        conv_mfma4_kernel<<<cgrid, 256, 0, stream>>>(gTu, Bpu, conv_b, asc, fea, oa, cosb, out);
        final3_kernel<<<(n_pix + 255) / 256, 256, 0, stream>>>(oa, cosb, gtconf, asc, out);
    } else if (ws_size >= ws_mid) {
        // mid path: no gTu; scalar conv + split cos/final2. tcl region absent:
        // reuse cosb for tcl (disjoint liveness: tcl dead after upsample;
        // cosb written by cos_kernel afterwards).
        float* tclm = cosb;
        tgt_cl_kernel<<<(n_tgt + 255) / 256, 256, 0, stream>>>(tgt, asc, tclm);
        upsample_cl2_kernel<<<(n_pix + 255) / 256, 256, 0, stream>>>(tclm, fea);
        dim3 cgrid(WW / 16, HH / 16, BB);
        conv_fallback<<<cgrid, 256, 0, stream>>>(guidance, conv_w, conv_b, asc, oa);
        dim3 ggrid(WW / 64, HH, BB);
        cos_kernel<<<ggrid, 256, 0, stream>>>(oa, fea, cosb);
        final2_kernel<<<(n_pix + 255) / 256, 256, 0, stream>>>(oa, cosb, gtconf, asc, out);
    } else {
        // --- emergency tiny-workspace path (old monolithic) ---
        int n_up = BB * 8 * HWSZ;
        upsample_kernel<<<(n_up + 255) / 256, 256, 0, stream>>>(tgt, asc, fea);
        dim3 cgrid(WW / 16, HH / 16, BB);
        conv_fallback<<<cgrid, 256, 0, stream>>>(guidance, conv_w, conv_b, asc, oa);
        final_kernel<<<(n_pix + 255) / 256, 256, 0, stream>>>(oa, fea, gtconf, asc, out);
    }
}